// Round 8
// baseline (705.312 us; speedup 1.0000x reference)
//
#include <hip/hip_runtime.h>
#include <hip/hip_bf16.h>
#include <stdint.h>

// Problem constants
#define NRES 8192
#define KNB  15
#define SDIM 128
#define EDIM 24
#define HIDD 512
#define NH   8
#define QDIM 256   // H*A
#define MIXN 10

typedef _Float16 f16;
typedef _Float16 f16x8 __attribute__((ext_vector_type(8)));
typedef float f32x4 __attribute__((ext_vector_type(4)));

struct F3 { float x, y, z; };
__device__ __forceinline__ F3 f3sub(F3 a, F3 b) { return {a.x-b.x, a.y-b.y, a.z-b.z}; }
__device__ __forceinline__ F3 f3cross(F3 a, F3 b) {
  return {a.y*b.z - a.z*b.y, a.z*b.x - a.x*b.z, a.x*b.y - a.y*b.x};
}
__device__ __forceinline__ F3 f3norm(F3 a) {
  float l = sqrtf(a.x*a.x + a.y*a.y + a.z*a.z) + 1e-8f;
  float r = 1.f / l;
  return {a.x*r, a.y*r, a.z*r};
}
__device__ __forceinline__ F3 ldpos(const float* p, int i) { return {p[i*3], p[i*3+1], p[i*3+2]}; }

// ---------------- geometry ----------------
__global__ void pos_kernel(const float* __restrict__ tert, float* __restrict__ pos) {
  int n = blockIdx.x * blockDim.x + threadIdx.x;
  if (n >= NRES) return;
  pos[n*3+0] = tert[n*9+3];
  pos[n*3+1] = tert[n*9+4];
  pos[n*3+2] = tert[n*9+5];
}

__global__ void frames_kernel(const float* __restrict__ pos, float* __restrict__ R) {
  int m = blockIdx.x * blockDim.x + threadIdx.x;
  if (m >= NRES) return;
  int s = m - 1; if (s < 0) s = 0; if (s > NRES-3) s = NRES-3;
  F3 p0 = ldpos(pos, s), p1 = ldpos(pos, s+1), p2 = ldpos(pos, s+2);
  F3 u0 = f3norm(f3sub(p1, p0));
  F3 u1 = f3norm(f3sub(p2, p1));
  F3 b  = f3norm(f3sub(u0, u1));
  F3 nn = f3norm(f3cross(u0, u1));
  F3 o  = f3cross(b, nn);
  float* r = R + m*9;
  r[0]=b.x; r[1]=nn.x; r[2]=o.x;
  r[3]=b.y; r[4]=nn.y; r[5]=o.y;
  r[6]=b.z; r[7]=nn.z; r[8]=o.z;
}

__device__ __forceinline__ float quat_comp(float t, float a, float b) {
  float s = (a > b) ? 1.f : ((a < b) ? -1.f : 0.f);
  return 0.5f * sqrtf(fmaxf(1e-8f, t)) * s;
}

__global__ void edges_kernel(const float* __restrict__ pos, const float* __restrict__ R,
                             const int* __restrict__ structure, f16* __restrict__ edges) {
  int id = blockIdx.x * blockDim.x + threadIdx.x;
  if (id >= NRES*KNB) return;
  int n = id / KNB;
  int tprev = (n - 1) & (NRES - 1);
  int sidx = structure[id];
  F3 pt = ldpos(pos, tprev), ps = ldpos(pos, sidx);
  F3 dv = f3sub(ps, pt);
  float dist = sqrtf(dv.x*dv.x + dv.y*dv.y + dv.z*dv.z);
  float rinv = 1.f / (dist + 1e-8f);
  F3 dh = {dv.x*rinv, dv.y*rinv, dv.z*rinv};
  float Rt[9], Rs[9];
#pragma unroll
  for (int i = 0; i < 9; i++) { Rt[i] = R[tprev*9+i]; Rs[i] = R[sidx*9+i]; }
  float dir[3];
#pragma unroll
  for (int i = 0; i < 3; i++) dir[i] = Rt[i]*dh.x + Rt[3+i]*dh.y + Rt[6+i]*dh.z;
  float Rr[9];
#pragma unroll
  for (int i = 0; i < 3; i++)
#pragma unroll
    for (int l = 0; l < 3; l++)
      Rr[i*3+l] = Rt[i]*Rs[l] + Rt[3+i]*Rs[3+l] + Rt[6+i]*Rs[6+l];
  float m00 = Rr[0], m11 = Rr[4], m22 = Rr[8];
  float qw = 0.5f * sqrtf(fmaxf(1e-8f, 1.f + m00 + m11 + m22));
  float qx = quat_comp(1.f + m00 - m11 - m22, Rr[7], Rr[5]);
  float qy = quat_comp(1.f - m00 + m11 - m22, Rr[2], Rr[6]);
  float qz = quat_comp(1.f - m00 - m11 + m22, Rr[3], Rr[1]);
  f16* e = edges + (size_t)id * EDIM;
#pragma unroll
  for (int j = 0; j < 16; j++) {
    float mu = (20.f / 15.f) * j;            // linspace(0,20,16)
    float zz = (dist - mu) * (1.f / 1.25f);  // sigma = 20/16
    e[j] = (f16)expf(-zz*zz);
  }
  e[16] = (f16)dir[0]; e[17] = (f16)dir[1]; e[18] = (f16)dir[2];
  e[19] = (f16)qw; e[20] = (f16)qx; e[21] = (f16)qy; e[22] = (f16)qz;
  e[23] = (f16)((float)(sidx - tprev) * 0.01f);
}

// ---------------- input embedding ----------------
__global__ __launch_bounds__(128) void init_kernel(const float* __restrict__ angles,
    const float* __restrict__ W_in, const float* __restrict__ b_in,
    const float* __restrict__ W_pre, const float* __restrict__ b_pre, float* __restrict__ x) {
  int n = blockIdx.x, c = threadIdx.x;
  __shared__ float fs[128];
  float af[6];
  if (n == 0) { af[0]=af[1]=af[2]=0.f; af[3]=af[4]=af[5]=1.f; }
  else {
#pragma unroll
    for (int j = 0; j < 3; j++) {
      float p = angles[(n-1)*3 + j];
      af[j] = sinf(p); af[3+j] = cosf(p);
    }
  }
  float f = b_in[c];
#pragma unroll
  for (int j = 0; j < 6; j++) f += af[j] * W_in[j*SDIM + c];
  fs[c] = f;
  __syncthreads();
  float xv = b_pre[c];
  for (int j = 0; j < 128; j++) xv += fs[j] * W_pre[j*SDIM + c];
  x[(size_t)n*SDIM + c] = xv;
}

// ---------------- layernorm: f32 in -> fp16 out (GEMM A-operand) ----------------
__global__ __launch_bounds__(128) void ln_kernel(const float* __restrict__ x,
    const float* __restrict__ g, const float* __restrict__ b, f16* __restrict__ out) {
  int n = blockIdx.x, c = threadIdx.x;
  float v = x[(size_t)n*SDIM + c];
  float s = v;
#pragma unroll
  for (int m = 32; m >= 1; m >>= 1) s += __shfl_xor(s, m, 64);
  __shared__ float p1[2], p2[2];
  if ((c & 63) == 0) p1[c >> 6] = s;
  __syncthreads();
  float mean = (p1[0] + p1[1]) * (1.f/128.f);
  float d = v - mean;
  float s2 = d * d;
#pragma unroll
  for (int m = 32; m >= 1; m >>= 1) s2 += __shfl_xor(s2, m, 64);
  if ((c & 63) == 0) p2[c >> 6] = s2;
  __syncthreads();
  float var = (p2[0] + p2[1]) * (1.f/128.f);
  out[(size_t)n*SDIM + c] = (f16)(d * rsqrtf(var + 1e-5f) * g[c] + b[c]);
}

// ---------------- weight convert+swizzle: f32 [K][N] -> fp16 frag layout ----------------
// dst[((k>>3)*dstN + colOff + n)*8 + (k&7)] so a b-frag (fixed n, 8 consecutive k) is one 16B load.
__global__ void convswz_kernel(const float* __restrict__ src, int srcLayerStride, int srcLd,
    int K, int N, f16* __restrict__ dst, int dstLayerHalves, int dstN, int colOff) {
  int d = blockIdx.y;
  const float* s = src + (size_t)d * srcLayerStride;
  f16* o = dst + (size_t)d * dstLayerHalves;
  for (int i = blockIdx.x*blockDim.x + threadIdx.x; i < K*N; i += gridDim.x*blockDim.x) {
    int k = i / N, n = i - k*N;
    o[((size_t)(k>>3)*dstN + colOff + n)*8 + (k&7)] = (f16)s[(size_t)k*srcLd + n];
  }
}

__global__ void bias768_kernel(const float* __restrict__ bq, float* __restrict__ out) {
  int i = blockIdx.x*blockDim.x + threadIdx.x;
  if (i >= 3*768) return;
  int d = i / 768, col = i - d*768;
  out[i] = (col < 256) ? bq[d*QDIM + col] : 0.f;  // pk/pv biases folded into attn algebra
}

// ---------------- MFMA GEMM: C(8192xN) = A(8192xK fp16) @ Bsw(KxN fp16 swizzled) ----------------
// One wave = 32(M) x 64(N) tile, no LDS, no syncthreads. M fixed at 8192 (mTiles=256).
// MODE 1: fp16 C = relu(AB+bias) ; MODE 2: f32 C += AB+bias ; MODE 3: fp16 qkv-split store (Nd=768)
template<int MODE>
__global__ __launch_bounds__(256) void gemm_mfma(const f16* __restrict__ A,
    const f16* __restrict__ Bsw, const float* __restrict__ bias,
    void* __restrict__ Cv, int Kd, int Nd) {
  int w = blockIdx.x * 4 + (threadIdx.x >> 6);
  int lane = threadIdx.x & 63;
  int wm = w & 255, wn = w >> 8;       // mTiles = 8192/32 = 256; wm fastest for B reuse on-CU
  int m0 = wm * 32, n0 = wn * 64;
  int r16 = lane & 15, qd = lane >> 4;
  f32x4 acc[2][4] = {};
  const f16* aBase = A + (size_t)(m0 + r16)*Kd + qd*8;
  for (int kc = 0; kc < Kd; kc += 32) {
    f16x8 af0 = *(const f16x8*)(aBase + kc);
    f16x8 af1 = *(const f16x8*)(aBase + (size_t)16*Kd + kc);
    const f16* bBase = Bsw + ((size_t)((kc>>3) + qd)*Nd + n0 + r16)*8;
    f16x8 bf[4];
#pragma unroll
    for (int nt = 0; nt < 4; nt++) bf[nt] = *(const f16x8*)(bBase + nt*16*8);
#pragma unroll
    for (int nt = 0; nt < 4; nt++) {
      acc[0][nt] = __builtin_amdgcn_mfma_f32_16x16x32_f16(af0, bf[nt], acc[0][nt], 0, 0, 0);
      acc[1][nt] = __builtin_amdgcn_mfma_f32_16x16x32_f16(af1, bf[nt], acc[1][nt], 0, 0, 0);
    }
  }
  // D layout: row = qd*4 + r, col = r16 (per 16x16 tile)
#pragma unroll
  for (int mt = 0; mt < 2; mt++) {
#pragma unroll
    for (int nt = 0; nt < 4; nt++) {
      int col = n0 + nt*16 + r16;
      float bj = bias ? bias[col] : 0.f;
#pragma unroll
      for (int r = 0; r < 4; r++) {
        int row = m0 + mt*16 + qd*4 + r;
        float v = acc[mt][nt][r] + bj;
        if (MODE == 1) {
          ((f16*)Cv)[(size_t)row*Nd + col] = (f16)fmaxf(v, 0.f);
        } else if (MODE == 2) {
          ((float*)Cv)[(size_t)row*Nd + col] += v;
        } else {  // MODE 3: cols [0,256)->q, [256,512)->pk, [512,768)->pv, each stride 256, fp16
          int third = col >> 8, cl = col & 255;
          ((f16*)Cv)[(size_t)third*NRES*QDIM + (size_t)row*QDIM + cl] = (f16)v;
        }
      }
    }
  }
}

// ---------------- fused attention (one block = one node, 256 threads = 256 channels) ----------------
// q/pk/pv/edges fp16; qW (edge-side K projection of q) computed inline via shuffle reduce.
__global__ __launch_bounds__(256) void attn_kernel(const f16* __restrict__ q,
    const f16* __restrict__ pk, const f16* __restrict__ pv,
    const f16* __restrict__ edges, const int* __restrict__ structure,
    const float* __restrict__ WkB, const float* __restrict__ bk,
    const float* __restrict__ WvB, const float* __restrict__ bv, f16* __restrict__ att) {
  int n = blockIdx.x, c = threadIdx.x;
  __shared__ float e_s[KNB*EDIM];
  __shared__ float qw_s[NH*25];
  __shared__ float logit_s[KNB][NH];
  __shared__ float attw_s[KNB][NH];
  __shared__ float ew_s[NH][EDIM];

  int s[KNB];
#pragma unroll
  for (int kk = 0; kk < KNB; kk++) s[kk] = structure[n*KNB + kk];
  // issue all 30 fp16 gathers immediately
  float pks[KNB], pvs[KNB];
#pragma unroll
  for (int kk = 0; kk < KNB; kk++) pks[kk] = (float)pk[(size_t)s[kk]*QDIM + c];
#pragma unroll
  for (int kk = 0; kk < KNB; kk++) pvs[kk] = (float)pv[(size_t)s[kk]*QDIM + c];
  float qc = (float)q[(size_t)n*QDIM + c];
  float bvc = bv[c];
  for (int i = c; i < KNB*EDIM; i += 256) e_s[i] = (float)edges[(size_t)n*KNB*EDIM + i];

  int h = c >> 5;
  // inline qW: qw_s[h*25+jj] = sum_{c in head h} q_c * (jj<24 ? WkB[jj][c] : bk[c])
  for (int jj = 0; jj < 25; jj++) {
    float wv = (jj < 24) ? WkB[jj*QDIM + c] : bk[c];
    float p = qc * wv;
    p += __shfl_xor(p, 16, 32);
    p += __shfl_xor(p, 8, 32);
    p += __shfl_xor(p, 4, 32);
    p += __shfl_xor(p, 2, 32);
    p += __shfl_xor(p, 1, 32);
    if ((c & 31) == 0) qw_s[h*25 + jj] = p;
  }
  // gather-dot part of logits
#pragma unroll
  for (int kk = 0; kk < KNB; kk++) {
    float p = qc * pks[kk];
    p += __shfl_xor(p, 16, 32);
    p += __shfl_xor(p, 8, 32);
    p += __shfl_xor(p, 4, 32);
    p += __shfl_xor(p, 2, 32);
    p += __shfl_xor(p, 1, 32);
    if ((c & 31) == 0) logit_s[kk][h] = p;
  }
  __syncthreads();
  if (c < KNB*NH) {
    int kk = c / NH, hh = c % NH;
    float l = logit_s[kk][hh] + qw_s[hh*25 + 24];
    const float* qwr = &qw_s[hh*25];
    const float* er  = &e_s[kk*EDIM];
#pragma unroll
    for (int j = 0; j < EDIM; j++) l += qwr[j] * er[j];
    logit_s[kk][hh] = l * 0.17677669529663687f;  // 1/sqrt(32)
  }
  __syncthreads();
  if (c < NH) {
    float mx = -1e30f;
    for (int kk = 0; kk < KNB; kk++) mx = fmaxf(mx, logit_s[kk][c]);
    float w[KNB]; float sum = 0.f;
    for (int kk = 0; kk < KNB; kk++) { w[kk] = expf(logit_s[kk][c] - mx); sum += w[kk]; }
    float inv = 1.f / sum;
    for (int kk = 0; kk < KNB; kk++) attw_s[kk][c] = w[kk] * inv;
  }
  __syncthreads();
  if (c < NH*EDIM) {
    int hh = c / EDIM, j = c % EDIM;
    float acc = 0.f;
#pragma unroll
    for (int kk = 0; kk < KNB; kk++) acc += attw_s[kk][hh] * e_s[kk*EDIM + j];
    ew_s[hh][j] = acc;
  }
  __syncthreads();
  float vg = bvc;
#pragma unroll
  for (int kk = 0; kk < KNB; kk++) vg += attw_s[kk][h] * pvs[kk];
  float o = vg;
#pragma unroll
  for (int j = 0; j < EDIM; j++) o += ew_s[h][j] * WvB[(size_t)j*QDIM + c];
  att[(size_t)n*QDIM + c] = (f16)o;
}

// ---------------- output head (f32 output) ----------------
__global__ __launch_bounds__(128) void head_kernel(const float* __restrict__ enc,
    const float* Ws, const float* bs, const float* Wc, const float* bc,
    const float* Wconc, const float* bconc, const float* Wwt, const float* bwt,
    const float* Wfac, const float* bfac, const float* __restrict__ angles, float* __restrict__ out) {
  int n = blockIdx.x, t = threadIdx.x;
  __shared__ float es[128];
  __shared__ float outs[103];
  es[t] = enc[(size_t)n*SDIM + t];
  __syncthreads();
  const float* W = nullptr; const float* bb = nullptr; int col = 0, nc = 0;
  if (t < 30)       { W = Ws;    bb = bs;    col = t;       nc = 30; }
  else if (t < 60)  { W = Wc;    bb = bc;    col = t - 30;  nc = 30; }
  else if (t < 90)  { W = Wconc; bb = bconc; col = t - 60;  nc = 30; }
  else if (t < 100) { W = Wwt;   bb = bwt;   col = t - 90;  nc = 10; }
  else if (t < 103) { W = Wfac;  bb = bfac;  col = t - 100; nc = 3;  }
  if (W) {
    float acc = bb[col];
    for (int j = 0; j < 128; j++) acc += es[j] * W[j*nc + col];
    outs[t] = acc;
  }
  __syncthreads();
  if (t < MIXN) {
    float mx = -1e30f;
    for (int m = 0; m < MIXN; m++) mx = fmaxf(mx, outs[90 + m]);
    float sum = 0.f;
    for (int m = 0; m < MIXN; m++) sum += expf(outs[90 + m] - mx);
    out[(size_t)n*MIXN + t] = expf(outs[90 + t] - mx) / sum;
  }
  if (t < 30) {
    int j = t / 10;
    float v = atan2f(outs[t], outs[30 + t]);
    float a0 = angles[n*3 + 0], a1 = angles[n*3 + 1];
    if (j == 1) v += outs[100] * a0;
    if (j == 2) v += outs[101] * a0 + outs[102] * a1;
    out[(size_t)NRES*MIXN + (size_t)n*30 + t] = v;
    float z = outs[60 + t];
    float sg = 1.f / (1.f + expf(-z));
    out[(size_t)NRES*MIXN + (size_t)NRES*30 + (size_t)n*30 + t] = 0.1f + 1000.f * sg;
  }
}

// ---------------- launch ----------------
extern "C" void kernel_launch(void* const* d_in, const int* in_sizes, int n_in,
                              void* d_out, int out_size, void* d_ws, size_t ws_size,
                              hipStream_t stream) {
  const float* angles   = (const float*)d_in[0];
  const float* tertiary = (const float*)d_in[1];
  const int*   structure = (const int*)d_in[2];
  // d_in[3] = subgraph (unused)
  const float* W_in  = (const float*)d_in[4];  const float* b_in  = (const float*)d_in[5];
  const float* W_pre = (const float*)d_in[6];  const float* b_pre = (const float*)d_in[7];
  const float* ln1_g = (const float*)d_in[8];  const float* ln1_b = (const float*)d_in[9];
  const float* ln2_g = (const float*)d_in[10]; const float* ln2_b = (const float*)d_in[11];
  const float* Wq = (const float*)d_in[12]; const float* bq = (const float*)d_in[13];
  const float* Wk = (const float*)d_in[14]; const float* bk = (const float*)d_in[15];
  const float* Wv = (const float*)d_in[16]; const float* bv = (const float*)d_in[17];
  const float* Wo = (const float*)d_in[18]; const float* bo = (const float*)d_in[19];
  const float* W1 = (const float*)d_in[20]; const float* b1 = (const float*)d_in[21];
  const float* W2 = (const float*)d_in[22]; const float* b2 = (const float*)d_in[23];
  const float* W3 = (const float*)d_in[24]; const float* b3 = (const float*)d_in[25];
  const float* Ws = (const float*)d_in[26]; const float* bs = (const float*)d_in[27];
  const float* Wc = (const float*)d_in[28]; const float* bc = (const float*)d_in[29];
  const float* Wconc = (const float*)d_in[30]; const float* bconc = (const float*)d_in[31];
  const float* Wwt = (const float*)d_in[32]; const float* bwt = (const float*)d_in[33];
  const float* Wfac = (const float*)d_in[34]; const float* bfac = (const float*)d_in[35];

  // workspace layout (bytes); high-water ~49.3 MB (<= 62.5 MB established safe)
  char* wsb = (char*)d_ws;
  float* pos   = (float*)(wsb + 0);           //    98,304 B
  float* Rm    = (float*)(wsb + 98304);       //   294,912 B
  f16*   edg_h = (f16*)  (wsb + 393216);      // 5,898,240 B
  float* x     = (float*)(wsb + 6291456);     // 4 MiB f32 residual
  f16*   nx_h  = (f16*)  (wsb + 10485760);    // 2 MiB
  f16*   att_h = (f16*)  (wsb + 12582912);    // 4 MiB
  f16*   qh    = (f16*)  (wsb + 16777216);    // 4 MiB  (q | pk | pv contiguous fp16)
  f16*   pkh   = (f16*)  (wsb + 20971520);    // 4 MiB
  f16*   pvh   = (f16*)  (wsb + 25165824);    // 4 MiB -> ends 29,360,128
  f16*   h1h   = (f16*)  (wsb + 29360128);    // 8 MiB
  f16*   h2h   = (f16*)  (wsb + 37748736);    // 8 MiB -> ends 46,137,344
  f16*   qkvw  = (f16*)  (wsb + 46137344);    //   589,824 B (3 x 128x768)
  f16*   w1w   = (f16*)  (wsb + 46727168);    //   393,216 B
  f16*   w2w   = (f16*)  (wsb + 47120384);    // 1,572,864 B
  f16*   w3w   = (f16*)  (wsb + 48693248);    //   393,216 B
  f16*   wow   = (f16*)  (wsb + 49086464);    //   196,608 B
  float* b768  = (float*)(wsb + 49283072);    //     9,216 B -> ends 49,292,288

  pos_kernel<<<dim3((NRES+255)/256), dim3(256), 0, stream>>>(tertiary, pos);
  frames_kernel<<<dim3((NRES+255)/256), dim3(256), 0, stream>>>(pos, Rm);
  edges_kernel<<<dim3((NRES*KNB+255)/256), dim3(256), 0, stream>>>(pos, Rm, structure, edg_h);
  init_kernel<<<dim3(NRES), dim3(128), 0, stream>>>(angles, W_in, b_in, W_pre, b_pre, x);

  // one-time weight conversions to fp16 frag-swizzled layouts (all 3 layers each)
  convswz_kernel<<<dim3(64,3), 256, 0, stream>>>(Wq, SDIM*QDIM, QDIM, 128, 256, qkvw, 98304, 768, 0);
  convswz_kernel<<<dim3(64,3), 256, 0, stream>>>(Wk, (SDIM+EDIM)*QDIM, QDIM, 128, 256, qkvw, 98304, 768, 256);
  convswz_kernel<<<dim3(64,3), 256, 0, stream>>>(Wv, (SDIM+EDIM)*QDIM, QDIM, 128, 256, qkvw, 98304, 768, 512);
  convswz_kernel<<<dim3(64,3), 256, 0, stream>>>(W1, SDIM*HIDD, HIDD, 128, 512, w1w, 65536, 512, 0);
  convswz_kernel<<<dim3(64,3), 256, 0, stream>>>(W2, HIDD*HIDD, HIDD, 512, 512, w2w, 262144, 512, 0);
  convswz_kernel<<<dim3(64,3), 256, 0, stream>>>(W3, HIDD*SDIM, SDIM, 512, 128, w3w, 65536, 128, 0);
  convswz_kernel<<<dim3(64,3), 256, 0, stream>>>(Wo, QDIM*SDIM, SDIM, 256, 128, wow, 32768, 128, 0);
  bias768_kernel<<<9, 256, 0, stream>>>(bq, b768);

  for (int d = 0; d < 3; ++d) {
    const float* WkD = Wk + (size_t)d*(SDIM+EDIM)*QDIM;
    const float* WvD = Wv + (size_t)d*(SDIM+EDIM)*QDIM;
    ln_kernel<<<dim3(NRES), dim3(128), 0, stream>>>(x, ln1_g + d*SDIM, ln1_b + d*SDIM, nx_h);
    // fused q|pk|pv GEMM: Nd=768 -> fp16 split store into qh/pkh/pvh (bias only on q part)
    gemm_mfma<3><<<768, 256, 0, stream>>>(nx_h, qkvw + (size_t)d*98304, b768 + d*768, qh, 128, 768);
    attn_kernel<<<dim3(NRES), dim3(256), 0, stream>>>(qh, pkh, pvh, edg_h, structure,
        WkD + (size_t)SDIM*QDIM, bk + d*QDIM,
        WvD + (size_t)SDIM*QDIM, bv + d*QDIM, att_h);
    gemm_mfma<2><<<128, 256, 0, stream>>>(att_h, wow + (size_t)d*32768, bo + d*SDIM, x, 256, 128);
    ln_kernel<<<dim3(NRES), dim3(128), 0, stream>>>(x, ln2_g + d*SDIM, ln2_b + d*SDIM, nx_h);
    gemm_mfma<1><<<512, 256, 0, stream>>>(nx_h, w1w + (size_t)d*65536, b1 + d*HIDD, h1h, 128, 512);
    gemm_mfma<1><<<512, 256, 0, stream>>>(h1h, w2w + (size_t)d*262144, b2 + d*HIDD, h2h, 512, 512);
    gemm_mfma<2><<<128, 256, 0, stream>>>(h2h, w3w + (size_t)d*65536, b3 + d*SDIM, x, 512, 128);
  }

  head_kernel<<<dim3(NRES), dim3(128), 0, stream>>>(x, Ws, bs, Wc, bc, Wconc, bconc,
      Wwt, bwt, Wfac, bfac, angles, (float*)d_out);
}

// Round 9
// 646.070 us; speedup vs baseline: 1.0917x; 1.0917x over previous
//
#include <hip/hip_runtime.h>
#include <hip/hip_bf16.h>
#include <stdint.h>

// Problem constants
#define NRES 8192
#define KNB  15
#define SDIM 128
#define EDIM 24
#define HIDD 512
#define NH   8
#define QDIM 256   // H*A
#define MIXN 10

typedef _Float16 f16;
typedef _Float16 f16x8 __attribute__((ext_vector_type(8)));
typedef float f32x4 __attribute__((ext_vector_type(4)));

struct F3 { float x, y, z; };
__device__ __forceinline__ F3 f3sub(F3 a, F3 b) { return {a.x-b.x, a.y-b.y, a.z-b.z}; }
__device__ __forceinline__ F3 f3cross(F3 a, F3 b) {
  return {a.y*b.z - a.z*b.y, a.z*b.x - a.x*b.z, a.x*b.y - a.y*b.x};
}
__device__ __forceinline__ F3 f3norm(F3 a) {
  float l = sqrtf(a.x*a.x + a.y*a.y + a.z*a.z) + 1e-8f;
  float r = 1.f / l;
  return {a.x*r, a.y*r, a.z*r};
}
__device__ __forceinline__ F3 ldpos(const float* p, int i) { return {p[i*3], p[i*3+1], p[i*3+2]}; }

// ---------------- geometry ----------------
__global__ void pos_kernel(const float* __restrict__ tert, float* __restrict__ pos) {
  int n = blockIdx.x * blockDim.x + threadIdx.x;
  if (n >= NRES) return;
  pos[n*3+0] = tert[n*9+3];
  pos[n*3+1] = tert[n*9+4];
  pos[n*3+2] = tert[n*9+5];
}

__global__ void frames_kernel(const float* __restrict__ pos, float* __restrict__ R) {
  int m = blockIdx.x * blockDim.x + threadIdx.x;
  if (m >= NRES) return;
  int s = m - 1; if (s < 0) s = 0; if (s > NRES-3) s = NRES-3;
  F3 p0 = ldpos(pos, s), p1 = ldpos(pos, s+1), p2 = ldpos(pos, s+2);
  F3 u0 = f3norm(f3sub(p1, p0));
  F3 u1 = f3norm(f3sub(p2, p1));
  F3 b  = f3norm(f3sub(u0, u1));
  F3 nn = f3norm(f3cross(u0, u1));
  F3 o  = f3cross(b, nn);
  float* r = R + m*9;
  r[0]=b.x; r[1]=nn.x; r[2]=o.x;
  r[3]=b.y; r[4]=nn.y; r[5]=o.y;
  r[6]=b.z; r[7]=nn.z; r[8]=o.z;
}

__device__ __forceinline__ float quat_comp(float t, float a, float b) {
  float s = (a > b) ? 1.f : ((a < b) ? -1.f : 0.f);
  return 0.5f * sqrtf(fmaxf(1e-8f, t)) * s;
}

__global__ void edges_kernel(const float* __restrict__ pos, const float* __restrict__ R,
                             const int* __restrict__ structure, f16* __restrict__ edges) {
  int id = blockIdx.x * blockDim.x + threadIdx.x;
  if (id >= NRES*KNB) return;
  int n = id / KNB;
  int tprev = (n - 1) & (NRES - 1);
  int sidx = structure[id];
  F3 pt = ldpos(pos, tprev), ps = ldpos(pos, sidx);
  F3 dv = f3sub(ps, pt);
  float dist = sqrtf(dv.x*dv.x + dv.y*dv.y + dv.z*dv.z);
  float rinv = 1.f / (dist + 1e-8f);
  F3 dh = {dv.x*rinv, dv.y*rinv, dv.z*rinv};
  float Rt[9], Rs[9];
#pragma unroll
  for (int i = 0; i < 9; i++) { Rt[i] = R[tprev*9+i]; Rs[i] = R[sidx*9+i]; }
  float dir[3];
#pragma unroll
  for (int i = 0; i < 3; i++) dir[i] = Rt[i]*dh.x + Rt[3+i]*dh.y + Rt[6+i]*dh.z;
  float Rr[9];
#pragma unroll
  for (int i = 0; i < 3; i++)
#pragma unroll
    for (int l = 0; l < 3; l++)
      Rr[i*3+l] = Rt[i]*Rs[l] + Rt[3+i]*Rs[3+l] + Rt[6+i]*Rs[6+l];
  float m00 = Rr[0], m11 = Rr[4], m22 = Rr[8];
  float qw = 0.5f * sqrtf(fmaxf(1e-8f, 1.f + m00 + m11 + m22));
  float qx = quat_comp(1.f + m00 - m11 - m22, Rr[7], Rr[5]);
  float qy = quat_comp(1.f - m00 + m11 - m22, Rr[2], Rr[6]);
  float qz = quat_comp(1.f - m00 - m11 + m22, Rr[3], Rr[1]);
  f16* e = edges + (size_t)id * EDIM;
#pragma unroll
  for (int j = 0; j < 16; j++) {
    float mu = (20.f / 15.f) * j;            // linspace(0,20,16)
    float zz = (dist - mu) * (1.f / 1.25f);  // sigma = 20/16
    e[j] = (f16)expf(-zz*zz);
  }
  e[16] = (f16)dir[0]; e[17] = (f16)dir[1]; e[18] = (f16)dir[2];
  e[19] = (f16)qw; e[20] = (f16)qx; e[21] = (f16)qy; e[22] = (f16)qz;
  e[23] = (f16)((float)(sidx - tprev) * 0.01f);
}

// ---------------- input embedding ----------------
__global__ __launch_bounds__(128) void init_kernel(const float* __restrict__ angles,
    const float* __restrict__ W_in, const float* __restrict__ b_in,
    const float* __restrict__ W_pre, const float* __restrict__ b_pre, float* __restrict__ x) {
  int n = blockIdx.x, c = threadIdx.x;
  __shared__ float fs[128];
  float af[6];
  if (n == 0) { af[0]=af[1]=af[2]=0.f; af[3]=af[4]=af[5]=1.f; }
  else {
#pragma unroll
    for (int j = 0; j < 3; j++) {
      float p = angles[(n-1)*3 + j];
      af[j] = sinf(p); af[3+j] = cosf(p);
    }
  }
  float f = b_in[c];
#pragma unroll
  for (int j = 0; j < 6; j++) f += af[j] * W_in[j*SDIM + c];
  fs[c] = f;
  __syncthreads();
  float xv = b_pre[c];
  for (int j = 0; j < 128; j++) xv += fs[j] * W_pre[j*SDIM + c];
  x[(size_t)n*SDIM + c] = xv;
}

// ---------------- layernorm: f32 in -> fp16 out (GEMM A-operand) ----------------
__global__ __launch_bounds__(128) void ln_kernel(const float* __restrict__ x,
    const float* __restrict__ g, const float* __restrict__ b, f16* __restrict__ out) {
  int n = blockIdx.x, c = threadIdx.x;
  float v = x[(size_t)n*SDIM + c];
  float s = v;
#pragma unroll
  for (int m = 32; m >= 1; m >>= 1) s += __shfl_xor(s, m, 64);
  __shared__ float p1[2], p2[2];
  if ((c & 63) == 0) p1[c >> 6] = s;
  __syncthreads();
  float mean = (p1[0] + p1[1]) * (1.f/128.f);
  float d = v - mean;
  float s2 = d * d;
#pragma unroll
  for (int m = 32; m >= 1; m >>= 1) s2 += __shfl_xor(s2, m, 64);
  if ((c & 63) == 0) p2[c >> 6] = s2;
  __syncthreads();
  float var = (p2[0] + p2[1]) * (1.f/128.f);
  out[(size_t)n*SDIM + c] = (f16)(d * rsqrtf(var + 1e-5f) * g[c] + b[c]);
}

// ---------------- weight convert+swizzle: f32 [K][N] -> fp16 frag layout ----------------
// dst[((k>>3)*dstN + colOff + n)*8 + (k&7)] so a b-frag (fixed n, 8 consecutive k) is one 16B load.
__global__ void convswz_kernel(const float* __restrict__ src, int srcLayerStride, int srcLd,
    int K, int N, f16* __restrict__ dst, int dstLayerHalves, int dstN, int colOff) {
  int d = blockIdx.y;
  const float* s = src + (size_t)d * srcLayerStride;
  f16* o = dst + (size_t)d * dstLayerHalves;
  for (int i = blockIdx.x*blockDim.x + threadIdx.x; i < K*N; i += gridDim.x*blockDim.x) {
    int k = i / N, n = i - k*N;
    o[((size_t)(k>>3)*dstN + colOff + n)*8 + (k&7)] = (f16)s[(size_t)k*srcLd + n];
  }
}

__global__ void bias768_kernel(const float* __restrict__ bq, float* __restrict__ out) {
  int i = blockIdx.x*blockDim.x + threadIdx.x;
  if (i >= 3*768) return;
  int d = i / 768, col = i - d*768;
  out[i] = (col < 256) ? bq[d*QDIM + col] : 0.f;  // pk/pv biases folded into attn algebra
}

// ---------------- MFMA GEMM: C(8192xN) = A(8192xK fp16) @ Bsw(KxN fp16 swizzled) ----------------
// One wave = 32(M) x 64(N) tile, no LDS, no syncthreads. M fixed at 8192 (mTiles=256).
// MODE 1: fp16 C = relu(AB+bias) ; MODE 2: f32 C += AB+bias ; MODE 3: fp16 qkv-split store (Nd=768)
template<int MODE>
__global__ __launch_bounds__(256) void gemm_mfma(const f16* __restrict__ A,
    const f16* __restrict__ Bsw, const float* __restrict__ bias,
    void* __restrict__ Cv, int Kd, int Nd) {
  int w = blockIdx.x * 4 + (threadIdx.x >> 6);
  int lane = threadIdx.x & 63;
  int wm = w & 255, wn = w >> 8;       // mTiles = 8192/32 = 256; wm fastest for B reuse on-CU
  int m0 = wm * 32, n0 = wn * 64;
  int r16 = lane & 15, qd = lane >> 4;
  f32x4 acc[2][4] = {};
  const f16* aBase = A + (size_t)(m0 + r16)*Kd + qd*8;
  for (int kc = 0; kc < Kd; kc += 32) {
    f16x8 af0 = *(const f16x8*)(aBase + kc);
    f16x8 af1 = *(const f16x8*)(aBase + (size_t)16*Kd + kc);
    const f16* bBase = Bsw + ((size_t)((kc>>3) + qd)*Nd + n0 + r16)*8;
    f16x8 bf[4];
#pragma unroll
    for (int nt = 0; nt < 4; nt++) bf[nt] = *(const f16x8*)(bBase + nt*16*8);
#pragma unroll
    for (int nt = 0; nt < 4; nt++) {
      acc[0][nt] = __builtin_amdgcn_mfma_f32_16x16x32_f16(af0, bf[nt], acc[0][nt], 0, 0, 0);
      acc[1][nt] = __builtin_amdgcn_mfma_f32_16x16x32_f16(af1, bf[nt], acc[1][nt], 0, 0, 0);
    }
  }
  // D layout: row = qd*4 + r, col = r16 (per 16x16 tile)
#pragma unroll
  for (int mt = 0; mt < 2; mt++) {
#pragma unroll
    for (int nt = 0; nt < 4; nt++) {
      int col = n0 + nt*16 + r16;
      float bj = bias ? bias[col] : 0.f;
#pragma unroll
      for (int r = 0; r < 4; r++) {
        int row = m0 + mt*16 + qd*4 + r;
        float v = acc[mt][nt][r] + bj;
        if (MODE == 1) {
          ((f16*)Cv)[(size_t)row*Nd + col] = (f16)fmaxf(v, 0.f);
        } else if (MODE == 2) {
          ((float*)Cv)[(size_t)row*Nd + col] += v;
        } else {  // MODE 3: cols [0,256)->q, [256,512)->pk, [512,768)->pv, each stride 256, fp16
          int third = col >> 8, cl = col & 255;
          ((f16*)Cv)[(size_t)third*NRES*QDIM + (size_t)row*QDIM + cl] = (f16)v;
        }
      }
    }
  }
}

// ---------------- qW precompute: qW[n,h,jj] = sum_{c in head h} q[n,c]*(jj<24 ? WkB[jj][c] : bk[c]) ----------------
__global__ __launch_bounds__(256) void qw_kernel(const f16* __restrict__ q,
    const float* __restrict__ WkB, const float* __restrict__ bk, float* __restrict__ qW) {
  int n = blockIdx.x, t = threadIdx.x;
  if (t >= NH*25) return;
  int h = t / 25, jj = t % 25;
  const f16*   qr = q + (size_t)n*QDIM + h*32;
  const float* wr = (jj < 24) ? (WkB + (size_t)jj*QDIM + h*32) : (bk + h*32);
  float acc = 0.f;
#pragma unroll
  for (int c2 = 0; c2 < 32; c2++) acc += (float)qr[c2] * wr[c2];
  qW[(size_t)n*(NH*25) + t] = acc;
}

// ---------------- fused attention (one block = one node, 256 threads = 256 channels) ----------------
__global__ __launch_bounds__(256) void attn_kernel(const f16* __restrict__ q,
    const f16* __restrict__ pk, const f16* __restrict__ pv,
    const f16* __restrict__ edges, const int* __restrict__ structure,
    const float* __restrict__ qW, const float* __restrict__ WvB,
    const float* __restrict__ bv, f16* __restrict__ att) {
  int n = blockIdx.x, c = threadIdx.x;
  __shared__ float e_s[KNB*EDIM];
  __shared__ float qw_s[NH*25];
  __shared__ float logit_s[KNB][NH];
  __shared__ float attw_s[KNB][NH];
  __shared__ float ew_s[NH][EDIM];

  int s[KNB];
#pragma unroll
  for (int kk = 0; kk < KNB; kk++) s[kk] = structure[n*KNB + kk];
  // issue all 30 fp16 gathers immediately
  float pks[KNB], pvs[KNB];
#pragma unroll
  for (int kk = 0; kk < KNB; kk++) pks[kk] = (float)pk[(size_t)s[kk]*QDIM + c];
#pragma unroll
  for (int kk = 0; kk < KNB; kk++) pvs[kk] = (float)pv[(size_t)s[kk]*QDIM + c];
  float qc = (float)q[(size_t)n*QDIM + c];
  float bvc = bv[c];
  for (int i = c; i < KNB*EDIM; i += 256) e_s[i] = (float)edges[(size_t)n*KNB*EDIM + i];
  for (int i = c; i < NH*25;    i += 256) qw_s[i] = qW[(size_t)n*(NH*25) + i];

  int h = c >> 5;
  // gather-dot part of logits
#pragma unroll
  for (int kk = 0; kk < KNB; kk++) {
    float p = qc * pks[kk];
    p += __shfl_xor(p, 16, 32);
    p += __shfl_xor(p, 8, 32);
    p += __shfl_xor(p, 4, 32);
    p += __shfl_xor(p, 2, 32);
    p += __shfl_xor(p, 1, 32);
    if ((c & 31) == 0) logit_s[kk][h] = p;
  }
  __syncthreads();
  if (c < KNB*NH) {
    int kk = c / NH, hh = c % NH;
    float l = logit_s[kk][hh] + qw_s[hh*25 + 24];
    const float* qwr = &qw_s[hh*25];
    const float* er  = &e_s[kk*EDIM];
#pragma unroll
    for (int j = 0; j < EDIM; j++) l += qwr[j] * er[j];
    logit_s[kk][hh] = l * 0.17677669529663687f;  // 1/sqrt(32)
  }
  __syncthreads();
  if (c < NH) {
    float mx = -1e30f;
    for (int kk = 0; kk < KNB; kk++) mx = fmaxf(mx, logit_s[kk][c]);
    float w[KNB]; float sum = 0.f;
    for (int kk = 0; kk < KNB; kk++) { w[kk] = expf(logit_s[kk][c] - mx); sum += w[kk]; }
    float inv = 1.f / sum;
    for (int kk = 0; kk < KNB; kk++) attw_s[kk][c] = w[kk] * inv;
  }
  __syncthreads();
  if (c < NH*EDIM) {
    int hh = c / EDIM, j = c % EDIM;
    float acc = 0.f;
#pragma unroll
    for (int kk = 0; kk < KNB; kk++) acc += attw_s[kk][hh] * e_s[kk*EDIM + j];
    ew_s[hh][j] = acc;
  }
  __syncthreads();
  float vg = bvc;
#pragma unroll
  for (int kk = 0; kk < KNB; kk++) vg += attw_s[kk][h] * pvs[kk];
  float o = vg;
#pragma unroll
  for (int j = 0; j < EDIM; j++) o += ew_s[h][j] * WvB[(size_t)j*QDIM + c];
  att[(size_t)n*QDIM + c] = (f16)o;
}

// ---------------- output head (f32 output) ----------------
__global__ __launch_bounds__(128) void head_kernel(const float* __restrict__ enc,
    const float* Ws, const float* bs, const float* Wc, const float* bc,
    const float* Wconc, const float* bconc, const float* Wwt, const float* bwt,
    const float* Wfac, const float* bfac, const float* __restrict__ angles, float* __restrict__ out) {
  int n = blockIdx.x, t = threadIdx.x;
  __shared__ float es[128];
  __shared__ float outs[103];
  es[t] = enc[(size_t)n*SDIM + t];
  __syncthreads();
  const float* W = nullptr; const float* bb = nullptr; int col = 0, nc = 0;
  if (t < 30)       { W = Ws;    bb = bs;    col = t;       nc = 30; }
  else if (t < 60)  { W = Wc;    bb = bc;    col = t - 30;  nc = 30; }
  else if (t < 90)  { W = Wconc; bb = bconc; col = t - 60;  nc = 30; }
  else if (t < 100) { W = Wwt;   bb = bwt;   col = t - 90;  nc = 10; }
  else if (t < 103) { W = Wfac;  bb = bfac;  col = t - 100; nc = 3;  }
  if (W) {
    float acc = bb[col];
    for (int j = 0; j < 128; j++) acc += es[j] * W[j*nc + col];
    outs[t] = acc;
  }
  __syncthreads();
  if (t < MIXN) {
    float mx = -1e30f;
    for (int m = 0; m < MIXN; m++) mx = fmaxf(mx, outs[90 + m]);
    float sum = 0.f;
    for (int m = 0; m < MIXN; m++) sum += expf(outs[90 + m] - mx);
    out[(size_t)n*MIXN + t] = expf(outs[90 + t] - mx) / sum;
  }
  if (t < 30) {
    int j = t / 10;
    float v = atan2f(outs[t], outs[30 + t]);
    float a0 = angles[n*3 + 0], a1 = angles[n*3 + 1];
    if (j == 1) v += outs[100] * a0;
    if (j == 2) v += outs[101] * a0 + outs[102] * a1;
    out[(size_t)NRES*MIXN + (size_t)n*30 + t] = v;
    float z = outs[60 + t];
    float sg = 1.f / (1.f + expf(-z));
    out[(size_t)NRES*MIXN + (size_t)NRES*30 + (size_t)n*30 + t] = 0.1f + 1000.f * sg;
  }
}

// ---------------- launch ----------------
extern "C" void kernel_launch(void* const* d_in, const int* in_sizes, int n_in,
                              void* d_out, int out_size, void* d_ws, size_t ws_size,
                              hipStream_t stream) {
  const float* angles   = (const float*)d_in[0];
  const float* tertiary = (const float*)d_in[1];
  const int*   structure = (const int*)d_in[2];
  // d_in[3] = subgraph (unused)
  const float* W_in  = (const float*)d_in[4];  const float* b_in  = (const float*)d_in[5];
  const float* W_pre = (const float*)d_in[6];  const float* b_pre = (const float*)d_in[7];
  const float* ln1_g = (const float*)d_in[8];  const float* ln1_b = (const float*)d_in[9];
  const float* ln2_g = (const float*)d_in[10]; const float* ln2_b = (const float*)d_in[11];
  const float* Wq = (const float*)d_in[12]; const float* bq = (const float*)d_in[13];
  const float* Wk = (const float*)d_in[14]; const float* bk = (const float*)d_in[15];
  const float* Wv = (const float*)d_in[16]; const float* bv = (const float*)d_in[17];
  const float* Wo = (const float*)d_in[18]; const float* bo = (const float*)d_in[19];
  const float* W1 = (const float*)d_in[20]; const float* b1 = (const float*)d_in[21];
  const float* W2 = (const float*)d_in[22]; const float* b2 = (const float*)d_in[23];
  const float* W3 = (const float*)d_in[24]; const float* b3 = (const float*)d_in[25];
  const float* Ws = (const float*)d_in[26]; const float* bs = (const float*)d_in[27];
  const float* Wc = (const float*)d_in[28]; const float* bc = (const float*)d_in[29];
  const float* Wconc = (const float*)d_in[30]; const float* bconc = (const float*)d_in[31];
  const float* Wwt = (const float*)d_in[32]; const float* bwt = (const float*)d_in[33];
  const float* Wfac = (const float*)d_in[34]; const float* bfac = (const float*)d_in[35];

  // workspace layout (bytes); high-water ~55.8 MB (<= 62.5 MB established safe)
  char* wsb = (char*)d_ws;
  float* pos   = (float*)(wsb + 0);           //    98,304 B
  float* Rm    = (float*)(wsb + 98304);       //   294,912 B
  f16*   edg_h = (f16*)  (wsb + 393216);      // 5,898,240 B
  float* x     = (float*)(wsb + 6291456);     // 4 MiB f32 residual
  f16*   nx_h  = (f16*)  (wsb + 10485760);    // 2 MiB
  f16*   att_h = (f16*)  (wsb + 12582912);    // 4 MiB
  f16*   qh    = (f16*)  (wsb + 16777216);    // 4 MiB  (q | pk | pv contiguous fp16)
  f16*   pkh   = (f16*)  (wsb + 20971520);    // 4 MiB
  f16*   pvh   = (f16*)  (wsb + 25165824);    // 4 MiB -> ends 29,360,128
  f16*   h1h   = (f16*)  (wsb + 29360128);    // 8 MiB
  f16*   h2h   = (f16*)  (wsb + 37748736);    // 8 MiB -> ends 46,137,344
  f16*   qkvw  = (f16*)  (wsb + 46137344);    //   589,824 B (3 x 128x768)
  f16*   w1w   = (f16*)  (wsb + 46727168);    //   393,216 B
  f16*   w2w   = (f16*)  (wsb + 47120384);    // 1,572,864 B
  f16*   w3w   = (f16*)  (wsb + 48693248);    //   393,216 B
  f16*   wow   = (f16*)  (wsb + 49086464);    //   196,608 B
  float* b768  = (float*)(wsb + 49283072);    //     9,216 B
  float* qWb   = (float*)(wsb + 49292288);    // 6,553,600 B -> ends 55,845,888

  pos_kernel<<<dim3((NRES+255)/256), dim3(256), 0, stream>>>(tertiary, pos);
  frames_kernel<<<dim3((NRES+255)/256), dim3(256), 0, stream>>>(pos, Rm);
  edges_kernel<<<dim3((NRES*KNB+255)/256), dim3(256), 0, stream>>>(pos, Rm, structure, edg_h);
  init_kernel<<<dim3(NRES), dim3(128), 0, stream>>>(angles, W_in, b_in, W_pre, b_pre, x);

  // one-time weight conversions to fp16 frag-swizzled layouts (all 3 layers each)
  convswz_kernel<<<dim3(64,3), 256, 0, stream>>>(Wq, SDIM*QDIM, QDIM, 128, 256, qkvw, 98304, 768, 0);
  convswz_kernel<<<dim3(64,3), 256, 0, stream>>>(Wk, (SDIM+EDIM)*QDIM, QDIM, 128, 256, qkvw, 98304, 768, 256);
  convswz_kernel<<<dim3(64,3), 256, 0, stream>>>(Wv, (SDIM+EDIM)*QDIM, QDIM, 128, 256, qkvw, 98304, 768, 512);
  convswz_kernel<<<dim3(64,3), 256, 0, stream>>>(W1, SDIM*HIDD, HIDD, 128, 512, w1w, 65536, 512, 0);
  convswz_kernel<<<dim3(64,3), 256, 0, stream>>>(W2, HIDD*HIDD, HIDD, 512, 512, w2w, 262144, 512, 0);
  convswz_kernel<<<dim3(64,3), 256, 0, stream>>>(W3, HIDD*SDIM, SDIM, 512, 128, w3w, 65536, 128, 0);
  convswz_kernel<<<dim3(64,3), 256, 0, stream>>>(Wo, QDIM*SDIM, SDIM, 256, 128, wow, 32768, 128, 0);
  bias768_kernel<<<9, 256, 0, stream>>>(bq, b768);

  for (int d = 0; d < 3; ++d) {
    const float* WkD = Wk + (size_t)d*(SDIM+EDIM)*QDIM;
    const float* WvD = Wv + (size_t)d*(SDIM+EDIM)*QDIM;
    ln_kernel<<<dim3(NRES), dim3(128), 0, stream>>>(x, ln1_g + d*SDIM, ln1_b + d*SDIM, nx_h);
    // fused q|pk|pv GEMM: Nd=768 -> fp16 split store into qh/pkh/pvh (bias only on q part)
    gemm_mfma<3><<<768, 256, 0, stream>>>(nx_h, qkvw + (size_t)d*98304, b768 + d*768, qh, 128, 768);
    qw_kernel<<<dim3(NRES), dim3(256), 0, stream>>>(
        qh, WkD + (size_t)SDIM*QDIM, bk + d*QDIM, qWb);
    attn_kernel<<<dim3(NRES), dim3(256), 0, stream>>>(qh, pkh, pvh, edg_h, structure,
        qWb, WvD + (size_t)SDIM*QDIM, bv + d*QDIM, att_h);
    gemm_mfma<2><<<128, 256, 0, stream>>>(att_h, wow + (size_t)d*32768, bo + d*SDIM, x, 256, 128);
    ln_kernel<<<dim3(NRES), dim3(128), 0, stream>>>(x, ln2_g + d*SDIM, ln2_b + d*SDIM, nx_h);
    gemm_mfma<1><<<512, 256, 0, stream>>>(nx_h, w1w + (size_t)d*65536, b1 + d*HIDD, h1h, 128, 512);
    gemm_mfma<1><<<512, 256, 0, stream>>>(h1h, w2w + (size_t)d*262144, b2 + d*HIDD, h2h, 512, 512);
    gemm_mfma<2><<<128, 256, 0, stream>>>(h2h, w3w + (size_t)d*65536, b3 + d*SDIM, x, 512, 128);
  }

  head_kernel<<<dim3(NRES), dim3(128), 0, stream>>>(x, Ws, bs, Wc, bc, Wconc, bconc,
      Wwt, bwt, Wfac, bfac, angles, (float*)d_out);
}

// Round 10
// 618.038 us; speedup vs baseline: 1.1412x; 1.0454x over previous
//
#include <hip/hip_runtime.h>
#include <hip/hip_bf16.h>
#include <stdint.h>

// Problem constants
#define NRES 8192
#define KNB  15
#define SDIM 128
#define EDIM 24
#define HIDD 512
#define NH   8
#define QDIM 256   // H*A
#define MIXN 10

typedef _Float16 f16;
typedef _Float16 f16x8 __attribute__((ext_vector_type(8)));
typedef _Float16 f16x2 __attribute__((ext_vector_type(2)));
typedef float f32x4 __attribute__((ext_vector_type(4)));

#if __has_builtin(__builtin_amdgcn_fdot2)
#define FDOT2(a,b,c) __builtin_amdgcn_fdot2((a),(b),(c),false)
#else
#define FDOT2(a,b,c) ((c) + (float)(a).x*(float)(b).x + (float)(a).y*(float)(b).y)
#endif

struct F3 { float x, y, z; };
__device__ __forceinline__ F3 f3sub(F3 a, F3 b) { return {a.x-b.x, a.y-b.y, a.z-b.z}; }
__device__ __forceinline__ F3 f3cross(F3 a, F3 b) {
  return {a.y*b.z - a.z*b.y, a.z*b.x - a.x*b.z, a.x*b.y - a.y*b.x};
}
__device__ __forceinline__ F3 f3norm(F3 a) {
  float l = sqrtf(a.x*a.x + a.y*a.y + a.z*a.z) + 1e-8f;
  float r = 1.f / l;
  return {a.x*r, a.y*r, a.z*r};
}
__device__ __forceinline__ F3 ldpos(const float* p, int i) { return {p[i*3], p[i*3+1], p[i*3+2]}; }

// ---------------- geometry ----------------
__global__ void pos_kernel(const float* __restrict__ tert, float* __restrict__ pos) {
  int n = blockIdx.x * blockDim.x + threadIdx.x;
  if (n >= NRES) return;
  pos[n*3+0] = tert[n*9+3];
  pos[n*3+1] = tert[n*9+4];
  pos[n*3+2] = tert[n*9+5];
}

__global__ void frames_kernel(const float* __restrict__ pos, float* __restrict__ R) {
  int m = blockIdx.x * blockDim.x + threadIdx.x;
  if (m >= NRES) return;
  int s = m - 1; if (s < 0) s = 0; if (s > NRES-3) s = NRES-3;
  F3 p0 = ldpos(pos, s), p1 = ldpos(pos, s+1), p2 = ldpos(pos, s+2);
  F3 u0 = f3norm(f3sub(p1, p0));
  F3 u1 = f3norm(f3sub(p2, p1));
  F3 b  = f3norm(f3sub(u0, u1));
  F3 nn = f3norm(f3cross(u0, u1));
  F3 o  = f3cross(b, nn);
  float* r = R + m*9;
  r[0]=b.x; r[1]=nn.x; r[2]=o.x;
  r[3]=b.y; r[4]=nn.y; r[5]=o.y;
  r[6]=b.z; r[7]=nn.z; r[8]=o.z;
}

__device__ __forceinline__ float quat_comp(float t, float a, float b) {
  float s = (a > b) ? 1.f : ((a < b) ? -1.f : 0.f);
  return 0.5f * sqrtf(fmaxf(1e-8f, t)) * s;
}

__global__ void edges_kernel(const float* __restrict__ pos, const float* __restrict__ R,
                             const int* __restrict__ structure, f16* __restrict__ edges) {
  int id = blockIdx.x * blockDim.x + threadIdx.x;
  if (id >= NRES*KNB) return;
  int n = id / KNB;
  int tprev = (n - 1) & (NRES - 1);
  int sidx = structure[id];
  F3 pt = ldpos(pos, tprev), ps = ldpos(pos, sidx);
  F3 dv = f3sub(ps, pt);
  float dist = sqrtf(dv.x*dv.x + dv.y*dv.y + dv.z*dv.z);
  float rinv = 1.f / (dist + 1e-8f);
  F3 dh = {dv.x*rinv, dv.y*rinv, dv.z*rinv};
  float Rt[9], Rs[9];
#pragma unroll
  for (int i = 0; i < 9; i++) { Rt[i] = R[tprev*9+i]; Rs[i] = R[sidx*9+i]; }
  float dir[3];
#pragma unroll
  for (int i = 0; i < 3; i++) dir[i] = Rt[i]*dh.x + Rt[3+i]*dh.y + Rt[6+i]*dh.z;
  float Rr[9];
#pragma unroll
  for (int i = 0; i < 3; i++)
#pragma unroll
    for (int l = 0; l < 3; l++)
      Rr[i*3+l] = Rt[i]*Rs[l] + Rt[3+i]*Rs[3+l] + Rt[6+i]*Rs[6+l];
  float m00 = Rr[0], m11 = Rr[4], m22 = Rr[8];
  float qw = 0.5f * sqrtf(fmaxf(1e-8f, 1.f + m00 + m11 + m22));
  float qx = quat_comp(1.f + m00 - m11 - m22, Rr[7], Rr[5]);
  float qy = quat_comp(1.f - m00 + m11 - m22, Rr[2], Rr[6]);
  float qz = quat_comp(1.f - m00 - m11 + m22, Rr[3], Rr[1]);
  f16* e = edges + (size_t)id * EDIM;
#pragma unroll
  for (int j = 0; j < 16; j++) {
    float mu = (20.f / 15.f) * j;            // linspace(0,20,16)
    float zz = (dist - mu) * (1.f / 1.25f);  // sigma = 20/16
    e[j] = (f16)expf(-zz*zz);
  }
  e[16] = (f16)dir[0]; e[17] = (f16)dir[1]; e[18] = (f16)dir[2];
  e[19] = (f16)qw; e[20] = (f16)qx; e[21] = (f16)qy; e[22] = (f16)qz;
  e[23] = (f16)((float)(sidx - tprev) * 0.01f);
}

// ---------------- input embedding ----------------
__global__ __launch_bounds__(128) void init_kernel(const float* __restrict__ angles,
    const float* __restrict__ W_in, const float* __restrict__ b_in,
    const float* __restrict__ W_pre, const float* __restrict__ b_pre, float* __restrict__ x) {
  int n = blockIdx.x, c = threadIdx.x;
  __shared__ float fs[128];
  float af[6];
  if (n == 0) { af[0]=af[1]=af[2]=0.f; af[3]=af[4]=af[5]=1.f; }
  else {
#pragma unroll
    for (int j = 0; j < 3; j++) {
      float p = angles[(n-1)*3 + j];
      af[j] = sinf(p); af[3+j] = cosf(p);
    }
  }
  float f = b_in[c];
#pragma unroll
  for (int j = 0; j < 6; j++) f += af[j] * W_in[j*SDIM + c];
  fs[c] = f;
  __syncthreads();
  float xv = b_pre[c];
  for (int j = 0; j < 128; j++) xv += fs[j] * W_pre[j*SDIM + c];
  x[(size_t)n*SDIM + c] = xv;
}

// ---------------- layernorm: f32 in -> fp16 out (GEMM A-operand) ----------------
__global__ __launch_bounds__(128) void ln_kernel(const float* __restrict__ x,
    const float* __restrict__ g, const float* __restrict__ b, f16* __restrict__ out) {
  int n = blockIdx.x, c = threadIdx.x;
  float v = x[(size_t)n*SDIM + c];
  float s = v;
#pragma unroll
  for (int m = 32; m >= 1; m >>= 1) s += __shfl_xor(s, m, 64);
  __shared__ float p1[2], p2[2];
  if ((c & 63) == 0) p1[c >> 6] = s;
  __syncthreads();
  float mean = (p1[0] + p1[1]) * (1.f/128.f);
  float d = v - mean;
  float s2 = d * d;
#pragma unroll
  for (int m = 32; m >= 1; m >>= 1) s2 += __shfl_xor(s2, m, 64);
  if ((c & 63) == 0) p2[c >> 6] = s2;
  __syncthreads();
  float var = (p2[0] + p2[1]) * (1.f/128.f);
  out[(size_t)n*SDIM + c] = (f16)(d * rsqrtf(var + 1e-5f) * g[c] + b[c]);
}

// ---------------- weight convert+swizzle: f32 [K][N] -> fp16 frag layout ----------------
__global__ void convswz_kernel(const float* __restrict__ src, int srcLayerStride, int srcLd,
    int K, int N, f16* __restrict__ dst, int dstLayerHalves, int dstN, int colOff) {
  int d = blockIdx.y;
  const float* s = src + (size_t)d * srcLayerStride;
  f16* o = dst + (size_t)d * dstLayerHalves;
  for (int i = blockIdx.x*blockDim.x + threadIdx.x; i < K*N; i += gridDim.x*blockDim.x) {
    int k = i / N, n = i - k*N;
    o[((size_t)(k>>3)*dstN + colOff + n)*8 + (k&7)] = (f16)s[(size_t)k*srcLd + n];
  }
}

__global__ void bias768_kernel(const float* __restrict__ bq, float* __restrict__ out) {
  int i = blockIdx.x*blockDim.x + threadIdx.x;
  if (i >= 3*768) return;
  int d = i / 768, col = i - d*768;
  out[i] = (col < 256) ? bq[d*QDIM + col] : 0.f;
}

// ---------------- MFMA GEMM 32x64 wave tile ----------------
// MODE 1: fp16 C = relu(AB+bias) ; MODE 3: fp16 qkv-split store (Nd=768)
template<int MODE>
__global__ __launch_bounds__(256) void gemm_mfma(const f16* __restrict__ A,
    const f16* __restrict__ Bsw, const float* __restrict__ bias,
    void* __restrict__ Cv, int Kd, int Nd) {
  int w = blockIdx.x * 4 + (threadIdx.x >> 6);
  int lane = threadIdx.x & 63;
  int wm = w & 255, wn = w >> 8;
  int m0 = wm * 32, n0 = wn * 64;
  int r16 = lane & 15, qd = lane >> 4;
  f32x4 acc[2][4] = {};
  const f16* aBase = A + (size_t)(m0 + r16)*Kd + qd*8;
  for (int kc = 0; kc < Kd; kc += 32) {
    f16x8 af0 = *(const f16x8*)(aBase + kc);
    f16x8 af1 = *(const f16x8*)(aBase + (size_t)16*Kd + kc);
    const f16* bBase = Bsw + ((size_t)((kc>>3) + qd)*Nd + n0 + r16)*8;
    f16x8 bf[4];
#pragma unroll
    for (int nt = 0; nt < 4; nt++) bf[nt] = *(const f16x8*)(bBase + nt*16*8);
#pragma unroll
    for (int nt = 0; nt < 4; nt++) {
      acc[0][nt] = __builtin_amdgcn_mfma_f32_16x16x32_f16(af0, bf[nt], acc[0][nt], 0, 0, 0);
      acc[1][nt] = __builtin_amdgcn_mfma_f32_16x16x32_f16(af1, bf[nt], acc[1][nt], 0, 0, 0);
    }
  }
#pragma unroll
  for (int mt = 0; mt < 2; mt++) {
#pragma unroll
    for (int nt = 0; nt < 4; nt++) {
      int col = n0 + nt*16 + r16;
      float bj = bias ? bias[col] : 0.f;
#pragma unroll
      for (int r = 0; r < 4; r++) {
        int row = m0 + mt*16 + qd*4 + r;
        float v = acc[mt][nt][r] + bj;
        if (MODE == 1) {
          ((f16*)Cv)[(size_t)row*Nd + col] = (f16)fmaxf(v, 0.f);
        } else {  // MODE 3
          int third = col >> 8, cl = col & 255;
          ((f16*)Cv)[(size_t)third*NRES*QDIM + (size_t)row*QDIM + cl] = (f16)v;
        }
      }
    }
  }
}

// ---------------- MFMA GEMM 16x64 wave tile, f32 C += AB + bias (Wo / W3, N=128) ----------------
__global__ __launch_bounds__(256) void gemm_mfma16(const f16* __restrict__ A,
    const f16* __restrict__ Bsw, const float* __restrict__ bias,
    float* __restrict__ C, int Kd, int Nd) {
  int w = blockIdx.x * 4 + (threadIdx.x >> 6);
  int lane = threadIdx.x & 63;
  int wm = w & 511, wn = w >> 9;       // 512 m-tiles of 16 rows
  int m0 = wm * 16, n0 = wn * 64;
  int r16 = lane & 15, qd = lane >> 4;
  f32x4 acc[4] = {};
  const f16* aBase = A + (size_t)(m0 + r16)*Kd + qd*8;
  for (int kc = 0; kc < Kd; kc += 32) {
    f16x8 af = *(const f16x8*)(aBase + kc);
    const f16* bBase = Bsw + ((size_t)((kc>>3) + qd)*Nd + n0 + r16)*8;
#pragma unroll
    for (int nt = 0; nt < 4; nt++) {
      f16x8 bf = *(const f16x8*)(bBase + nt*16*8);
      acc[nt] = __builtin_amdgcn_mfma_f32_16x16x32_f16(af, bf, acc[nt], 0, 0, 0);
    }
  }
#pragma unroll
  for (int nt = 0; nt < 4; nt++) {
    int col = n0 + nt*16 + r16;
    float bj = bias[col];
#pragma unroll
    for (int r = 0; r < 4; r++) {
      int row = m0 + qd*4 + r;
      C[(size_t)row*Nd + col] += acc[nt][r] + bj;
    }
  }
}

// ---------------- qW precompute ----------------
__global__ __launch_bounds__(256) void qw_kernel(const f16* __restrict__ q,
    const float* __restrict__ WkB, const float* __restrict__ bk, float* __restrict__ qW) {
  int n = blockIdx.x, t = threadIdx.x;
  if (t >= NH*25) return;
  int h = t / 25, jj = t % 25;
  const f16*   qr = q + (size_t)n*QDIM + h*32;
  const float* wr = (jj < 24) ? (WkB + (size_t)jj*QDIM + h*32) : (bk + h*32);
  float acc = 0.f;
#pragma unroll
  for (int c2 = 0; c2 < 32; c2++) acc += (float)qr[c2] * wr[c2];
  qW[(size_t)n*(NH*25) + t] = acc;
}

// ---------------- fused attention: 2 nodes/block, f16x2 channel pairs, 128 lanes/node ----------------
__global__ __launch_bounds__(256) void attn_kernel(const f16* __restrict__ q,
    const f16* __restrict__ pk, const f16* __restrict__ pv,
    const f16* __restrict__ edges, const int* __restrict__ structure,
    const float* __restrict__ qW, const float* __restrict__ WvB,
    const float* __restrict__ bv, f16* __restrict__ att) {
  int t = threadIdx.x;
  int half = t >> 7;            // which node within block
  int lt = t & 127;             // channel-pair index p: channels 2p, 2p+1
  int n = blockIdx.x*2 + half;
  __shared__ float e_s[2][KNB*EDIM];
  __shared__ float qw_s[2][NH*25];
  __shared__ float logit_s[2][KNB][NH];
  __shared__ float attw_s[2][KNB][NH];
  __shared__ float ew_s[2][NH][EDIM];

  int s[KNB];
#pragma unroll
  for (int kk = 0; kk < KNB; kk++) s[kk] = structure[n*KNB + kk];
  const f16x2* pk2 = (const f16x2*)pk;
  const f16x2* pv2 = (const f16x2*)pv;
  f16x2 pks[KNB], pvs[KNB];
#pragma unroll
  for (int kk = 0; kk < KNB; kk++) pks[kk] = pk2[(size_t)s[kk]*128 + lt];
#pragma unroll
  for (int kk = 0; kk < KNB; kk++) pvs[kk] = pv2[(size_t)s[kk]*128 + lt];
  f16x2 q2 = ((const f16x2*)q)[(size_t)n*128 + lt];
  float2 bv2 = ((const float2*)bv)[lt];
  for (int i = lt; i < KNB*EDIM; i += 128) e_s[half][i] = (float)edges[(size_t)n*KNB*EDIM + i];
  for (int i = lt; i < NH*25;    i += 128) qw_s[half][i] = qW[(size_t)n*(NH*25) + i];

  int h = lt >> 4;   // head 0..7 (4 heads per wave, 16 contiguous lanes each)
  // gather-dot logits: f16x2 dot + 4-stage 16-lane reduction
#pragma unroll
  for (int kk = 0; kk < KNB; kk++) {
    float p = FDOT2(q2, pks[kk], 0.f);
    p += __shfl_xor(p, 8, 64);
    p += __shfl_xor(p, 4, 64);
    p += __shfl_xor(p, 2, 64);
    p += __shfl_xor(p, 1, 64);
    if ((lt & 15) == 0) logit_s[half][kk][h] = p;
  }
  __syncthreads();
  if (lt < KNB*NH) {
    int kk = lt / NH, hh = lt % NH;
    float l = logit_s[half][kk][hh] + qw_s[half][hh*25 + 24];
    const float* qwr = &qw_s[half][hh*25];
    const float* er  = &e_s[half][kk*EDIM];
#pragma unroll
    for (int j = 0; j < EDIM; j++) l += qwr[j] * er[j];
    logit_s[half][kk][hh] = l * 0.17677669529663687f;  // 1/sqrt(32)
  }
  __syncthreads();
  if (lt < NH) {
    float mx = -1e30f;
    for (int kk = 0; kk < KNB; kk++) mx = fmaxf(mx, logit_s[half][kk][lt]);
    float w[KNB]; float sum = 0.f;
    for (int kk = 0; kk < KNB; kk++) { w[kk] = expf(logit_s[half][kk][lt] - mx); sum += w[kk]; }
    float inv = 1.f / sum;
    for (int kk = 0; kk < KNB; kk++) attw_s[half][kk][lt] = w[kk] * inv;
  }
  __syncthreads();
  for (int i = lt; i < NH*EDIM; i += 128) {
    int hh = i / EDIM, j = i % EDIM;
    float acc = 0.f;
#pragma unroll
    for (int kk = 0; kk < KNB; kk++) acc += attw_s[half][kk][hh] * e_s[half][kk*EDIM + j];
    ew_s[half][hh][j] = acc;
  }
  __syncthreads();
  float o0 = bv2.x, o1 = bv2.y;
#pragma unroll
  for (int kk = 0; kk < KNB; kk++) {
    float a = attw_s[half][kk][h];
    o0 += a * (float)pvs[kk].x;
    o1 += a * (float)pvs[kk].y;
  }
  const float2* wv2 = (const float2*)WvB;
#pragma unroll
  for (int j = 0; j < EDIM; j++) {
    float w = ew_s[half][h][j];
    float2 wv = wv2[(size_t)j*128 + lt];
    o0 += w * wv.x;
    o1 += w * wv.y;
  }
  f16x2 o; o.x = (f16)o0; o.y = (f16)o1;
  ((f16x2*)att)[(size_t)n*128 + lt] = o;
}

// ---------------- output head (f32 output) ----------------
__global__ __launch_bounds__(128) void head_kernel(const float* __restrict__ enc,
    const float* Ws, const float* bs, const float* Wc, const float* bc,
    const float* Wconc, const float* bconc, const float* Wwt, const float* bwt,
    const float* Wfac, const float* bfac, const float* __restrict__ angles, float* __restrict__ out) {
  int n = blockIdx.x, t = threadIdx.x;
  __shared__ float es[128];
  __shared__ float outs[103];
  es[t] = enc[(size_t)n*SDIM + t];
  __syncthreads();
  const float* W = nullptr; const float* bb = nullptr; int col = 0, nc = 0;
  if (t < 30)       { W = Ws;    bb = bs;    col = t;       nc = 30; }
  else if (t < 60)  { W = Wc;    bb = bc;    col = t - 30;  nc = 30; }
  else if (t < 90)  { W = Wconc; bb = bconc; col = t - 60;  nc = 30; }
  else if (t < 100) { W = Wwt;   bb = bwt;   col = t - 90;  nc = 10; }
  else if (t < 103) { W = Wfac;  bb = bfac;  col = t - 100; nc = 3;  }
  if (W) {
    float acc = bb[col];
    for (int j = 0; j < 128; j++) acc += es[j] * W[j*nc + col];
    outs[t] = acc;
  }
  __syncthreads();
  if (t < MIXN) {
    float mx = -1e30f;
    for (int m = 0; m < MIXN; m++) mx = fmaxf(mx, outs[90 + m]);
    float sum = 0.f;
    for (int m = 0; m < MIXN; m++) sum += expf(outs[90 + m] - mx);
    out[(size_t)n*MIXN + t] = expf(outs[90 + t] - mx) / sum;
  }
  if (t < 30) {
    int j = t / 10;
    float v = atan2f(outs[t], outs[30 + t]);
    float a0 = angles[n*3 + 0], a1 = angles[n*3 + 1];
    if (j == 1) v += outs[100] * a0;
    if (j == 2) v += outs[101] * a0 + outs[102] * a1;
    out[(size_t)NRES*MIXN + (size_t)n*30 + t] = v;
    float z = outs[60 + t];
    float sg = 1.f / (1.f + expf(-z));
    out[(size_t)NRES*MIXN + (size_t)NRES*30 + (size_t)n*30 + t] = 0.1f + 1000.f * sg;
  }
}

// ---------------- launch ----------------
extern "C" void kernel_launch(void* const* d_in, const int* in_sizes, int n_in,
                              void* d_out, int out_size, void* d_ws, size_t ws_size,
                              hipStream_t stream) {
  const float* angles   = (const float*)d_in[0];
  const float* tertiary = (const float*)d_in[1];
  const int*   structure = (const int*)d_in[2];
  const float* W_in  = (const float*)d_in[4];  const float* b_in  = (const float*)d_in[5];
  const float* W_pre = (const float*)d_in[6];  const float* b_pre = (const float*)d_in[7];
  const float* ln1_g = (const float*)d_in[8];  const float* ln1_b = (const float*)d_in[9];
  const float* ln2_g = (const float*)d_in[10]; const float* ln2_b = (const float*)d_in[11];
  const float* Wq = (const float*)d_in[12]; const float* bq = (const float*)d_in[13];
  const float* Wk = (const float*)d_in[14]; const float* bk = (const float*)d_in[15];
  const float* Wv = (const float*)d_in[16]; const float* bv = (const float*)d_in[17];
  const float* Wo = (const float*)d_in[18]; const float* bo = (const float*)d_in[19];
  const float* W1 = (const float*)d_in[20]; const float* b1 = (const float*)d_in[21];
  const float* W2 = (const float*)d_in[22]; const float* b2 = (const float*)d_in[23];
  const float* W3 = (const float*)d_in[24]; const float* b3 = (const float*)d_in[25];
  const float* Ws = (const float*)d_in[26]; const float* bs = (const float*)d_in[27];
  const float* Wc = (const float*)d_in[28]; const float* bc = (const float*)d_in[29];
  const float* Wconc = (const float*)d_in[30]; const float* bconc = (const float*)d_in[31];
  const float* Wwt = (const float*)d_in[32]; const float* bwt = (const float*)d_in[33];
  const float* Wfac = (const float*)d_in[34]; const float* bfac = (const float*)d_in[35];

  // workspace layout (bytes); high-water ~55.8 MB (<= 62.5 MB established safe)
  char* wsb = (char*)d_ws;
  float* pos   = (float*)(wsb + 0);
  float* Rm    = (float*)(wsb + 98304);
  f16*   edg_h = (f16*)  (wsb + 393216);      // 5,898,240 B
  float* x     = (float*)(wsb + 6291456);     // 4 MiB f32 residual
  f16*   nx_h  = (f16*)  (wsb + 10485760);    // 2 MiB
  f16*   att_h = (f16*)  (wsb + 12582912);    // 4 MiB
  f16*   qh    = (f16*)  (wsb + 16777216);    // 4 MiB
  f16*   pkh   = (f16*)  (wsb + 20971520);    // 4 MiB
  f16*   pvh   = (f16*)  (wsb + 25165824);    // 4 MiB
  f16*   h1h   = (f16*)  (wsb + 29360128);    // 8 MiB
  f16*   h2h   = (f16*)  (wsb + 37748736);    // 8 MiB
  f16*   qkvw  = (f16*)  (wsb + 46137344);
  f16*   w1w   = (f16*)  (wsb + 46727168);
  f16*   w2w   = (f16*)  (wsb + 47120384);
  f16*   w3w   = (f16*)  (wsb + 48693248);
  f16*   wow   = (f16*)  (wsb + 49086464);
  float* b768  = (float*)(wsb + 49283072);
  float* qWb   = (float*)(wsb + 49292288);    // 6,553,600 B -> ends 55,845,888

  pos_kernel<<<dim3((NRES+255)/256), dim3(256), 0, stream>>>(tertiary, pos);
  frames_kernel<<<dim3((NRES+255)/256), dim3(256), 0, stream>>>(pos, Rm);
  edges_kernel<<<dim3((NRES*KNB+255)/256), dim3(256), 0, stream>>>(pos, Rm, structure, edg_h);
  init_kernel<<<dim3(NRES), dim3(128), 0, stream>>>(angles, W_in, b_in, W_pre, b_pre, x);

  convswz_kernel<<<dim3(64,3), 256, 0, stream>>>(Wq, SDIM*QDIM, QDIM, 128, 256, qkvw, 98304, 768, 0);
  convswz_kernel<<<dim3(64,3), 256, 0, stream>>>(Wk, (SDIM+EDIM)*QDIM, QDIM, 128, 256, qkvw, 98304, 768, 256);
  convswz_kernel<<<dim3(64,3), 256, 0, stream>>>(Wv, (SDIM+EDIM)*QDIM, QDIM, 128, 256, qkvw, 98304, 768, 512);
  convswz_kernel<<<dim3(64,3), 256, 0, stream>>>(W1, SDIM*HIDD, HIDD, 128, 512, w1w, 65536, 512, 0);
  convswz_kernel<<<dim3(64,3), 256, 0, stream>>>(W2, HIDD*HIDD, HIDD, 512, 512, w2w, 262144, 512, 0);
  convswz_kernel<<<dim3(64,3), 256, 0, stream>>>(W3, HIDD*SDIM, SDIM, 512, 128, w3w, 65536, 128, 0);
  convswz_kernel<<<dim3(64,3), 256, 0, stream>>>(Wo, QDIM*SDIM, SDIM, 256, 128, wow, 32768, 128, 0);
  bias768_kernel<<<9, 256, 0, stream>>>(bq, b768);

  for (int d = 0; d < 3; ++d) {
    const float* WkD = Wk + (size_t)d*(SDIM+EDIM)*QDIM;
    const float* WvD = Wv + (size_t)d*(SDIM+EDIM)*QDIM;
    ln_kernel<<<dim3(NRES), dim3(128), 0, stream>>>(x, ln1_g + d*SDIM, ln1_b + d*SDIM, nx_h);
    gemm_mfma<3><<<768, 256, 0, stream>>>(nx_h, qkvw + (size_t)d*98304, b768 + d*768, qh, 128, 768);
    qw_kernel<<<dim3(NRES), dim3(256), 0, stream>>>(
        qh, WkD + (size_t)SDIM*QDIM, bk + d*QDIM, qWb);
    attn_kernel<<<dim3(NRES/2), dim3(256), 0, stream>>>(qh, pkh, pvh, edg_h, structure,
        qWb, WvD + (size_t)SDIM*QDIM, bv + d*QDIM, att_h);
    gemm_mfma16<<<256, 256, 0, stream>>>(att_h, wow + (size_t)d*32768, bo + d*SDIM, x, 256, 128);
    ln_kernel<<<dim3(NRES), dim3(128), 0, stream>>>(x, ln2_g + d*SDIM, ln2_b + d*SDIM, nx_h);
    gemm_mfma<1><<<512, 256, 0, stream>>>(nx_h, w1w + (size_t)d*65536, b1 + d*HIDD, h1h, 128, 512);
    gemm_mfma<1><<<512, 256, 0, stream>>>(h1h, w2w + (size_t)d*262144, b2 + d*HIDD, h2h, 512, 512);
    gemm_mfma16<<<256, 256, 0, stream>>>(h2h, w3w + (size_t)d*65536, b3 + d*SDIM, x, 512, 128);
  }

  head_kernel<<<dim3(NRES), dim3(128), 0, stream>>>(x, Ws, bs, Wc, bc, Wconc, bconc,
      Wwt, bwt, Wfac, bfac, angles, (float*)d_out);
}

// Round 11
// 519.392 us; speedup vs baseline: 1.3580x; 1.1899x over previous
//
#include <hip/hip_runtime.h>
#include <hip/hip_bf16.h>
#include <stdint.h>

// Problem constants
#define NRES 8192
#define KNB  15
#define SDIM 128
#define EDIM 24
#define HIDD 512
#define NH   8
#define QDIM 256   // H*A
#define MIXN 10

typedef _Float16 f16;
typedef _Float16 f16x8 __attribute__((ext_vector_type(8)));
typedef _Float16 f16x4 __attribute__((ext_vector_type(4)));
typedef _Float16 f16x2 __attribute__((ext_vector_type(2)));
typedef float f32x4 __attribute__((ext_vector_type(4)));

#if __has_builtin(__builtin_amdgcn_fdot2)
#define FDOT2(a,b,c) __builtin_amdgcn_fdot2((a),(b),(c),false)
#else
#define FDOT2(a,b,c) ((c) + (float)(a).x*(float)(b).x + (float)(a).y*(float)(b).y)
#endif

struct F3 { float x, y, z; };
__device__ __forceinline__ F3 f3sub(F3 a, F3 b) { return {a.x-b.x, a.y-b.y, a.z-b.z}; }
__device__ __forceinline__ F3 f3cross(F3 a, F3 b) {
  return {a.y*b.z - a.z*b.y, a.z*b.x - a.x*b.z, a.x*b.y - a.y*b.x};
}
__device__ __forceinline__ F3 f3norm(F3 a) {
  float l = sqrtf(a.x*a.x + a.y*a.y + a.z*a.z) + 1e-8f;
  float r = 1.f / l;
  return {a.x*r, a.y*r, a.z*r};
}
__device__ __forceinline__ F3 ldpos(const float* p, int i) { return {p[i*3], p[i*3+1], p[i*3+2]}; }

// ---------------- geometry ----------------
__global__ void pos_kernel(const float* __restrict__ tert, float* __restrict__ pos) {
  int n = blockIdx.x * blockDim.x + threadIdx.x;
  if (n >= NRES) return;
  pos[n*3+0] = tert[n*9+3];
  pos[n*3+1] = tert[n*9+4];
  pos[n*3+2] = tert[n*9+5];
}

__global__ void frames_kernel(const float* __restrict__ pos, float* __restrict__ R) {
  int m = blockIdx.x * blockDim.x + threadIdx.x;
  if (m >= NRES) return;
  int s = m - 1; if (s < 0) s = 0; if (s > NRES-3) s = NRES-3;
  F3 p0 = ldpos(pos, s), p1 = ldpos(pos, s+1), p2 = ldpos(pos, s+2);
  F3 u0 = f3norm(f3sub(p1, p0));
  F3 u1 = f3norm(f3sub(p2, p1));
  F3 b  = f3norm(f3sub(u0, u1));
  F3 nn = f3norm(f3cross(u0, u1));
  F3 o  = f3cross(b, nn);
  float* r = R + m*9;
  r[0]=b.x; r[1]=nn.x; r[2]=o.x;
  r[3]=b.y; r[4]=nn.y; r[5]=o.y;
  r[6]=b.z; r[7]=nn.z; r[8]=o.z;
}

__device__ __forceinline__ float quat_comp(float t, float a, float b) {
  float s = (a > b) ? 1.f : ((a < b) ? -1.f : 0.f);
  return 0.5f * sqrtf(fmaxf(1e-8f, t)) * s;
}

__global__ void edges_kernel(const float* __restrict__ pos, const float* __restrict__ R,
                             const int* __restrict__ structure, f16* __restrict__ edges) {
  int id = blockIdx.x * blockDim.x + threadIdx.x;
  if (id >= NRES*KNB) return;
  int n = id / KNB;
  int tprev = (n - 1) & (NRES - 1);
  int sidx = structure[id];
  F3 pt = ldpos(pos, tprev), ps = ldpos(pos, sidx);
  F3 dv = f3sub(ps, pt);
  float dist = sqrtf(dv.x*dv.x + dv.y*dv.y + dv.z*dv.z);
  float rinv = 1.f / (dist + 1e-8f);
  F3 dh = {dv.x*rinv, dv.y*rinv, dv.z*rinv};
  float Rt[9], Rs[9];
#pragma unroll
  for (int i = 0; i < 9; i++) { Rt[i] = R[tprev*9+i]; Rs[i] = R[sidx*9+i]; }
  float dir[3];
#pragma unroll
  for (int i = 0; i < 3; i++) dir[i] = Rt[i]*dh.x + Rt[3+i]*dh.y + Rt[6+i]*dh.z;
  float Rr[9];
#pragma unroll
  for (int i = 0; i < 3; i++)
#pragma unroll
    for (int l = 0; l < 3; l++)
      Rr[i*3+l] = Rt[i]*Rs[l] + Rt[3+i]*Rs[3+l] + Rt[6+i]*Rs[6+l];
  float m00 = Rr[0], m11 = Rr[4], m22 = Rr[8];
  float qw = 0.5f * sqrtf(fmaxf(1e-8f, 1.f + m00 + m11 + m22));
  float qx = quat_comp(1.f + m00 - m11 - m22, Rr[7], Rr[5]);
  float qy = quat_comp(1.f - m00 + m11 - m22, Rr[2], Rr[6]);
  float qz = quat_comp(1.f - m00 - m11 + m22, Rr[3], Rr[1]);
  f16* e = edges + (size_t)id * EDIM;
#pragma unroll
  for (int j = 0; j < 16; j++) {
    float mu = (20.f / 15.f) * j;            // linspace(0,20,16)
    float zz = (dist - mu) * (1.f / 1.25f);  // sigma = 20/16
    e[j] = (f16)expf(-zz*zz);
  }
  e[16] = (f16)dir[0]; e[17] = (f16)dir[1]; e[18] = (f16)dir[2];
  e[19] = (f16)qw; e[20] = (f16)qx; e[21] = (f16)qy; e[22] = (f16)qz;
  e[23] = (f16)((float)(sidx - tprev) * 0.01f);
}

// ---------------- input embedding ----------------
__global__ __launch_bounds__(128) void init_kernel(const float* __restrict__ angles,
    const float* __restrict__ W_in, const float* __restrict__ b_in,
    const float* __restrict__ W_pre, const float* __restrict__ b_pre, float* __restrict__ x) {
  int n = blockIdx.x, c = threadIdx.x;
  __shared__ float fs[128];
  float af[6];
  if (n == 0) { af[0]=af[1]=af[2]=0.f; af[3]=af[4]=af[5]=1.f; }
  else {
#pragma unroll
    for (int j = 0; j < 3; j++) {
      float p = angles[(n-1)*3 + j];
      af[j] = sinf(p); af[3+j] = cosf(p);
    }
  }
  float f = b_in[c];
#pragma unroll
  for (int j = 0; j < 6; j++) f += af[j] * W_in[j*SDIM + c];
  fs[c] = f;
  __syncthreads();
  float xv = b_pre[c];
  for (int j = 0; j < 128; j++) xv += fs[j] * W_pre[j*SDIM + c];
  x[(size_t)n*SDIM + c] = xv;
}

// ---------------- layernorm: f32 in -> fp16 out (GEMM A-operand) ----------------
__global__ __launch_bounds__(128) void ln_kernel(const float* __restrict__ x,
    const float* __restrict__ g, const float* __restrict__ b, f16* __restrict__ out) {
  int n = blockIdx.x, c = threadIdx.x;
  float v = x[(size_t)n*SDIM + c];
  float s = v;
#pragma unroll
  for (int m = 32; m >= 1; m >>= 1) s += __shfl_xor(s, m, 64);
  __shared__ float p1[2], p2[2];
  if ((c & 63) == 0) p1[c >> 6] = s;
  __syncthreads();
  float mean = (p1[0] + p1[1]) * (1.f/128.f);
  float d = v - mean;
  float s2 = d * d;
#pragma unroll
  for (int m = 32; m >= 1; m >>= 1) s2 += __shfl_xor(s2, m, 64);
  if ((c & 63) == 0) p2[c >> 6] = s2;
  __syncthreads();
  float var = (p2[0] + p2[1]) * (1.f/128.f);
  out[(size_t)n*SDIM + c] = (f16)(d * rsqrtf(var + 1e-5f) * g[c] + b[c]);
}

// ---------------- weight convert+swizzle: f32 [K][N] -> fp16 frag layout ----------------
__global__ void convswz_kernel(const float* __restrict__ src, int srcLayerStride, int srcLd,
    int K, int N, f16* __restrict__ dst, int dstLayerHalves, int dstN, int colOff) {
  int d = blockIdx.y;
  const float* s = src + (size_t)d * srcLayerStride;
  f16* o = dst + (size_t)d * dstLayerHalves;
  for (int i = blockIdx.x*blockDim.x + threadIdx.x; i < K*N; i += gridDim.x*blockDim.x) {
    int k = i / N, n = i - k*N;
    o[((size_t)(k>>3)*dstN + colOff + n)*8 + (k&7)] = (f16)s[(size_t)k*srcLd + n];
  }
}

// dense per-head-masked qW weight: cols h*25+jj (jj<24 -> WkB[jj], jj==24 -> bk), zero outside head
__global__ void wqdense_kernel(const float* __restrict__ Wk, const float* __restrict__ bk,
                               f16* __restrict__ dst) {
  int idx = blockIdx.x*blockDim.x + threadIdx.x;
  if (idx >= 3*256*256) return;
  int d = idx >> 16, r = (idx >> 8) & 255, col = idx & 255;  // r = input channel
  float v = 0.f;
  if (col < 200) {
    int h = col / 25, jj = col % 25;
    if ((r >> 5) == h) {
      const float* WkB = Wk + (size_t)d*(SDIM+EDIM)*QDIM + (size_t)SDIM*QDIM;
      v = (jj < 24) ? WkB[(size_t)jj*QDIM + r] : bk[d*QDIM + r];
    }
  }
  dst[(size_t)d*65536 + ((size_t)(r>>3)*256 + col)*8 + (r&7)] = (f16)v;
}

__global__ void bias768_kernel(const float* __restrict__ bq, float* __restrict__ out) {
  int i = blockIdx.x*blockDim.x + threadIdx.x;
  if (i >= 3*768) return;
  int d = i / 768, col = i - d*768;
  out[i] = (col < 256) ? bq[d*QDIM + col] : 0.f;
}

// ---------------- MFMA GEMM 32x64 wave tile ----------------
// MODE 1: fp16 C = relu(AB+bias) ; MODE 3: fp16 qkv-split store (Nd=768) ; MODE 4: f32 C = AB
template<int MODE>
__global__ __launch_bounds__(256) void gemm_mfma(const f16* __restrict__ A,
    const f16* __restrict__ Bsw, const float* __restrict__ bias,
    void* __restrict__ Cv, int Kd, int Nd) {
  int w = blockIdx.x * 4 + (threadIdx.x >> 6);
  int lane = threadIdx.x & 63;
  int wm = w & 255, wn = w >> 8;
  int m0 = wm * 32, n0 = wn * 64;
  int r16 = lane & 15, qd = lane >> 4;
  f32x4 acc[2][4] = {};
  const f16* aBase = A + (size_t)(m0 + r16)*Kd + qd*8;
  for (int kc = 0; kc < Kd; kc += 32) {
    f16x8 af0 = *(const f16x8*)(aBase + kc);
    f16x8 af1 = *(const f16x8*)(aBase + (size_t)16*Kd + kc);
    const f16* bBase = Bsw + ((size_t)((kc>>3) + qd)*Nd + n0 + r16)*8;
    f16x8 bf[4];
#pragma unroll
    for (int nt = 0; nt < 4; nt++) bf[nt] = *(const f16x8*)(bBase + nt*16*8);
#pragma unroll
    for (int nt = 0; nt < 4; nt++) {
      acc[0][nt] = __builtin_amdgcn_mfma_f32_16x16x32_f16(af0, bf[nt], acc[0][nt], 0, 0, 0);
      acc[1][nt] = __builtin_amdgcn_mfma_f32_16x16x32_f16(af1, bf[nt], acc[1][nt], 0, 0, 0);
    }
  }
#pragma unroll
  for (int mt = 0; mt < 2; mt++) {
#pragma unroll
    for (int nt = 0; nt < 4; nt++) {
      int col = n0 + nt*16 + r16;
      float bj = bias ? bias[col] : 0.f;
#pragma unroll
      for (int r = 0; r < 4; r++) {
        int row = m0 + mt*16 + qd*4 + r;
        float v = acc[mt][nt][r] + bj;
        if (MODE == 1) {
          ((f16*)Cv)[(size_t)row*Nd + col] = (f16)fmaxf(v, 0.f);
        } else if (MODE == 4) {
          ((float*)Cv)[(size_t)row*Nd + col] = v;
        } else {  // MODE 3
          int third = col >> 8, cl = col & 255;
          ((f16*)Cv)[(size_t)third*NRES*QDIM + (size_t)row*QDIM + cl] = (f16)v;
        }
      }
    }
  }
}

// ---------------- MFMA GEMM 16x64 wave tile, f32 C += AB + bias (Wo / W3, N=128) ----------------
__global__ __launch_bounds__(256) void gemm_mfma16(const f16* __restrict__ A,
    const f16* __restrict__ Bsw, const float* __restrict__ bias,
    float* __restrict__ C, int Kd, int Nd) {
  int w = blockIdx.x * 4 + (threadIdx.x >> 6);
  int lane = threadIdx.x & 63;
  int wm = w & 511, wn = w >> 9;
  int m0 = wm * 16, n0 = wn * 64;
  int r16 = lane & 15, qd = lane >> 4;
  f32x4 acc[4] = {};
  const f16* aBase = A + (size_t)(m0 + r16)*Kd + qd*8;
  for (int kc = 0; kc < Kd; kc += 32) {
    f16x8 af = *(const f16x8*)(aBase + kc);
    const f16* bBase = Bsw + ((size_t)((kc>>3) + qd)*Nd + n0 + r16)*8;
#pragma unroll
    for (int nt = 0; nt < 4; nt++) {
      f16x8 bf = *(const f16x8*)(bBase + nt*16*8);
      acc[nt] = __builtin_amdgcn_mfma_f32_16x16x32_f16(af, bf, acc[nt], 0, 0, 0);
    }
  }
#pragma unroll
  for (int nt = 0; nt < 4; nt++) {
    int col = n0 + nt*16 + r16;
    float bj = bias[col];
#pragma unroll
    for (int r = 0; r < 4; r++) {
      int row = m0 + qd*4 + r;
      C[(size_t)row*Nd + col] += acc[nt][r] + bj;
    }
  }
}

// ---------------- fused attention: ONE WAVE PER NODE, barrier-free ----------------
// lane l: channels 4l..4l+3 (f16x4); head h = l>>3 (8 lanes/head); i = l&7.
// All reductions via shfl butterflies; softmax computed redundantly in all 8 lanes of a head.
__global__ __launch_bounds__(256) void attn_kernel(const f16* __restrict__ q,
    const f16* __restrict__ pk, const f16* __restrict__ pv,
    const f16* __restrict__ edges, const int* __restrict__ structure,
    const float* __restrict__ qW, const float* __restrict__ WvB,
    const float* __restrict__ bv, f16* __restrict__ att) {
  int t = threadIdx.x;
  int n = blockIdx.x*4 + (t >> 6);
  int lane = t & 63;
  int h = lane >> 3, i = lane & 7, base = h << 3;

  int s[KNB];
#pragma unroll
  for (int kk = 0; kk < KNB; kk++) s[kk] = structure[n*KNB + kk];
  const f16x4* pk4 = (const f16x4*)pk;   // row stride 64 (256 ch / 4)
  const f16x4* pv4 = (const f16x4*)pv;
  f16x4 pks[KNB], pvs[KNB];
#pragma unroll
  for (int kk = 0; kk < KNB; kk++) pks[kk] = pk4[(size_t)s[kk]*64 + lane];
#pragma unroll
  for (int kk = 0; kk < KNB; kk++) pvs[kk] = pv4[(size_t)s[kk]*64 + lane];
  f16x4 q4 = ((const f16x4*)q)[(size_t)n*64 + lane];

  // edge-logit partials: this lane handles kkA = i and kkB = i+8 (if valid)
  const float* qwr = qW + (size_t)n*256 + h*25;
  float qbias = qwr[24];
  float elA = qbias, elB = qbias;
  {
    const f16x2* eA = (const f16x2*)(edges + (size_t)n*KNB*EDIM + i*EDIM);
#pragma unroll
    for (int j2 = 0; j2 < 12; j2++) {
      f16x2 e2 = eA[j2];
      elA += qwr[2*j2]*(float)e2.x + qwr[2*j2+1]*(float)e2.y;
    }
  }
  if (i < 7) {
    const f16x2* eB = (const f16x2*)(edges + (size_t)n*KNB*EDIM + (i+8)*EDIM);
#pragma unroll
    for (int j2 = 0; j2 < 12; j2++) {
      f16x2 e2 = eB[j2];
      elB += qwr[2*j2]*(float)e2.x + qwr[2*j2+1]*(float)e2.y;
    }
  }

  // dot logits: fdot2 x2 + 3-stage butterfly over the 8 lanes of the head
  float dot[KNB];
  f16x2 qlo; qlo.x = q4.x; qlo.y = q4.y;
  f16x2 qhi; qhi.x = q4.z; qhi.y = q4.w;
#pragma unroll
  for (int kk = 0; kk < KNB; kk++) {
    f16x2 plo; plo.x = pks[kk].x; plo.y = pks[kk].y;
    f16x2 phi; phi.x = pks[kk].z; phi.y = pks[kk].w;
    float p = FDOT2(qlo, plo, 0.f);
    p = FDOT2(qhi, phi, p);
    p += __shfl_xor(p, 4, 64);
    p += __shfl_xor(p, 2, 64);
    p += __shfl_xor(p, 1, 64);
    dot[kk] = p;   // full 32-ch dot present in all 8 lanes of the head
  }

  // combine with broadcast edge terms, scale
  float logit[KNB];
#pragma unroll
  for (int kk = 0; kk < 8; kk++) {
    float el = __shfl(elA, base + kk, 64);
    logit[kk] = (dot[kk] + el) * 0.17677669529663687f;  // 1/sqrt(32)
  }
#pragma unroll
  for (int kk = 8; kk < KNB; kk++) {
    float el = __shfl(elB, base + (kk - 8), 64);
    logit[kk] = (dot[kk] + el) * 0.17677669529663687f;
  }

  // softmax (redundant per lane, consistent within head)
  float mx = -1e30f;
#pragma unroll
  for (int kk = 0; kk < KNB; kk++) mx = fmaxf(mx, logit[kk]);
  float attw[KNB]; float sum = 0.f;
#pragma unroll
  for (int kk = 0; kk < KNB; kk++) { attw[kk] = expf(logit[kk] - mx); sum += attw[kk]; }
  float inv = 1.f / sum;
#pragma unroll
  for (int kk = 0; kk < KNB; kk++) attw[kk] *= inv;

  // V: gathered part
  float4 o = ((const float4*)bv)[lane];
#pragma unroll
  for (int kk = 0; kk < KNB; kk++) {
    float a = attw[kk];
    o.x += a * (float)pvs[kk].x;
    o.y += a * (float)pvs[kk].y;
    o.z += a * (float)pvs[kk].z;
    o.w += a * (float)pvs[kk].w;
  }

  // ew distributed: lane computes j = 3i..3i+2 (rows L1-hot from edge-logit stage)
  const f16* ebase = edges + (size_t)n*KNB*EDIM;
  float ew0 = 0.f, ew1 = 0.f, ew2 = 0.f;
#pragma unroll
  for (int kk = 0; kk < KNB; kk++) {
    float a = attw[kk];
    ew0 += a * (float)ebase[kk*EDIM + 3*i + 0];
    ew1 += a * (float)ebase[kk*EDIM + 3*i + 1];
    ew2 += a * (float)ebase[kk*EDIM + 3*i + 2];
  }

  // V: edge part — broadcast ew within head, WvB f32 (L2-hot)
#pragma unroll
  for (int src = 0; src < 8; src++) {
    float w0 = __shfl(ew0, base + src, 64);
    float w1 = __shfl(ew1, base + src, 64);
    float w2 = __shfl(ew2, base + src, 64);
    float4 wv0 = ((const float4*)(WvB + (size_t)(3*src + 0)*QDIM))[lane];
    float4 wv1 = ((const float4*)(WvB + (size_t)(3*src + 1)*QDIM))[lane];
    float4 wv2 = ((const float4*)(WvB + (size_t)(3*src + 2)*QDIM))[lane];
    o.x += w0*wv0.x + w1*wv1.x + w2*wv2.x;
    o.y += w0*wv0.y + w1*wv1.y + w2*wv2.y;
    o.z += w0*wv0.z + w1*wv1.z + w2*wv2.z;
    o.w += w0*wv0.w + w1*wv1.w + w2*wv2.w;
  }

  f16x4 ov; ov.x = (f16)o.x; ov.y = (f16)o.y; ov.z = (f16)o.z; ov.w = (f16)o.w;
  ((f16x4*)att)[(size_t)n*64 + lane] = ov;
}

// ---------------- output head (f32 output) ----------------
__global__ __launch_bounds__(128) void head_kernel(const float* __restrict__ enc,
    const float* Ws, const float* bs, const float* Wc, const float* bc,
    const float* Wconc, const float* bconc, const float* Wwt, const float* bwt,
    const float* Wfac, const float* bfac, const float* __restrict__ angles, float* __restrict__ out) {
  int n = blockIdx.x, t = threadIdx.x;
  __shared__ float es[128];
  __shared__ float outs[103];
  es[t] = enc[(size_t)n*SDIM + t];
  __syncthreads();
  const float* W = nullptr; const float* bb = nullptr; int col = 0, nc = 0;
  if (t < 30)       { W = Ws;    bb = bs;    col = t;       nc = 30; }
  else if (t < 60)  { W = Wc;    bb = bc;    col = t - 30;  nc = 30; }
  else if (t < 90)  { W = Wconc; bb = bconc; col = t - 60;  nc = 30; }
  else if (t < 100) { W = Wwt;   bb = bwt;   col = t - 90;  nc = 10; }
  else if (t < 103) { W = Wfac;  bb = bfac;  col = t - 100; nc = 3;  }
  if (W) {
    float acc = bb[col];
    for (int j = 0; j < 128; j++) acc += es[j] * W[j*nc + col];
    outs[t] = acc;
  }
  __syncthreads();
  if (t < MIXN) {
    float mx = -1e30f;
    for (int m = 0; m < MIXN; m++) mx = fmaxf(mx, outs[90 + m]);
    float sum = 0.f;
    for (int m = 0; m < MIXN; m++) sum += expf(outs[90 + m] - mx);
    out[(size_t)n*MIXN + t] = expf(outs[90 + t] - mx) / sum;
  }
  if (t < 30) {
    int j = t / 10;
    float v = atan2f(outs[t], outs[30 + t]);
    float a0 = angles[n*3 + 0], a1 = angles[n*3 + 1];
    if (j == 1) v += outs[100] * a0;
    if (j == 2) v += outs[101] * a0 + outs[102] * a1;
    out[(size_t)NRES*MIXN + (size_t)n*30 + t] = v;
    float z = outs[60 + t];
    float sg = 1.f / (1.f + expf(-z));
    out[(size_t)NRES*MIXN + (size_t)NRES*30 + (size_t)n*30 + t] = 0.1f + 1000.f * sg;
  }
}

// ---------------- launch ----------------
extern "C" void kernel_launch(void* const* d_in, const int* in_sizes, int n_in,
                              void* d_out, int out_size, void* d_ws, size_t ws_size,
                              hipStream_t stream) {
  const float* angles   = (const float*)d_in[0];
  const float* tertiary = (const float*)d_in[1];
  const int*   structure = (const int*)d_in[2];
  const float* W_in  = (const float*)d_in[4];  const float* b_in  = (const float*)d_in[5];
  const float* W_pre = (const float*)d_in[6];  const float* b_pre = (const float*)d_in[7];
  const float* ln1_g = (const float*)d_in[8];  const float* ln1_b = (const float*)d_in[9];
  const float* ln2_g = (const float*)d_in[10]; const float* ln2_b = (const float*)d_in[11];
  const float* Wq = (const float*)d_in[12]; const float* bq = (const float*)d_in[13];
  const float* Wk = (const float*)d_in[14]; const float* bk = (const float*)d_in[15];
  const float* Wv = (const float*)d_in[16]; const float* bv = (const float*)d_in[17];
  const float* Wo = (const float*)d_in[18]; const float* bo = (const float*)d_in[19];
  const float* W1 = (const float*)d_in[20]; const float* b1 = (const float*)d_in[21];
  const float* W2 = (const float*)d_in[22]; const float* b2 = (const float*)d_in[23];
  const float* W3 = (const float*)d_in[24]; const float* b3 = (const float*)d_in[25];
  const float* Ws = (const float*)d_in[26]; const float* bs = (const float*)d_in[27];
  const float* Wc = (const float*)d_in[28]; const float* bc = (const float*)d_in[29];
  const float* Wconc = (const float*)d_in[30]; const float* bconc = (const float*)d_in[31];
  const float* Wwt = (const float*)d_in[32]; const float* bwt = (const float*)d_in[33];
  const float* Wfac = (const float*)d_in[34]; const float* bfac = (const float*)d_in[35];

  // workspace layout (bytes); high-water ~58.1 MB (<= 62.5 MB established safe)
  char* wsb = (char*)d_ws;
  float* pos   = (float*)(wsb + 0);
  float* Rm    = (float*)(wsb + 98304);
  f16*   edg_h = (f16*)  (wsb + 393216);      // 5,898,240 B
  float* x     = (float*)(wsb + 6291456);     // 4 MiB f32 residual
  f16*   nx_h  = (f16*)  (wsb + 10485760);    // 2 MiB
  f16*   att_h = (f16*)  (wsb + 12582912);    // 4 MiB
  f16*   qh    = (f16*)  (wsb + 16777216);    // 4 MiB
  f16*   pkh   = (f16*)  (wsb + 20971520);    // 4 MiB
  f16*   pvh   = (f16*)  (wsb + 25165824);    // 4 MiB
  f16*   h1h   = (f16*)  (wsb + 29360128);    // 8 MiB
  f16*   h2h   = (f16*)  (wsb + 37748736);    // 8 MiB
  f16*   qkvw  = (f16*)  (wsb + 46137344);
  f16*   w1w   = (f16*)  (wsb + 46727168);
  f16*   w2w   = (f16*)  (wsb + 47120384);
  f16*   w3w   = (f16*)  (wsb + 48693248);
  f16*   wow   = (f16*)  (wsb + 49086464);
  float* b768  = (float*)(wsb + 49283072);
  float* qWb   = (float*)(wsb + 49292288);    // 8,388,608 B f32 [8192][256]
  f16*   wqd   = (f16*)  (wsb + 57680896);    //   393,216 B (3 x 256x256 dense masked) -> 58,074,112

  pos_kernel<<<dim3((NRES+255)/256), dim3(256), 0, stream>>>(tertiary, pos);
  frames_kernel<<<dim3((NRES+255)/256), dim3(256), 0, stream>>>(pos, Rm);
  edges_kernel<<<dim3((NRES*KNB+255)/256), dim3(256), 0, stream>>>(pos, Rm, structure, edg_h);
  init_kernel<<<dim3(NRES), dim3(128), 0, stream>>>(angles, W_in, b_in, W_pre, b_pre, x);

  convswz_kernel<<<dim3(64,3), 256, 0, stream>>>(Wq, SDIM*QDIM, QDIM, 128, 256, qkvw, 98304, 768, 0);
  convswz_kernel<<<dim3(64,3), 256, 0, stream>>>(Wk, (SDIM+EDIM)*QDIM, QDIM, 128, 256, qkvw, 98304, 768, 256);
  convswz_kernel<<<dim3(64,3), 256, 0, stream>>>(Wv, (SDIM+EDIM)*QDIM, QDIM, 128, 256, qkvw, 98304, 768, 512);
  convswz_kernel<<<dim3(64,3), 256, 0, stream>>>(W1, SDIM*HIDD, HIDD, 128, 512, w1w, 65536, 512, 0);
  convswz_kernel<<<dim3(64,3), 256, 0, stream>>>(W2, HIDD*HIDD, HIDD, 512, 512, w2w, 262144, 512, 0);
  convswz_kernel<<<dim3(64,3), 256, 0, stream>>>(W3, HIDD*SDIM, SDIM, 512, 128, w3w, 65536, 128, 0);
  convswz_kernel<<<dim3(64,3), 256, 0, stream>>>(Wo, QDIM*SDIM, SDIM, 256, 128, wow, 32768, 128, 0);
  wqdense_kernel<<<768, 256, 0, stream>>>(Wk, bk, wqd);
  bias768_kernel<<<9, 256, 0, stream>>>(bq, b768);

  for (int d = 0; d < 3; ++d) {
    const float* WvD = Wv + (size_t)d*(SDIM+EDIM)*QDIM;
    ln_kernel<<<dim3(NRES), dim3(128), 0, stream>>>(x, ln1_g + d*SDIM, ln1_b + d*SDIM, nx_h);
    gemm_mfma<3><<<768, 256, 0, stream>>>(nx_h, qkvw + (size_t)d*98304, b768 + d*768, qh, 128, 768);
    // qW = q @ dense masked WkB|bk  (f32 out, stride 256)
    gemm_mfma<4><<<256, 256, 0, stream>>>(qh, wqd + (size_t)d*65536, nullptr, qWb, 256, 256);
    attn_kernel<<<dim3(NRES/4), dim3(256), 0, stream>>>(qh, pkh, pvh, edg_h, structure,
        qWb, WvD + (size_t)SDIM*QDIM, bv + d*QDIM, att_h);
    gemm_mfma16<<<256, 256, 0, stream>>>(att_h, wow + (size_t)d*32768, bo + d*SDIM, x, 256, 128);
    ln_kernel<<<dim3(NRES), dim3(128), 0, stream>>>(x, ln2_g + d*SDIM, ln2_b + d*SDIM, nx_h);
    gemm_mfma<1><<<512, 256, 0, stream>>>(nx_h, w1w + (size_t)d*65536, b1 + d*HIDD, h1h, 128, 512);
    gemm_mfma<1><<<512, 256, 0, stream>>>(h1h, w2w + (size_t)d*262144, b2 + d*HIDD, h2h, 512, 512);
    gemm_mfma16<<<256, 256, 0, stream>>>(h2h, w3w + (size_t)d*65536, b3 + d*SDIM, x, 512, 128);
  }

  head_kernel<<<dim3(NRES), dim3(128), 0, stream>>>(x, Ws, bs, Wc, bc, Wconc, bconc,
      Wwt, bwt, Wfac, bfac, angles, (float*)d_out);
}

// Round 12
// 504.724 us; speedup vs baseline: 1.3974x; 1.0291x over previous
//
#include <hip/hip_runtime.h>
#include <hip/hip_bf16.h>
#include <stdint.h>

// Problem constants
#define NRES 8192
#define KNB  15
#define SDIM 128
#define EDIM 24
#define HIDD 512
#define NH   8
#define QDIM 256   // H*A
#define MIXN 10

typedef _Float16 f16;
typedef _Float16 f16x8 __attribute__((ext_vector_type(8)));
typedef _Float16 f16x4 __attribute__((ext_vector_type(4)));
typedef _Float16 f16x2 __attribute__((ext_vector_type(2)));
typedef float f32x4 __attribute__((ext_vector_type(4)));

#if __has_builtin(__builtin_amdgcn_fdot2)
#define FDOT2(a,b,c) __builtin_amdgcn_fdot2((a),(b),(c),false)
#else
#define FDOT2(a,b,c) ((c) + (float)(a).x*(float)(b).x + (float)(a).y*(float)(b).y)
#endif

struct F3 { float x, y, z; };
__device__ __forceinline__ F3 f3sub(F3 a, F3 b) { return {a.x-b.x, a.y-b.y, a.z-b.z}; }
__device__ __forceinline__ F3 f3cross(F3 a, F3 b) {
  return {a.y*b.z - a.z*b.y, a.z*b.x - a.x*b.z, a.x*b.y - a.y*b.x};
}
__device__ __forceinline__ F3 f3norm(F3 a) {
  float l = sqrtf(a.x*a.x + a.y*a.y + a.z*a.z) + 1e-8f;
  float r = 1.f / l;
  return {a.x*r, a.y*r, a.z*r};
}
__device__ __forceinline__ F3 ldpos(const float* p, int i) { return {p[i*3], p[i*3+1], p[i*3+2]}; }

// ---------------- geometry ----------------
__global__ void pos_kernel(const float* __restrict__ tert, float* __restrict__ pos) {
  int n = blockIdx.x * blockDim.x + threadIdx.x;
  if (n >= NRES) return;
  pos[n*3+0] = tert[n*9+3];
  pos[n*3+1] = tert[n*9+4];
  pos[n*3+2] = tert[n*9+5];
}

__global__ void frames_kernel(const float* __restrict__ pos, float* __restrict__ R) {
  int m = blockIdx.x * blockDim.x + threadIdx.x;
  if (m >= NRES) return;
  int s = m - 1; if (s < 0) s = 0; if (s > NRES-3) s = NRES-3;
  F3 p0 = ldpos(pos, s), p1 = ldpos(pos, s+1), p2 = ldpos(pos, s+2);
  F3 u0 = f3norm(f3sub(p1, p0));
  F3 u1 = f3norm(f3sub(p2, p1));
  F3 b  = f3norm(f3sub(u0, u1));
  F3 nn = f3norm(f3cross(u0, u1));
  F3 o  = f3cross(b, nn);
  float* r = R + m*9;
  r[0]=b.x; r[1]=nn.x; r[2]=o.x;
  r[3]=b.y; r[4]=nn.y; r[5]=o.y;
  r[6]=b.z; r[7]=nn.z; r[8]=o.z;
}

__device__ __forceinline__ float quat_comp(float t, float a, float b) {
  float s = (a > b) ? 1.f : ((a < b) ? -1.f : 0.f);
  return 0.5f * sqrtf(fmaxf(1e-8f, t)) * s;
}

__global__ void edges_kernel(const float* __restrict__ pos, const float* __restrict__ R,
                             const int* __restrict__ structure, f16* __restrict__ edges) {
  int id = blockIdx.x * blockDim.x + threadIdx.x;
  if (id >= NRES*KNB) return;
  int n = id / KNB;
  int tprev = (n - 1) & (NRES - 1);
  int sidx = structure[id];
  F3 pt = ldpos(pos, tprev), ps = ldpos(pos, sidx);
  F3 dv = f3sub(ps, pt);
  float dist = sqrtf(dv.x*dv.x + dv.y*dv.y + dv.z*dv.z);
  float rinv = 1.f / (dist + 1e-8f);
  F3 dh = {dv.x*rinv, dv.y*rinv, dv.z*rinv};
  float Rt[9], Rs[9];
#pragma unroll
  for (int i = 0; i < 9; i++) { Rt[i] = R[tprev*9+i]; Rs[i] = R[sidx*9+i]; }
  float dir[3];
#pragma unroll
  for (int i = 0; i < 3; i++) dir[i] = Rt[i]*dh.x + Rt[3+i]*dh.y + Rt[6+i]*dh.z;
  float Rr[9];
#pragma unroll
  for (int i = 0; i < 3; i++)
#pragma unroll
    for (int l = 0; l < 3; l++)
      Rr[i*3+l] = Rt[i]*Rs[l] + Rt[3+i]*Rs[3+l] + Rt[6+i]*Rs[6+l];
  float m00 = Rr[0], m11 = Rr[4], m22 = Rr[8];
  float qw = 0.5f * sqrtf(fmaxf(1e-8f, 1.f + m00 + m11 + m22));
  float qx = quat_comp(1.f + m00 - m11 - m22, Rr[7], Rr[5]);
  float qy = quat_comp(1.f - m00 + m11 - m22, Rr[2], Rr[6]);
  float qz = quat_comp(1.f - m00 - m11 + m22, Rr[3], Rr[1]);
  f16* e = edges + (size_t)id * EDIM;
#pragma unroll
  for (int j = 0; j < 16; j++) {
    float mu = (20.f / 15.f) * j;            // linspace(0,20,16)
    float zz = (dist - mu) * (1.f / 1.25f);  // sigma = 20/16
    e[j] = (f16)expf(-zz*zz);
  }
  e[16] = (f16)dir[0]; e[17] = (f16)dir[1]; e[18] = (f16)dir[2];
  e[19] = (f16)qw; e[20] = (f16)qx; e[21] = (f16)qy; e[22] = (f16)qz;
  e[23] = (f16)((float)(sidx - tprev) * 0.01f);
}

// ---------------- input embedding ----------------
__global__ __launch_bounds__(128) void init_kernel(const float* __restrict__ angles,
    const float* __restrict__ W_in, const float* __restrict__ b_in,
    const float* __restrict__ W_pre, const float* __restrict__ b_pre, float* __restrict__ x) {
  int n = blockIdx.x, c = threadIdx.x;
  __shared__ float fs[128];
  float af[6];
  if (n == 0) { af[0]=af[1]=af[2]=0.f; af[3]=af[4]=af[5]=1.f; }
  else {
#pragma unroll
    for (int j = 0; j < 3; j++) {
      float p = angles[(n-1)*3 + j];
      af[j] = sinf(p); af[3+j] = cosf(p);
    }
  }
  float f = b_in[c];
#pragma unroll
  for (int j = 0; j < 6; j++) f += af[j] * W_in[j*SDIM + c];
  fs[c] = f;
  __syncthreads();
  float xv = b_pre[c];
  for (int j = 0; j < 128; j++) xv += fs[j] * W_pre[j*SDIM + c];
  x[(size_t)n*SDIM + c] = xv;
}

// ---------------- weight convert+swizzle: f32 [K][N] -> fp16 frag layout ----------------
__global__ void convswz_kernel(const float* __restrict__ src, int srcLayerStride, int srcLd,
    int K, int N, f16* __restrict__ dst, int dstLayerHalves, int dstN, int colOff) {
  int d = blockIdx.y;
  const float* s = src + (size_t)d * srcLayerStride;
  f16* o = dst + (size_t)d * dstLayerHalves;
  for (int i = blockIdx.x*blockDim.x + threadIdx.x; i < K*N; i += gridDim.x*blockDim.x) {
    int k = i / N, n = i - k*N;
    o[((size_t)(k>>3)*dstN + colOff + n)*8 + (k&7)] = (f16)s[(size_t)k*srcLd + n];
  }
}

// Wcomb = Wq @ Wd (per-head-masked WkB|bk), written as cols 768..1024 of the qkv swizzled B.
// Also bias_qw[col] = bq @ Wd  -> b1024 cols 768..1024.
__global__ __launch_bounds__(128) void wcomb_kernel(const float* __restrict__ Wq,
    const float* __restrict__ bq, const float* __restrict__ Wk, const float* __restrict__ bk,
    f16* __restrict__ qkvw, float* __restrict__ b1024) {
  int blk = blockIdx.x;          // d*256 + col
  int d = blk >> 8, col = blk & 255;
  int k = threadIdx.x;           // 0..127
  float acc = 0.f, bacc = 0.f;
  if (col < 200) {
    int h = col / 25, jj = col % 25;
    const float* WkB = Wk + (size_t)d*(SDIM+EDIM)*QDIM + (size_t)SDIM*QDIM;
    const float* wqrow = Wq + (size_t)d*SDIM*QDIM + (size_t)k*QDIM;
    int r0 = h*32;
    for (int rr = 0; rr < 32; rr++) {
      int r = r0 + rr;
      float wd = (jj < 24) ? WkB[(size_t)jj*QDIM + r] : bk[d*QDIM + r];
      acc += wqrow[r] * wd;
      if (k == 0) bacc += bq[d*QDIM + r] * wd;
    }
  }
  qkvw[(size_t)d*131072 + ((size_t)(k>>3)*1024 + 768 + col)*8 + (k&7)] = (f16)acc;
  if (k == 0) b1024[d*1024 + 768 + col] = bacc;
}

__global__ void bias1024_kernel(const float* __restrict__ bq, float* __restrict__ out) {
  int i = blockIdx.x*blockDim.x + threadIdx.x;
  if (i >= 3*768) return;
  int d = i / 768, col = i - d*768;
  out[d*1024 + col] = (col < 256) ? bq[d*QDIM + col] : 0.f;
}

// ---------------- MFMA GEMM 32x64 wave tile (fp16 A) ----------------
// MODE 1: fp16 C = relu(AB+bias)
template<int MODE>
__global__ __launch_bounds__(256) void gemm_mfma(const f16* __restrict__ A,
    const f16* __restrict__ Bsw, const float* __restrict__ bias,
    void* __restrict__ Cv, int Kd, int Nd) {
  int w = blockIdx.x * 4 + (threadIdx.x >> 6);
  int lane = threadIdx.x & 63;
  int wm = w & 255, wn = w >> 8;
  int m0 = wm * 32, n0 = wn * 64;
  int r16 = lane & 15, qd = lane >> 4;
  f32x4 acc[2][4] = {};
  const f16* aBase = A + (size_t)(m0 + r16)*Kd + qd*8;
  for (int kc = 0; kc < Kd; kc += 32) {
    f16x8 af0 = *(const f16x8*)(aBase + kc);
    f16x8 af1 = *(const f16x8*)(aBase + (size_t)16*Kd + kc);
    const f16* bBase = Bsw + ((size_t)((kc>>3) + qd)*Nd + n0 + r16)*8;
    f16x8 bf[4];
#pragma unroll
    for (int nt = 0; nt < 4; nt++) bf[nt] = *(const f16x8*)(bBase + nt*16*8);
#pragma unroll
    for (int nt = 0; nt < 4; nt++) {
      acc[0][nt] = __builtin_amdgcn_mfma_f32_16x16x32_f16(af0, bf[nt], acc[0][nt], 0, 0, 0);
      acc[1][nt] = __builtin_amdgcn_mfma_f32_16x16x32_f16(af1, bf[nt], acc[1][nt], 0, 0, 0);
    }
  }
#pragma unroll
  for (int mt = 0; mt < 2; mt++) {
#pragma unroll
    for (int nt = 0; nt < 4; nt++) {
      int col = n0 + nt*16 + r16;
      float bj = bias ? bias[col] : 0.f;
#pragma unroll
      for (int r = 0; r < 4; r++) {
        int row = m0 + mt*16 + qd*4 + r;
        float v = acc[mt][nt][r] + bj;
        ((f16*)Cv)[(size_t)row*Nd + col] = (f16)fmaxf(v, 0.f);
      }
    }
  }
}

// ---------------- LN-fused MFMA GEMM: A = f32 x (8192x128), LN applied per row ----------------
// MODE 1: fp16 C = relu(AB+bias), Nd=512 ; MODE 3: Nd=1024, cols 0..768 fp16 q|pk|pv split,
//         cols 768..1024 f32 qW into C2 (stride 256).
template<int MODE>
__global__ __launch_bounds__(256) void gemm_ln_mfma(const float* __restrict__ A,
    const float* __restrict__ lng, const float* __restrict__ lnb,
    const f16* __restrict__ Bsw, const float* __restrict__ bias,
    void* __restrict__ Cv, float* __restrict__ C2, int Nd) {
  int w = blockIdx.x * 4 + (threadIdx.x >> 6);
  int lane = threadIdx.x & 63;
  int wm = w & 255, wn = w >> 8;
  int m0 = wm * 32, n0 = wn * 64;
  int r16 = lane & 15, qd = lane >> 4;
  // load 2 rows x 32 channels (this lane's share: ch = qd*8 + kc*32 + j)
  const float* r0p = A + (size_t)(m0 + r16)*SDIM + qd*8;
  const float* r1p = r0p + (size_t)16*SDIM;
  float4 a0[8], a1[8];
#pragma unroll
  for (int kc = 0; kc < 4; kc++) {
    a0[kc*2+0] = *(const float4*)(r0p + kc*32);
    a0[kc*2+1] = *(const float4*)(r0p + kc*32 + 4);
    a1[kc*2+0] = *(const float4*)(r1p + kc*32);
    a1[kc*2+1] = *(const float4*)(r1p + kc*32 + 4);
  }
  float s0 = 0.f, s1 = 0.f;
#pragma unroll
  for (int c = 0; c < 8; c++) {
    s0 += a0[c].x + a0[c].y + a0[c].z + a0[c].w;
    s1 += a1[c].x + a1[c].y + a1[c].z + a1[c].w;
  }
  s0 += __shfl_xor(s0, 16, 64); s0 += __shfl_xor(s0, 32, 64);
  s1 += __shfl_xor(s1, 16, 64); s1 += __shfl_xor(s1, 32, 64);
  float mean0 = s0 * (1.f/128.f), mean1 = s1 * (1.f/128.f);
  float v0 = 0.f, v1 = 0.f;
#pragma unroll
  for (int c = 0; c < 8; c++) {
    float d0x = a0[c].x-mean0, d0y = a0[c].y-mean0, d0z = a0[c].z-mean0, d0w = a0[c].w-mean0;
    v0 += d0x*d0x + d0y*d0y + d0z*d0z + d0w*d0w;
    float d1x = a1[c].x-mean1, d1y = a1[c].y-mean1, d1z = a1[c].z-mean1, d1w = a1[c].w-mean1;
    v1 += d1x*d1x + d1y*d1y + d1z*d1z + d1w*d1w;
  }
  v0 += __shfl_xor(v0, 16, 64); v0 += __shfl_xor(v0, 32, 64);
  v1 += __shfl_xor(v1, 16, 64); v1 += __shfl_xor(v1, 32, 64);
  float rs0 = rsqrtf(v0 * (1.f/128.f) + 1e-5f);
  float rs1 = rsqrtf(v1 * (1.f/128.f) + 1e-5f);
  // build fp16 frags: val = (a-mean)*rstd*g + b
  f16x8 af0[4], af1[4];
#pragma unroll
  for (int kc = 0; kc < 4; kc++) {
    float4 g0 = *(const float4*)(lng + qd*8 + kc*32);
    float4 g1 = *(const float4*)(lng + qd*8 + kc*32 + 4);
    float4 bl0 = *(const float4*)(lnb + qd*8 + kc*32);
    float4 bl1 = *(const float4*)(lnb + qd*8 + kc*32 + 4);
    f16x8 f0, f1;
    f0[0] = (f16)((a0[kc*2].x  -mean0)*rs0*g0.x + bl0.x);
    f0[1] = (f16)((a0[kc*2].y  -mean0)*rs0*g0.y + bl0.y);
    f0[2] = (f16)((a0[kc*2].z  -mean0)*rs0*g0.z + bl0.z);
    f0[3] = (f16)((a0[kc*2].w  -mean0)*rs0*g0.w + bl0.w);
    f0[4] = (f16)((a0[kc*2+1].x-mean0)*rs0*g1.x + bl1.x);
    f0[5] = (f16)((a0[kc*2+1].y-mean0)*rs0*g1.y + bl1.y);
    f0[6] = (f16)((a0[kc*2+1].z-mean0)*rs0*g1.z + bl1.z);
    f0[7] = (f16)((a0[kc*2+1].w-mean0)*rs0*g1.w + bl1.w);
    f1[0] = (f16)((a1[kc*2].x  -mean1)*rs1*g0.x + bl0.x);
    f1[1] = (f16)((a1[kc*2].y  -mean1)*rs1*g0.y + bl0.y);
    f1[2] = (f16)((a1[kc*2].z  -mean1)*rs1*g0.z + bl0.z);
    f1[3] = (f16)((a1[kc*2].w  -mean1)*rs1*g0.w + bl0.w);
    f1[4] = (f16)((a1[kc*2+1].x-mean1)*rs1*g1.x + bl1.x);
    f1[5] = (f16)((a1[kc*2+1].y-mean1)*rs1*g1.y + bl1.y);
    f1[6] = (f16)((a1[kc*2+1].z-mean1)*rs1*g1.z + bl1.z);
    f1[7] = (f16)((a1[kc*2+1].w-mean1)*rs1*g1.w + bl1.w);
    af0[kc] = f0; af1[kc] = f1;
  }
  f32x4 acc[2][4] = {};
#pragma unroll
  for (int kc = 0; kc < 4; kc++) {
    const f16* bBase = Bsw + ((size_t)(kc*4 + qd)*Nd + n0 + r16)*8;
    f16x8 bf[4];
#pragma unroll
    for (int nt = 0; nt < 4; nt++) bf[nt] = *(const f16x8*)(bBase + nt*16*8);
#pragma unroll
    for (int nt = 0; nt < 4; nt++) {
      acc[0][nt] = __builtin_amdgcn_mfma_f32_16x16x32_f16(af0[kc], bf[nt], acc[0][nt], 0, 0, 0);
      acc[1][nt] = __builtin_amdgcn_mfma_f32_16x16x32_f16(af1[kc], bf[nt], acc[1][nt], 0, 0, 0);
    }
  }
#pragma unroll
  for (int mt = 0; mt < 2; mt++) {
#pragma unroll
    for (int nt = 0; nt < 4; nt++) {
      int col = n0 + nt*16 + r16;
      float bj = bias[col];
#pragma unroll
      for (int r = 0; r < 4; r++) {
        int row = m0 + mt*16 + qd*4 + r;
        float v = acc[mt][nt][r] + bj;
        if (MODE == 1) {
          ((f16*)Cv)[(size_t)row*Nd + col] = (f16)fmaxf(v, 0.f);
        } else {  // MODE 3: q|pk|pv fp16 + qW f32
          int third = col >> 8, cl = col & 255;
          if (third < 3)
            ((f16*)Cv)[(size_t)third*NRES*QDIM + (size_t)row*QDIM + cl] = (f16)v;
          else
            C2[(size_t)row*256 + cl] = v;
        }
      }
    }
  }
}

// ---------------- MFMA GEMM 16x64 wave tile, f32 C += AB + bias (Wo / W3, N=128) ----------------
__global__ __launch_bounds__(256) void gemm_mfma16(const f16* __restrict__ A,
    const f16* __restrict__ Bsw, const float* __restrict__ bias,
    float* __restrict__ C, int Kd, int Nd) {
  int w = blockIdx.x * 4 + (threadIdx.x >> 6);
  int lane = threadIdx.x & 63;
  int wm = w & 511, wn = w >> 9;
  int m0 = wm * 16, n0 = wn * 64;
  int r16 = lane & 15, qd = lane >> 4;
  f32x4 acc[4] = {};
  const f16* aBase = A + (size_t)(m0 + r16)*Kd + qd*8;
  for (int kc = 0; kc < Kd; kc += 32) {
    f16x8 af = *(const f16x8*)(aBase + kc);
    const f16* bBase = Bsw + ((size_t)((kc>>3) + qd)*Nd + n0 + r16)*8;
#pragma unroll
    for (int nt = 0; nt < 4; nt++) {
      f16x8 bf = *(const f16x8*)(bBase + nt*16*8);
      acc[nt] = __builtin_amdgcn_mfma_f32_16x16x32_f16(af, bf, acc[nt], 0, 0, 0);
    }
  }
#pragma unroll
  for (int nt = 0; nt < 4; nt++) {
    int col = n0 + nt*16 + r16;
    float bj = bias[col];
#pragma unroll
    for (int r = 0; r < 4; r++) {
      int row = m0 + qd*4 + r;
      C[(size_t)row*Nd + col] += acc[nt][r] + bj;
    }
  }
}

// ---------------- fused attention: ONE WAVE PER NODE, barrier-free ----------------
__global__ __launch_bounds__(256) void attn_kernel(const f16* __restrict__ q,
    const f16* __restrict__ pk, const f16* __restrict__ pv,
    const f16* __restrict__ edges, const int* __restrict__ structure,
    const float* __restrict__ qW, const float* __restrict__ WvB,
    const float* __restrict__ bv, f16* __restrict__ att) {
  int t = threadIdx.x;
  int n = blockIdx.x*4 + (t >> 6);
  int lane = t & 63;
  int h = lane >> 3, i = lane & 7, base = h << 3;

  int s[KNB];
#pragma unroll
  for (int kk = 0; kk < KNB; kk++) s[kk] = structure[n*KNB + kk];
  const f16x4* pk4 = (const f16x4*)pk;
  const f16x4* pv4 = (const f16x4*)pv;
  f16x4 pks[KNB], pvs[KNB];
#pragma unroll
  for (int kk = 0; kk < KNB; kk++) pks[kk] = pk4[(size_t)s[kk]*64 + lane];
#pragma unroll
  for (int kk = 0; kk < KNB; kk++) pvs[kk] = pv4[(size_t)s[kk]*64 + lane];
  f16x4 q4 = ((const f16x4*)q)[(size_t)n*64 + lane];

  const float* qwr = qW + (size_t)n*256 + h*25;
  float qbias = qwr[24];
  float elA = qbias, elB = qbias;
  {
    const f16x2* eA = (const f16x2*)(edges + (size_t)n*KNB*EDIM + i*EDIM);
#pragma unroll
    for (int j2 = 0; j2 < 12; j2++) {
      f16x2 e2 = eA[j2];
      elA += qwr[2*j2]*(float)e2.x + qwr[2*j2+1]*(float)e2.y;
    }
  }
  if (i < 7) {
    const f16x2* eB = (const f16x2*)(edges + (size_t)n*KNB*EDIM + (i+8)*EDIM);
#pragma unroll
    for (int j2 = 0; j2 < 12; j2++) {
      f16x2 e2 = eB[j2];
      elB += qwr[2*j2]*(float)e2.x + qwr[2*j2+1]*(float)e2.y;
    }
  }

  float dot[KNB];
  f16x2 qlo; qlo.x = q4.x; qlo.y = q4.y;
  f16x2 qhi; qhi.x = q4.z; qhi.y = q4.w;
#pragma unroll
  for (int kk = 0; kk < KNB; kk++) {
    f16x2 plo; plo.x = pks[kk].x; plo.y = pks[kk].y;
    f16x2 phi; phi.x = pks[kk].z; phi.y = pks[kk].w;
    float p = FDOT2(qlo, plo, 0.f);
    p = FDOT2(qhi, phi, p);
    p += __shfl_xor(p, 4, 64);
    p += __shfl_xor(p, 2, 64);
    p += __shfl_xor(p, 1, 64);
    dot[kk] = p;
  }

  float logit[KNB];
#pragma unroll
  for (int kk = 0; kk < 8; kk++) {
    float el = __shfl(elA, base + kk, 64);
    logit[kk] = (dot[kk] + el) * 0.17677669529663687f;
  }
#pragma unroll
  for (int kk = 8; kk < KNB; kk++) {
    float el = __shfl(elB, base + (kk - 8), 64);
    logit[kk] = (dot[kk] + el) * 0.17677669529663687f;
  }

  float mx = -1e30f;
#pragma unroll
  for (int kk = 0; kk < KNB; kk++) mx = fmaxf(mx, logit[kk]);
  float attw[KNB]; float sum = 0.f;
#pragma unroll
  for (int kk = 0; kk < KNB; kk++) { attw[kk] = expf(logit[kk] - mx); sum += attw[kk]; }
  float inv = 1.f / sum;
#pragma unroll
  for (int kk = 0; kk < KNB; kk++) attw[kk] *= inv;

  float4 o = ((const float4*)bv)[lane];
#pragma unroll
  for (int kk = 0; kk < KNB; kk++) {
    float a = attw[kk];
    o.x += a * (float)pvs[kk].x;
    o.y += a * (float)pvs[kk].y;
    o.z += a * (float)pvs[kk].z;
    o.w += a * (float)pvs[kk].w;
  }

  const f16* ebase = edges + (size_t)n*KNB*EDIM;
  float ew0 = 0.f, ew1 = 0.f, ew2 = 0.f;
#pragma unroll
  for (int kk = 0; kk < KNB; kk++) {
    float a = attw[kk];
    ew0 += a * (float)ebase[kk*EDIM + 3*i + 0];
    ew1 += a * (float)ebase[kk*EDIM + 3*i + 1];
    ew2 += a * (float)ebase[kk*EDIM + 3*i + 2];
  }

#pragma unroll
  for (int src = 0; src < 8; src++) {
    float w0 = __shfl(ew0, base + src, 64);
    float w1 = __shfl(ew1, base + src, 64);
    float w2 = __shfl(ew2, base + src, 64);
    float4 wv0 = ((const float4*)(WvB + (size_t)(3*src + 0)*QDIM))[lane];
    float4 wv1 = ((const float4*)(WvB + (size_t)(3*src + 1)*QDIM))[lane];
    float4 wv2 = ((const float4*)(WvB + (size_t)(3*src + 2)*QDIM))[lane];
    o.x += w0*wv0.x + w1*wv1.x + w2*wv2.x;
    o.y += w0*wv0.y + w1*wv1.y + w2*wv2.y;
    o.z += w0*wv0.z + w1*wv1.z + w2*wv2.z;
    o.w += w0*wv0.w + w1*wv1.w + w2*wv2.w;
  }

  f16x4 ov; ov.x = (f16)o.x; ov.y = (f16)o.y; ov.z = (f16)o.z; ov.w = (f16)o.w;
  ((f16x4*)att)[(size_t)n*64 + lane] = ov;
}

// ---------------- output head (f32 output) ----------------
__global__ __launch_bounds__(128) void head_kernel(const float* __restrict__ enc,
    const float* Ws, const float* bs, const float* Wc, const float* bc,
    const float* Wconc, const float* bconc, const float* Wwt, const float* bwt,
    const float* Wfac, const float* bfac, const float* __restrict__ angles, float* __restrict__ out) {
  int n = blockIdx.x, t = threadIdx.x;
  __shared__ float es[128];
  __shared__ float outs[103];
  es[t] = enc[(size_t)n*SDIM + t];
  __syncthreads();
  const float* W = nullptr; const float* bb = nullptr; int col = 0, nc = 0;
  if (t < 30)       { W = Ws;    bb = bs;    col = t;       nc = 30; }
  else if (t < 60)  { W = Wc;    bb = bc;    col = t - 30;  nc = 30; }
  else if (t < 90)  { W = Wconc; bb = bconc; col = t - 60;  nc = 30; }
  else if (t < 100) { W = Wwt;   bb = bwt;   col = t - 90;  nc = 10; }
  else if (t < 103) { W = Wfac;  bb = bfac;  col = t - 100; nc = 3;  }
  if (W) {
    float acc = bb[col];
    for (int j = 0; j < 128; j++) acc += es[j] * W[j*nc + col];
    outs[t] = acc;
  }
  __syncthreads();
  if (t < MIXN) {
    float mx = -1e30f;
    for (int m = 0; m < MIXN; m++) mx = fmaxf(mx, outs[90 + m]);
    float sum = 0.f;
    for (int m = 0; m < MIXN; m++) sum += expf(outs[90 + m] - mx);
    out[(size_t)n*MIXN + t] = expf(outs[90 + t] - mx) / sum;
  }
  if (t < 30) {
    int j = t / 10;
    float v = atan2f(outs[t], outs[30 + t]);
    float a0 = angles[n*3 + 0], a1 = angles[n*3 + 1];
    if (j == 1) v += outs[100] * a0;
    if (j == 2) v += outs[101] * a0 + outs[102] * a1;
    out[(size_t)NRES*MIXN + (size_t)n*30 + t] = v;
    float z = outs[60 + t];
    float sg = 1.f / (1.f + expf(-z));
    out[(size_t)NRES*MIXN + (size_t)NRES*30 + (size_t)n*30 + t] = 0.1f + 1000.f * sg;
  }
}

// ---------------- launch ----------------
extern "C" void kernel_launch(void* const* d_in, const int* in_sizes, int n_in,
                              void* d_out, int out_size, void* d_ws, size_t ws_size,
                              hipStream_t stream) {
  const float* angles   = (const float*)d_in[0];
  const float* tertiary = (const float*)d_in[1];
  const int*   structure = (const int*)d_in[2];
  const float* W_in  = (const float*)d_in[4];  const float* b_in  = (const float*)d_in[5];
  const float* W_pre = (const float*)d_in[6];  const float* b_pre = (const float*)d_in[7];
  const float* ln1_g = (const float*)d_in[8];  const float* ln1_b = (const float*)d_in[9];
  const float* ln2_g = (const float*)d_in[10]; const float* ln2_b = (const float*)d_in[11];
  const float* Wq = (const float*)d_in[12]; const float* bq = (const float*)d_in[13];
  const float* Wk = (const float*)d_in[14]; const float* bk = (const float*)d_in[15];
  const float* Wv = (const float*)d_in[16]; const float* bv = (const float*)d_in[17];
  const float* Wo = (const float*)d_in[18]; const float* bo = (const float*)d_in[19];
  const float* W1 = (const float*)d_in[20]; const float* b1 = (const float*)d_in[21];
  const float* W2 = (const float*)d_in[22]; const float* b2 = (const float*)d_in[23];
  const float* W3 = (const float*)d_in[24]; const float* b3 = (const float*)d_in[25];
  const float* Ws = (const float*)d_in[26]; const float* bs = (const float*)d_in[27];
  const float* Wc = (const float*)d_in[28]; const float* bc = (const float*)d_in[29];
  const float* Wconc = (const float*)d_in[30]; const float* bconc = (const float*)d_in[31];
  const float* Wwt = (const float*)d_in[32]; const float* bwt = (const float*)d_in[33];
  const float* Wfac = (const float*)d_in[34]; const float* bfac = (const float*)d_in[35];

  // workspace layout (bytes); high-water ~57.9 MB (<= 62.5 MB established safe)
  char* wsb = (char*)d_ws;
  float* pos   = (float*)(wsb + 0);
  float* Rm    = (float*)(wsb + 98304);
  f16*   edg_h = (f16*)  (wsb + 393216);      // 5,898,240 B
  float* x     = (float*)(wsb + 6291456);     // 4 MiB f32 residual
  f16*   att_h = (f16*)  (wsb + 12582912);    // 4 MiB
  f16*   qh    = (f16*)  (wsb + 16777216);    // 4 MiB (q | pk | pv contiguous fp16)
  f16*   pkh   = (f16*)  (wsb + 20971520);    // 4 MiB
  f16*   pvh   = (f16*)  (wsb + 25165824);    // 4 MiB
  f16*   h1h   = (f16*)  (wsb + 29360128);    // 8 MiB
  f16*   h2h   = (f16*)  (wsb + 37748736);    // 8 MiB
  f16*   qkvw  = (f16*)  (wsb + 46137344);    //   786,432 B (3 x 128x1024 swizzled)
  f16*   w1w   = (f16*)  (wsb + 46923776);    //   393,216 B
  f16*   w2w   = (f16*)  (wsb + 47316992);    // 1,572,864 B
  f16*   w3w   = (f16*)  (wsb + 48889856);    //   393,216 B
  f16*   wow   = (f16*)  (wsb + 49283072);    //   196,608 B
  float* b1024 = (float*)(wsb + 49479680);    //    12,288 B
  float* qWb   = (float*)(wsb + 49491968);    // 8,388,608 B f32 [8192][256] -> 57,880,576

  pos_kernel<<<dim3((NRES+255)/256), dim3(256), 0, stream>>>(tertiary, pos);
  frames_kernel<<<dim3((NRES+255)/256), dim3(256), 0, stream>>>(pos, Rm);
  edges_kernel<<<dim3((NRES*KNB+255)/256), dim3(256), 0, stream>>>(pos, Rm, structure, edg_h);
  init_kernel<<<dim3(NRES), dim3(128), 0, stream>>>(angles, W_in, b_in, W_pre, b_pre, x);

  convswz_kernel<<<dim3(64,3), 256, 0, stream>>>(Wq, SDIM*QDIM, QDIM, 128, 256, qkvw, 131072, 1024, 0);
  convswz_kernel<<<dim3(64,3), 256, 0, stream>>>(Wk, (SDIM+EDIM)*QDIM, QDIM, 128, 256, qkvw, 131072, 1024, 256);
  convswz_kernel<<<dim3(64,3), 256, 0, stream>>>(Wv, (SDIM+EDIM)*QDIM, QDIM, 128, 256, qkvw, 131072, 1024, 512);
  convswz_kernel<<<dim3(64,3), 256, 0, stream>>>(W1, SDIM*HIDD, HIDD, 128, 512, w1w, 65536, 512, 0);
  convswz_kernel<<<dim3(64,3), 256, 0, stream>>>(W2, HIDD*HIDD, HIDD, 512, 512, w2w, 262144, 512, 0);
  convswz_kernel<<<dim3(64,3), 256, 0, stream>>>(W3, HIDD*SDIM, SDIM, 512, 128, w3w, 65536, 128, 0);
  convswz_kernel<<<dim3(64,3), 256, 0, stream>>>(Wo, QDIM*SDIM, SDIM, 256, 128, wow, 32768, 128, 0);
  wcomb_kernel<<<768, 128, 0, stream>>>(Wq, bq, Wk, bk, qkvw, b1024);
  bias1024_kernel<<<9, 256, 0, stream>>>(bq, b1024);

  for (int d = 0; d < 3; ++d) {
    const float* WvD = Wv + (size_t)d*(SDIM+EDIM)*QDIM;
    // LN1 + q|pk|pv + qW in one GEMM (Nd=1024, 256 m-tiles x 16 n-tiles)
    gemm_ln_mfma<3><<<1024, 256, 0, stream>>>(x, ln1_g + d*SDIM, ln1_b + d*SDIM,
        qkvw + (size_t)d*131072, b1024 + d*1024, qh, qWb, 1024);
    attn_kernel<<<dim3(NRES/4), dim3(256), 0, stream>>>(qh, pkh, pvh, edg_h, structure,
        qWb, WvD + (size_t)SDIM*QDIM, bv + d*QDIM, att_h);
    gemm_mfma16<<<256, 256, 0, stream>>>(att_h, wow + (size_t)d*32768, bo + d*SDIM, x, 256, 128);
    // LN2 + W1 in one GEMM (Nd=512, 256 m-tiles x 8 n-tiles)
    gemm_ln_mfma<1><<<512, 256, 0, stream>>>(x, ln2_g + d*SDIM, ln2_b + d*SDIM,
        w1w + (size_t)d*65536, b1 + d*HIDD, h1h, nullptr, 512);
    gemm_mfma<1><<<512, 256, 0, stream>>>(h1h, w2w + (size_t)d*262144, b2 + d*HIDD, h2h, 512, 512);
    gemm_mfma16<<<256, 256, 0, stream>>>(h2h, w3w + (size_t)d*65536, b3 + d*SDIM, x, 512, 128);
  }

  head_kernel<<<dim3(NRES), dim3(128), 0, stream>>>(x, Ws, bs, Wc, bc, Wconc, bconc,
      Wwt, bwt, Wfac, bfac, angles, (float*)d_out);
}

// Round 13
// 439.431 us; speedup vs baseline: 1.6051x; 1.1486x over previous
//
#include <hip/hip_runtime.h>
#include <hip/hip_bf16.h>
#include <stdint.h>

// Problem constants
#define NRES 8192
#define KNB  15
#define SDIM 128
#define EDIM 24
#define HIDD 512
#define NH   8
#define QDIM 256   // H*A
#define MIXN 10

typedef _Float16 f16;
typedef _Float16 f16x8 __attribute__((ext_vector_type(8)));
typedef _Float16 f16x4 __attribute__((ext_vector_type(4)));
typedef _Float16 f16x2 __attribute__((ext_vector_type(2)));
typedef float f32x4 __attribute__((ext_vector_type(4)));

#if __has_builtin(__builtin_amdgcn_fdot2)
#define FDOT2(a,b,c) __builtin_amdgcn_fdot2((a),(b),(c),false)
#else
#define FDOT2(a,b,c) ((c) + (float)(a).x*(float)(b).x + (float)(a).y*(float)(b).y)
#endif

struct F3 { float x, y, z; };
__device__ __forceinline__ F3 f3sub(F3 a, F3 b) { return {a.x-b.x, a.y-b.y, a.z-b.z}; }
__device__ __forceinline__ F3 f3cross(F3 a, F3 b) {
  return {a.y*b.z - a.z*b.y, a.z*b.x - a.x*b.z, a.x*b.y - a.y*b.x};
}
__device__ __forceinline__ F3 f3norm(F3 a) {
  float l = sqrtf(a.x*a.x + a.y*a.y + a.z*a.z) + 1e-8f;
  float r = 1.f / l;
  return {a.x*r, a.y*r, a.z*r};
}
__device__ __forceinline__ F3 ldter(const float* t, int i) {
  return {t[i*9+3], t[i*9+4], t[i*9+5]};
}

// ---------------- geometry (reads pos directly out of tertiary) ----------------
__global__ void frames_kernel(const float* __restrict__ tert, float* __restrict__ R) {
  int m = blockIdx.x * blockDim.x + threadIdx.x;
  if (m >= NRES) return;
  int s = m - 1; if (s < 0) s = 0; if (s > NRES-3) s = NRES-3;
  F3 p0 = ldter(tert, s), p1 = ldter(tert, s+1), p2 = ldter(tert, s+2);
  F3 u0 = f3norm(f3sub(p1, p0));
  F3 u1 = f3norm(f3sub(p2, p1));
  F3 b  = f3norm(f3sub(u0, u1));
  F3 nn = f3norm(f3cross(u0, u1));
  F3 o  = f3cross(b, nn);
  float* r = R + m*9;
  r[0]=b.x; r[1]=nn.x; r[2]=o.x;
  r[3]=b.y; r[4]=nn.y; r[5]=o.y;
  r[6]=b.z; r[7]=nn.z; r[8]=o.z;
}

__device__ __forceinline__ float quat_comp(float t, float a, float b) {
  float s = (a > b) ? 1.f : ((a < b) ? -1.f : 0.f);
  return 0.5f * sqrtf(fmaxf(1e-8f, t)) * s;
}

__global__ void edges_kernel(const float* __restrict__ tert, const float* __restrict__ R,
                             const int* __restrict__ structure, f16* __restrict__ edges) {
  int id = blockIdx.x * blockDim.x + threadIdx.x;
  if (id >= NRES*KNB) return;
  int n = id / KNB;
  int tprev = (n - 1) & (NRES - 1);
  int sidx = structure[id];
  F3 pt = ldter(tert, tprev), ps = ldter(tert, sidx);
  F3 dv = f3sub(ps, pt);
  float dist = sqrtf(dv.x*dv.x + dv.y*dv.y + dv.z*dv.z);
  float rinv = 1.f / (dist + 1e-8f);
  F3 dh = {dv.x*rinv, dv.y*rinv, dv.z*rinv};
  float Rt[9], Rs[9];
#pragma unroll
  for (int i = 0; i < 9; i++) { Rt[i] = R[tprev*9+i]; Rs[i] = R[sidx*9+i]; }
  float dir[3];
#pragma unroll
  for (int i = 0; i < 3; i++) dir[i] = Rt[i]*dh.x + Rt[3+i]*dh.y + Rt[6+i]*dh.z;
  float Rr[9];
#pragma unroll
  for (int i = 0; i < 3; i++)
#pragma unroll
    for (int l = 0; l < 3; l++)
      Rr[i*3+l] = Rt[i]*Rs[l] + Rt[3+i]*Rs[3+l] + Rt[6+i]*Rs[6+l];
  float m00 = Rr[0], m11 = Rr[4], m22 = Rr[8];
  float qw = 0.5f * sqrtf(fmaxf(1e-8f, 1.f + m00 + m11 + m22));
  float qx = quat_comp(1.f + m00 - m11 - m22, Rr[7], Rr[5]);
  float qy = quat_comp(1.f - m00 + m11 - m22, Rr[2], Rr[6]);
  float qz = quat_comp(1.f - m00 - m11 + m22, Rr[3], Rr[1]);
  f16* e = edges + (size_t)id * EDIM;
#pragma unroll
  for (int j = 0; j < 16; j++) {
    float mu = (20.f / 15.f) * j;            // linspace(0,20,16)
    float zz = (dist - mu) * (1.f / 1.25f);  // sigma = 20/16
    e[j] = (f16)expf(-zz*zz);
  }
  e[16] = (f16)dir[0]; e[17] = (f16)dir[1]; e[18] = (f16)dir[2];
  e[19] = (f16)qw; e[20] = (f16)qx; e[21] = (f16)qy; e[22] = (f16)qz;
  e[23] = (f16)((float)(sidx - tprev) * 0.01f);
}

// ---------------- input embedding ----------------
__global__ __launch_bounds__(128) void init_kernel(const float* __restrict__ angles,
    const float* __restrict__ W_in, const float* __restrict__ b_in,
    const float* __restrict__ W_pre, const float* __restrict__ b_pre, float* __restrict__ x) {
  int n = blockIdx.x, c = threadIdx.x;
  __shared__ float fs[128];
  float af[6];
  if (n == 0) { af[0]=af[1]=af[2]=0.f; af[3]=af[4]=af[5]=1.f; }
  else {
#pragma unroll
    for (int j = 0; j < 3; j++) {
      float p = angles[(n-1)*3 + j];
      af[j] = sinf(p); af[3+j] = cosf(p);
    }
  }
  float f = b_in[c];
#pragma unroll
  for (int j = 0; j < 6; j++) f += af[j] * W_in[j*SDIM + c];
  fs[c] = f;
  __syncthreads();
  float xv = b_pre[c];
  for (int j = 0; j < 128; j++) xv += fs[j] * W_pre[j*SDIM + c];
  x[(size_t)n*SDIM + c] = xv;
}

// ---------------- all weight convert+swizzle jobs in ONE dispatch ----------------
struct SwzJob { const float* src; int srcStride, srcLd, K, N; size_t dstOff; int dstLayerHalves, dstN, colOff; };
struct SwzJobs { SwzJob j[7]; };
__global__ void convswz_all(SwzJobs jobs, char* __restrict__ wsb) {
  SwzJob jb = jobs.j[blockIdx.y];
  int d = blockIdx.z;
  const float* s = jb.src + (size_t)d * jb.srcStride;
  f16* o = (f16*)(wsb + jb.dstOff) + (size_t)d * jb.dstLayerHalves;
  int tot = jb.K * jb.N;
  for (int i = blockIdx.x*blockDim.x + threadIdx.x; i < tot; i += gridDim.x*blockDim.x) {
    int k = i / jb.N, n = i - k*jb.N;
    o[((size_t)(k>>3)*jb.dstN + jb.colOff + n)*8 + (k&7)] = (f16)s[(size_t)k*jb.srcLd + n];
  }
}

// Wcomb = Wq @ Wd (per-head-masked WkB|bk) -> cols 768..1024 of qkv swizzled B; also fills b1024.
__global__ __launch_bounds__(128) void wcomb_kernel(const float* __restrict__ Wq,
    const float* __restrict__ bq, const float* __restrict__ Wk, const float* __restrict__ bk,
    f16* __restrict__ qkvw, float* __restrict__ b1024) {
  int blk = blockIdx.x;          // d*256 + col
  int d = blk >> 8, col = blk & 255;
  int k = threadIdx.x;           // 0..127
  float acc = 0.f, bacc = 0.f;
  if (col < 200) {
    int h = col / 25, jj = col % 25;
    const float* WkB = Wk + (size_t)d*(SDIM+EDIM)*QDIM + (size_t)SDIM*QDIM;
    const float* wqrow = Wq + (size_t)d*SDIM*QDIM + (size_t)k*QDIM;
    int r0 = h*32;
    for (int rr = 0; rr < 32; rr++) {
      int r = r0 + rr;
      float wd = (jj < 24) ? WkB[(size_t)jj*QDIM + r] : bk[d*QDIM + r];
      acc += wqrow[r] * wd;
      if (k == 0) bacc += bq[d*QDIM + r] * wd;
    }
  }
  qkvw[(size_t)d*131072 + ((size_t)(k>>3)*1024 + 768 + col)*8 + (k&7)] = (f16)acc;
  if (k == 0) {
    b1024[d*1024 + col]       = bq[d*QDIM + col];
    b1024[d*1024 + 256 + col] = 0.f;
    b1024[d*1024 + 512 + col] = 0.f;
    b1024[d*1024 + 768 + col] = bacc;
  }
}

// ---------------- LN-fused MFMA GEMM: A = f32 x (8192x128), LN applied per row ----------------
// MODE 3: Nd=1024, cols 0..768 fp16 q|pk|pv split, cols 768..1024 f32 qW into C2 (stride 256).
template<int MODE>
__global__ __launch_bounds__(256) void gemm_ln_mfma(const float* __restrict__ A,
    const float* __restrict__ lng, const float* __restrict__ lnb,
    const f16* __restrict__ Bsw, const float* __restrict__ bias,
    void* __restrict__ Cv, float* __restrict__ C2, int Nd) {
  int w = blockIdx.x * 4 + (threadIdx.x >> 6);
  int lane = threadIdx.x & 63;
  int wm = w & 255, wn = w >> 8;
  int m0 = wm * 32, n0 = wn * 64;
  int r16 = lane & 15, qd = lane >> 4;
  const float* r0p = A + (size_t)(m0 + r16)*SDIM + qd*8;
  const float* r1p = r0p + (size_t)16*SDIM;
  float4 a0[8], a1[8];
#pragma unroll
  for (int kc = 0; kc < 4; kc++) {
    a0[kc*2+0] = *(const float4*)(r0p + kc*32);
    a0[kc*2+1] = *(const float4*)(r0p + kc*32 + 4);
    a1[kc*2+0] = *(const float4*)(r1p + kc*32);
    a1[kc*2+1] = *(const float4*)(r1p + kc*32 + 4);
  }
  float s0 = 0.f, s1 = 0.f;
#pragma unroll
  for (int c = 0; c < 8; c++) {
    s0 += a0[c].x + a0[c].y + a0[c].z + a0[c].w;
    s1 += a1[c].x + a1[c].y + a1[c].z + a1[c].w;
  }
  s0 += __shfl_xor(s0, 16, 64); s0 += __shfl_xor(s0, 32, 64);
  s1 += __shfl_xor(s1, 16, 64); s1 += __shfl_xor(s1, 32, 64);
  float mean0 = s0 * (1.f/128.f), mean1 = s1 * (1.f/128.f);
  float v0 = 0.f, v1 = 0.f;
#pragma unroll
  for (int c = 0; c < 8; c++) {
    float d0x = a0[c].x-mean0, d0y = a0[c].y-mean0, d0z = a0[c].z-mean0, d0w = a0[c].w-mean0;
    v0 += d0x*d0x + d0y*d0y + d0z*d0z + d0w*d0w;
    float d1x = a1[c].x-mean1, d1y = a1[c].y-mean1, d1z = a1[c].z-mean1, d1w = a1[c].w-mean1;
    v1 += d1x*d1x + d1y*d1y + d1z*d1z + d1w*d1w;
  }
  v0 += __shfl_xor(v0, 16, 64); v0 += __shfl_xor(v0, 32, 64);
  v1 += __shfl_xor(v1, 16, 64); v1 += __shfl_xor(v1, 32, 64);
  float rs0 = rsqrtf(v0 * (1.f/128.f) + 1e-5f);
  float rs1 = rsqrtf(v1 * (1.f/128.f) + 1e-5f);
  f16x8 af0[4], af1[4];
#pragma unroll
  for (int kc = 0; kc < 4; kc++) {
    float4 g0 = *(const float4*)(lng + qd*8 + kc*32);
    float4 g1 = *(const float4*)(lng + qd*8 + kc*32 + 4);
    float4 bl0 = *(const float4*)(lnb + qd*8 + kc*32);
    float4 bl1 = *(const float4*)(lnb + qd*8 + kc*32 + 4);
    f16x8 f0, f1;
    f0[0] = (f16)((a0[kc*2].x  -mean0)*rs0*g0.x + bl0.x);
    f0[1] = (f16)((a0[kc*2].y  -mean0)*rs0*g0.y + bl0.y);
    f0[2] = (f16)((a0[kc*2].z  -mean0)*rs0*g0.z + bl0.z);
    f0[3] = (f16)((a0[kc*2].w  -mean0)*rs0*g0.w + bl0.w);
    f0[4] = (f16)((a0[kc*2+1].x-mean0)*rs0*g1.x + bl1.x);
    f0[5] = (f16)((a0[kc*2+1].y-mean0)*rs0*g1.y + bl1.y);
    f0[6] = (f16)((a0[kc*2+1].z-mean0)*rs0*g1.z + bl1.z);
    f0[7] = (f16)((a0[kc*2+1].w-mean0)*rs0*g1.w + bl1.w);
    f1[0] = (f16)((a1[kc*2].x  -mean1)*rs1*g0.x + bl0.x);
    f1[1] = (f16)((a1[kc*2].y  -mean1)*rs1*g0.y + bl0.y);
    f1[2] = (f16)((a1[kc*2].z  -mean1)*rs1*g0.z + bl0.z);
    f1[3] = (f16)((a1[kc*2].w  -mean1)*rs1*g0.w + bl0.w);
    f1[4] = (f16)((a1[kc*2+1].x-mean1)*rs1*g1.x + bl1.x);
    f1[5] = (f16)((a1[kc*2+1].y-mean1)*rs1*g1.y + bl1.y);
    f1[6] = (f16)((a1[kc*2+1].z-mean1)*rs1*g1.z + bl1.z);
    f1[7] = (f16)((a1[kc*2+1].w-mean1)*rs1*g1.w + bl1.w);
    af0[kc] = f0; af1[kc] = f1;
  }
  f32x4 acc[2][4] = {};
#pragma unroll
  for (int kc = 0; kc < 4; kc++) {
    const f16* bBase = Bsw + ((size_t)(kc*4 + qd)*Nd + n0 + r16)*8;
    f16x8 bf[4];
#pragma unroll
    for (int nt = 0; nt < 4; nt++) bf[nt] = *(const f16x8*)(bBase + nt*16*8);
#pragma unroll
    for (int nt = 0; nt < 4; nt++) {
      acc[0][nt] = __builtin_amdgcn_mfma_f32_16x16x32_f16(af0[kc], bf[nt], acc[0][nt], 0, 0, 0);
      acc[1][nt] = __builtin_amdgcn_mfma_f32_16x16x32_f16(af1[kc], bf[nt], acc[1][nt], 0, 0, 0);
    }
  }
#pragma unroll
  for (int mt = 0; mt < 2; mt++) {
#pragma unroll
    for (int nt = 0; nt < 4; nt++) {
      int col = n0 + nt*16 + r16;
      float bj = bias[col];
#pragma unroll
      for (int r = 0; r < 4; r++) {
        int row = m0 + mt*16 + qd*4 + r;
        float v = acc[mt][nt][r] + bj;
        if (MODE == 1) {
          ((f16*)Cv)[(size_t)row*Nd + col] = (f16)fmaxf(v, 0.f);
        } else {  // MODE 3: q|pk|pv fp16 + qW f32
          int third = col >> 8, cl = col & 255;
          if (third < 3)
            ((f16*)Cv)[(size_t)third*NRES*QDIM + (size_t)row*QDIM + cl] = (f16)v;
          else
            C2[(size_t)row*256 + cl] = v;
        }
      }
    }
  }
}

// ---------------- MFMA GEMM 16x64 wave tile, f32 C += AB + bias (Wo, N=128) ----------------
__global__ __launch_bounds__(256) void gemm_mfma16(const f16* __restrict__ A,
    const f16* __restrict__ Bsw, const float* __restrict__ bias,
    float* __restrict__ C, int Kd, int Nd) {
  int w = blockIdx.x * 4 + (threadIdx.x >> 6);
  int lane = threadIdx.x & 63;
  int wm = w & 511, wn = w >> 9;
  int m0 = wm * 16, n0 = wn * 64;
  int r16 = lane & 15, qd = lane >> 4;
  f32x4 acc[4] = {};
  const f16* aBase = A + (size_t)(m0 + r16)*Kd + qd*8;
  for (int kc = 0; kc < Kd; kc += 32) {
    f16x8 af = *(const f16x8*)(aBase + kc);
    const f16* bBase = Bsw + ((size_t)((kc>>3) + qd)*Nd + n0 + r16)*8;
#pragma unroll
    for (int nt = 0; nt < 4; nt++) {
      f16x8 bf = *(const f16x8*)(bBase + nt*16*8);
      acc[nt] = __builtin_amdgcn_mfma_f32_16x16x32_f16(af, bf, acc[nt], 0, 0, 0);
    }
  }
#pragma unroll
  for (int nt = 0; nt < 4; nt++) {
    int col = n0 + nt*16 + r16;
    float bj = bias[col];
#pragma unroll
    for (int r = 0; r < 4; r++) {
      int row = m0 + qd*4 + r;
      C[(size_t)row*Nd + col] += acc[nt][r] + bj;
    }
  }
}

// ---------------- fused FFN: LN2 + W1(relu) + W2(relu) + W3 + residual, one kernel ----------------
// 16-row tile per block, 4 waves. h1/h2 tiles live in LDS (row stride 520 halves: pad 8 -> 2-way
// bank aliasing only). Numerics identical to the unfused chain (same fp16 rounding points,
// same kc accumulation order).
__global__ __launch_bounds__(256) void ffn_kernel(const float* __restrict__ xin,
    const float* __restrict__ lng, const float* __restrict__ lnb,
    const f16* __restrict__ w1sw, const float* __restrict__ b1,
    const f16* __restrict__ w2sw, const float* __restrict__ b2,
    const f16* __restrict__ w3sw, const float* __restrict__ b3,
    float* __restrict__ xout) {
  __shared__ f16 h1s[16][520];
  __shared__ f16 h2s[16][520];
  int wv = threadIdx.x >> 6;
  int lane = threadIdx.x & 63;
  int m0 = blockIdx.x * 16;
  int r16 = lane & 15, qd = lane >> 4;

  // LN on this block's 16 rows (each lane: row r16, 32 channels)
  const float* rp = xin + (size_t)(m0 + r16)*SDIM + qd*8;
  float4 a0[8];
#pragma unroll
  for (int kc = 0; kc < 4; kc++) {
    a0[kc*2+0] = *(const float4*)(rp + kc*32);
    a0[kc*2+1] = *(const float4*)(rp + kc*32 + 4);
  }
  float s0 = 0.f;
#pragma unroll
  for (int c = 0; c < 8; c++) s0 += a0[c].x + a0[c].y + a0[c].z + a0[c].w;
  s0 += __shfl_xor(s0, 16, 64); s0 += __shfl_xor(s0, 32, 64);
  float mean0 = s0 * (1.f/128.f);
  float v0 = 0.f;
#pragma unroll
  for (int c = 0; c < 8; c++) {
    float dx = a0[c].x-mean0, dy = a0[c].y-mean0, dz = a0[c].z-mean0, dw = a0[c].w-mean0;
    v0 += dx*dx + dy*dy + dz*dz + dw*dw;
  }
  v0 += __shfl_xor(v0, 16, 64); v0 += __shfl_xor(v0, 32, 64);
  float rs0 = rsqrtf(v0 * (1.f/128.f) + 1e-5f);
  f16x8 af[4];
#pragma unroll
  for (int kc = 0; kc < 4; kc++) {
    float4 g0 = *(const float4*)(lng + qd*8 + kc*32);
    float4 g1 = *(const float4*)(lng + qd*8 + kc*32 + 4);
    float4 bl0 = *(const float4*)(lnb + qd*8 + kc*32);
    float4 bl1 = *(const float4*)(lnb + qd*8 + kc*32 + 4);
    f16x8 f0;
    f0[0] = (f16)((a0[kc*2].x  -mean0)*rs0*g0.x + bl0.x);
    f0[1] = (f16)((a0[kc*2].y  -mean0)*rs0*g0.y + bl0.y);
    f0[2] = (f16)((a0[kc*2].z  -mean0)*rs0*g0.z + bl0.z);
    f0[3] = (f16)((a0[kc*2].w  -mean0)*rs0*g0.w + bl0.w);
    f0[4] = (f16)((a0[kc*2+1].x-mean0)*rs0*g1.x + bl1.x);
    f0[5] = (f16)((a0[kc*2+1].y-mean0)*rs0*g1.y + bl1.y);
    f0[6] = (f16)((a0[kc*2+1].z-mean0)*rs0*g1.z + bl1.z);
    f0[7] = (f16)((a0[kc*2+1].w-mean0)*rs0*g1.w + bl1.w);
    af[kc] = f0;
  }
  // stage A: h1 cols [wv*128, +128)
  {
    f32x4 acc[8] = {};
#pragma unroll
    for (int kc = 0; kc < 4; kc++) {
      const f16* bBase = w1sw + ((size_t)(kc*4 + qd)*HIDD + wv*128 + r16)*8;
#pragma unroll
      for (int nt = 0; nt < 8; nt++) {
        f16x8 bf = *(const f16x8*)(bBase + nt*16*8);
        acc[nt] = __builtin_amdgcn_mfma_f32_16x16x32_f16(af[kc], bf, acc[nt], 0, 0, 0);
      }
    }
#pragma unroll
    for (int nt = 0; nt < 8; nt++) {
      int col = wv*128 + nt*16 + r16;
      float bj = b1[col];
#pragma unroll
      for (int r = 0; r < 4; r++)
        h1s[qd*4 + r][col] = (f16)fmaxf(acc[nt][r] + bj, 0.f);
    }
  }
  __syncthreads();
  // stage B: h2 cols [wv*128, +128), K=512 from LDS h1
  {
    f32x4 acc[8] = {};
    for (int kc = 0; kc < 16; kc++) {
      f16x8 a = *(const f16x8*)&h1s[r16][qd*8 + kc*32];
      const f16* bBase = w2sw + ((size_t)(kc*4 + qd)*HIDD + wv*128 + r16)*8;
#pragma unroll
      for (int nt = 0; nt < 8; nt++) {
        f16x8 bf = *(const f16x8*)(bBase + nt*16*8);
        acc[nt] = __builtin_amdgcn_mfma_f32_16x16x32_f16(a, bf, acc[nt], 0, 0, 0);
      }
    }
#pragma unroll
    for (int nt = 0; nt < 8; nt++) {
      int col = wv*128 + nt*16 + r16;
      float bj = b2[col];
#pragma unroll
      for (int r = 0; r < 4; r++)
        h2s[qd*4 + r][col] = (f16)fmaxf(acc[nt][r] + bj, 0.f);
    }
  }
  __syncthreads();
  // stage C: out cols [wv*32, +32), K=512 from LDS h2, residual into xout
  {
    f32x4 acc[2] = {};
    for (int kc = 0; kc < 16; kc++) {
      f16x8 a = *(const f16x8*)&h2s[r16][qd*8 + kc*32];
      const f16* bBase = w3sw + ((size_t)(kc*4 + qd)*SDIM + wv*32 + r16)*8;
#pragma unroll
      for (int nt = 0; nt < 2; nt++) {
        f16x8 bf = *(const f16x8*)(bBase + nt*16*8);
        acc[nt] = __builtin_amdgcn_mfma_f32_16x16x32_f16(a, bf, acc[nt], 0, 0, 0);
      }
    }
#pragma unroll
    for (int nt = 0; nt < 2; nt++) {
      int col = wv*32 + nt*16 + r16;
      float bj = b3[col];
#pragma unroll
      for (int r = 0; r < 4; r++) {
        int row = m0 + qd*4 + r;
        xout[(size_t)row*SDIM + col] += acc[nt][r] + bj;
      }
    }
  }
}

// ---------------- fused attention: ONE WAVE PER NODE, barrier-free ----------------
__global__ __launch_bounds__(256) void attn_kernel(const f16* __restrict__ q,
    const f16* __restrict__ pk, const f16* __restrict__ pv,
    const f16* __restrict__ edges, const int* __restrict__ structure,
    const float* __restrict__ qW, const float* __restrict__ WvB,
    const float* __restrict__ bv, f16* __restrict__ att) {
  int t = threadIdx.x;
  int n = blockIdx.x*4 + (t >> 6);
  int lane = t & 63;
  int h = lane >> 3, i = lane & 7, base = h << 3;

  int s[KNB];
#pragma unroll
  for (int kk = 0; kk < KNB; kk++) s[kk] = structure[n*KNB + kk];
  const f16x4* pk4 = (const f16x4*)pk;
  const f16x4* pv4 = (const f16x4*)pv;
  f16x4 pks[KNB], pvs[KNB];
#pragma unroll
  for (int kk = 0; kk < KNB; kk++) pks[kk] = pk4[(size_t)s[kk]*64 + lane];
#pragma unroll
  for (int kk = 0; kk < KNB; kk++) pvs[kk] = pv4[(size_t)s[kk]*64 + lane];
  f16x4 q4 = ((const f16x4*)q)[(size_t)n*64 + lane];

  const float* qwr = qW + (size_t)n*256 + h*25;
  float qbias = qwr[24];
  float elA = qbias, elB = qbias;
  {
    const f16x2* eA = (const f16x2*)(edges + (size_t)n*KNB*EDIM + i*EDIM);
#pragma unroll
    for (int j2 = 0; j2 < 12; j2++) {
      f16x2 e2 = eA[j2];
      elA += qwr[2*j2]*(float)e2.x + qwr[2*j2+1]*(float)e2.y;
    }
  }
  if (i < 7) {
    const f16x2* eB = (const f16x2*)(edges + (size_t)n*KNB*EDIM + (i+8)*EDIM);
#pragma unroll
    for (int j2 = 0; j2 < 12; j2++) {
      f16x2 e2 = eB[j2];
      elB += qwr[2*j2]*(float)e2.x + qwr[2*j2+1]*(float)e2.y;
    }
  }

  float dot[KNB];
  f16x2 qlo; qlo.x = q4.x; qlo.y = q4.y;
  f16x2 qhi; qhi.x = q4.z; qhi.y = q4.w;
#pragma unroll
  for (int kk = 0; kk < KNB; kk++) {
    f16x2 plo; plo.x = pks[kk].x; plo.y = pks[kk].y;
    f16x2 phi; phi.x = pks[kk].z; phi.y = pks[kk].w;
    float p = FDOT2(qlo, plo, 0.f);
    p = FDOT2(qhi, phi, p);
    p += __shfl_xor(p, 4, 64);
    p += __shfl_xor(p, 2, 64);
    p += __shfl_xor(p, 1, 64);
    dot[kk] = p;
  }

  float logit[KNB];
#pragma unroll
  for (int kk = 0; kk < 8; kk++) {
    float el = __shfl(elA, base + kk, 64);
    logit[kk] = (dot[kk] + el) * 0.17677669529663687f;
  }
#pragma unroll
  for (int kk = 8; kk < KNB; kk++) {
    float el = __shfl(elB, base + (kk - 8), 64);
    logit[kk] = (dot[kk] + el) * 0.17677669529663687f;
  }

  float mx = -1e30f;
#pragma unroll
  for (int kk = 0; kk < KNB; kk++) mx = fmaxf(mx, logit[kk]);
  float attw[KNB]; float sum = 0.f;
#pragma unroll
  for (int kk = 0; kk < KNB; kk++) { attw[kk] = expf(logit[kk] - mx); sum += attw[kk]; }
  float inv = 1.f / sum;
#pragma unroll
  for (int kk = 0; kk < KNB; kk++) attw[kk] *= inv;

  float4 o = ((const float4*)bv)[lane];
#pragma unroll
  for (int kk = 0; kk < KNB; kk++) {
    float a = attw[kk];
    o.x += a * (float)pvs[kk].x;
    o.y += a * (float)pvs[kk].y;
    o.z += a * (float)pvs[kk].z;
    o.w += a * (float)pvs[kk].w;
  }

  const f16* ebase = edges + (size_t)n*KNB*EDIM;
  float ew0 = 0.f, ew1 = 0.f, ew2 = 0.f;
#pragma unroll
  for (int kk = 0; kk < KNB; kk++) {
    float a = attw[kk];
    ew0 += a * (float)ebase[kk*EDIM + 3*i + 0];
    ew1 += a * (float)ebase[kk*EDIM + 3*i + 1];
    ew2 += a * (float)ebase[kk*EDIM + 3*i + 2];
  }

#pragma unroll
  for (int src = 0; src < 8; src++) {
    float w0 = __shfl(ew0, base + src, 64);
    float w1 = __shfl(ew1, base + src, 64);
    float w2 = __shfl(ew2, base + src, 64);
    float4 wv0 = ((const float4*)(WvB + (size_t)(3*src + 0)*QDIM))[lane];
    float4 wv1 = ((const float4*)(WvB + (size_t)(3*src + 1)*QDIM))[lane];
    float4 wv2 = ((const float4*)(WvB + (size_t)(3*src + 2)*QDIM))[lane];
    o.x += w0*wv0.x + w1*wv1.x + w2*wv2.x;
    o.y += w0*wv0.y + w1*wv1.y + w2*wv2.y;
    o.z += w0*wv0.z + w1*wv1.z + w2*wv2.z;
    o.w += w0*wv0.w + w1*wv1.w + w2*wv2.w;
  }

  f16x4 ov; ov.x = (f16)o.x; ov.y = (f16)o.y; ov.z = (f16)o.z; ov.w = (f16)o.w;
  ((f16x4*)att)[(size_t)n*64 + lane] = ov;
}

// ---------------- output head (f32 output) ----------------
__global__ __launch_bounds__(128) void head_kernel(const float* __restrict__ enc,
    const float* Ws, const float* bs, const float* Wc, const float* bc,
    const float* Wconc, const float* bconc, const float* Wwt, const float* bwt,
    const float* Wfac, const float* bfac, const float* __restrict__ angles, float* __restrict__ out) {
  int n = blockIdx.x, t = threadIdx.x;
  __shared__ float es[128];
  __shared__ float outs[103];
  es[t] = enc[(size_t)n*SDIM + t];
  __syncthreads();
  const float* W = nullptr; const float* bb = nullptr; int col = 0, nc = 0;
  if (t < 30)       { W = Ws;    bb = bs;    col = t;       nc = 30; }
  else if (t < 60)  { W = Wc;    bb = bc;    col = t - 30;  nc = 30; }
  else if (t < 90)  { W = Wconc; bb = bconc; col = t - 60;  nc = 30; }
  else if (t < 100) { W = Wwt;   bb = bwt;   col = t - 90;  nc = 10; }
  else if (t < 103) { W = Wfac;  bb = bfac;  col = t - 100; nc = 3;  }
  if (W) {
    float acc = bb[col];
    for (int j = 0; j < 128; j++) acc += es[j] * W[j*nc + col];
    outs[t] = acc;
  }
  __syncthreads();
  if (t < MIXN) {
    float mx = -1e30f;
    for (int m = 0; m < MIXN; m++) mx = fmaxf(mx, outs[90 + m]);
    float sum = 0.f;
    for (int m = 0; m < MIXN; m++) sum += expf(outs[90 + m] - mx);
    out[(size_t)n*MIXN + t] = expf(outs[90 + t] - mx) / sum;
  }
  if (t < 30) {
    int j = t / 10;
    float v = atan2f(outs[t], outs[30 + t]);
    float a0 = angles[n*3 + 0], a1 = angles[n*3 + 1];
    if (j == 1) v += outs[100] * a0;
    if (j == 2) v += outs[101] * a0 + outs[102] * a1;
    out[(size_t)NRES*MIXN + (size_t)n*30 + t] = v;
    float z = outs[60 + t];
    float sg = 1.f / (1.f + expf(-z));
    out[(size_t)NRES*MIXN + (size_t)NRES*30 + (size_t)n*30 + t] = 0.1f + 1000.f * sg;
  }
}

// ---------------- launch ----------------
extern "C" void kernel_launch(void* const* d_in, const int* in_sizes, int n_in,
                              void* d_out, int out_size, void* d_ws, size_t ws_size,
                              hipStream_t stream) {
  const float* angles   = (const float*)d_in[0];
  const float* tertiary = (const float*)d_in[1];
  const int*   structure = (const int*)d_in[2];
  const float* W_in  = (const float*)d_in[4];  const float* b_in  = (const float*)d_in[5];
  const float* W_pre = (const float*)d_in[6];  const float* b_pre = (const float*)d_in[7];
  const float* ln1_g = (const float*)d_in[8];  const float* ln1_b = (const float*)d_in[9];
  const float* ln2_g = (const float*)d_in[10]; const float* ln2_b = (const float*)d_in[11];
  const float* Wq = (const float*)d_in[12]; const float* bq = (const float*)d_in[13];
  const float* Wk = (const float*)d_in[14]; const float* bk = (const float*)d_in[15];
  const float* Wv = (const float*)d_in[16]; const float* bv = (const float*)d_in[17];
  const float* Wo = (const float*)d_in[18]; const float* bo = (const float*)d_in[19];
  const float* W1 = (const float*)d_in[20]; const float* b1 = (const float*)d_in[21];
  const float* W2 = (const float*)d_in[22]; const float* b2 = (const float*)d_in[23];
  const float* W3 = (const float*)d_in[24]; const float* b3 = (const float*)d_in[25];
  const float* Ws = (const float*)d_in[26]; const float* bs = (const float*)d_in[27];
  const float* Wc = (const float*)d_in[28]; const float* bc = (const float*)d_in[29];
  const float* Wconc = (const float*)d_in[30]; const float* bconc = (const float*)d_in[31];
  const float* Wwt = (const float*)d_in[32]; const float* bwt = (const float*)d_in[33];
  const float* Wfac = (const float*)d_in[34]; const float* bfac = (const float*)d_in[35];

  // workspace layout (bytes); high-water ~38.9 MB
  char* wsb = (char*)d_ws;
  float* Rm    = (float*)(wsb + 0);           //   294,912 B
  f16*   edg_h = (f16*)  (wsb + 294912);      // 5,898,240 B
  float* x     = (float*)(wsb + 6193152);     // 4 MiB f32 residual
  f16*   att_h = (f16*)  (wsb + 10387456);    // 4 MiB
  f16*   qh    = (f16*)  (wsb + 14581760);    // 4 MiB (q | pk | pv contiguous fp16)
  f16*   pkh   = (f16*)  (wsb + 18776064);    // 4 MiB
  f16*   pvh   = (f16*)  (wsb + 22970368);    // 4 MiB
  size_t qkvwOff = 27164672;                  //   786,432 B (3 x 128x1024 swizzled)
  size_t w1wOff  = 27951104;                  //   393,216 B
  size_t w2wOff  = 28344320;                  // 1,572,864 B
  size_t w3wOff  = 29917184;                  //   393,216 B
  size_t wowOff  = 30310400;                  //   196,608 B
  f16*   qkvw  = (f16*)(wsb + qkvwOff);
  f16*   w1w   = (f16*)(wsb + w1wOff);
  f16*   w2w   = (f16*)(wsb + w2wOff);
  f16*   w3w   = (f16*)(wsb + w3wOff);
  f16*   wow   = (f16*)(wsb + wowOff);
  float* b1024 = (float*)(wsb + 30507008);    //    12,288 B
  float* qWb   = (float*)(wsb + 30519296);    // 8,388,608 B f32 [8192][256] -> 38,907,904

  frames_kernel<<<dim3((NRES+255)/256), dim3(256), 0, stream>>>(tertiary, Rm);
  edges_kernel<<<dim3((NRES*KNB+255)/256), dim3(256), 0, stream>>>(tertiary, Rm, structure, edg_h);
  init_kernel<<<dim3(NRES), dim3(128), 0, stream>>>(angles, W_in, b_in, W_pre, b_pre, x);

  SwzJobs jobs;
  jobs.j[0] = { Wq, SDIM*QDIM,        QDIM, 128, 256, qkvwOff, 131072, 1024, 0   };
  jobs.j[1] = { Wk, (SDIM+EDIM)*QDIM, QDIM, 128, 256, qkvwOff, 131072, 1024, 256 };
  jobs.j[2] = { Wv, (SDIM+EDIM)*QDIM, QDIM, 128, 256, qkvwOff, 131072, 1024, 512 };
  jobs.j[3] = { W1, SDIM*HIDD, HIDD, 128, 512, w1wOff, 65536,  512, 0 };
  jobs.j[4] = { W2, HIDD*HIDD, HIDD, 512, 512, w2wOff, 262144, 512, 0 };
  jobs.j[5] = { W3, HIDD*SDIM, SDIM, 512, 128, w3wOff, 65536,  128, 0 };
  jobs.j[6] = { Wo, QDIM*SDIM, SDIM, 256, 128, wowOff, 32768,  128, 0 };
  convswz_all<<<dim3(64, 7, 3), dim3(256), 0, stream>>>(jobs, wsb);
  wcomb_kernel<<<768, 128, 0, stream>>>(Wq, bq, Wk, bk, qkvw, b1024);

  for (int d = 0; d < 3; ++d) {
    const float* WvD = Wv + (size_t)d*(SDIM+EDIM)*QDIM;
    // LN1 + q|pk|pv + qW in one GEMM (Nd=1024)
    gemm_ln_mfma<3><<<1024, 256, 0, stream>>>(x, ln1_g + d*SDIM, ln1_b + d*SDIM,
        qkvw + (size_t)d*131072, b1024 + d*1024, qh, qWb, 1024);
    attn_kernel<<<dim3(NRES/4), dim3(256), 0, stream>>>(qh, pkh, pvh, edg_h, structure,
        qWb, WvD + (size_t)SDIM*QDIM, bv + d*QDIM, att_h);
    gemm_mfma16<<<256, 256, 0, stream>>>(att_h, wow + (size_t)d*32768, bo + d*SDIM, x, 256, 128);
    // LN2 + W1 + W2 + W3 + residual, one kernel
    ffn_kernel<<<dim3(NRES/16), dim3(256), 0, stream>>>(x, ln2_g + d*SDIM, ln2_b + d*SDIM,
        w1w + (size_t)d*65536, b1 + d*HIDD,
        w2w + (size_t)d*262144, b2 + d*HIDD,
        w3w + (size_t)d*65536, b3 + d*SDIM, x);
  }

  head_kernel<<<dim3(NRES), dim3(128), 0, stream>>>(x, Ws, bs, Wc, bc, Wconc, bconc,
      Wwt, bwt, Wfac, bfac, angles, (float*)d_out);
}

// Round 14
// 416.002 us; speedup vs baseline: 1.6955x; 1.0563x over previous
//
#include <hip/hip_runtime.h>
#include <hip/hip_bf16.h>
#include <stdint.h>

// Problem constants
#define NRES 8192
#define KNB  15
#define SDIM 128
#define EDIM 24
#define HIDD 512
#define NH   8
#define QDIM 256   // H*A
#define MIXN 10

typedef _Float16 f16;
typedef _Float16 f16x8 __attribute__((ext_vector_type(8)));
typedef _Float16 f16x4 __attribute__((ext_vector_type(4)));
typedef _Float16 f16x2 __attribute__((ext_vector_type(2)));
typedef float f32x4 __attribute__((ext_vector_type(4)));

#if __has_builtin(__builtin_amdgcn_fdot2)
#define FDOT2(a,b,c) __builtin_amdgcn_fdot2((a),(b),(c),false)
#else
#define FDOT2(a,b,c) ((c) + (float)(a).x*(float)(b).x + (float)(a).y*(float)(b).y)
#endif

struct F3 { float x, y, z; };
__device__ __forceinline__ F3 f3sub(F3 a, F3 b) { return {a.x-b.x, a.y-b.y, a.z-b.z}; }
__device__ __forceinline__ F3 f3cross(F3 a, F3 b) {
  return {a.y*b.z - a.z*b.y, a.z*b.x - a.x*b.z, a.x*b.y - a.y*b.x};
}
__device__ __forceinline__ F3 f3norm(F3 a) {
  float l = sqrtf(a.x*a.x + a.y*a.y + a.z*a.z) + 1e-8f;
  float r = 1.f / l;
  return {a.x*r, a.y*r, a.z*r};
}
__device__ __forceinline__ F3 ldter(const float* t, int i) {
  return {t[i*9+3], t[i*9+4], t[i*9+5]};
}

// ---------------- geometry (reads pos directly out of tertiary) ----------------
__global__ void frames_kernel(const float* __restrict__ tert, float* __restrict__ R) {
  int m = blockIdx.x * blockDim.x + threadIdx.x;
  if (m >= NRES) return;
  int s = m - 1; if (s < 0) s = 0; if (s > NRES-3) s = NRES-3;
  F3 p0 = ldter(tert, s), p1 = ldter(tert, s+1), p2 = ldter(tert, s+2);
  F3 u0 = f3norm(f3sub(p1, p0));
  F3 u1 = f3norm(f3sub(p2, p1));
  F3 b  = f3norm(f3sub(u0, u1));
  F3 nn = f3norm(f3cross(u0, u1));
  F3 o  = f3cross(b, nn);
  float* r = R + m*9;
  r[0]=b.x; r[1]=nn.x; r[2]=o.x;
  r[3]=b.y; r[4]=nn.y; r[5]=o.y;
  r[6]=b.z; r[7]=nn.z; r[8]=o.z;
}

__device__ __forceinline__ float quat_comp(float t, float a, float b) {
  float s = (a > b) ? 1.f : ((a < b) ? -1.f : 0.f);
  return 0.5f * sqrtf(fmaxf(1e-8f, t)) * s;
}

__global__ void edges_kernel(const float* __restrict__ tert, const float* __restrict__ R,
                             const int* __restrict__ structure, f16* __restrict__ edges) {
  int id = blockIdx.x * blockDim.x + threadIdx.x;
  if (id >= NRES*KNB) return;
  int n = id / KNB;
  int tprev = (n - 1) & (NRES - 1);
  int sidx = structure[id];
  F3 pt = ldter(tert, tprev), ps = ldter(tert, sidx);
  F3 dv = f3sub(ps, pt);
  float dist = sqrtf(dv.x*dv.x + dv.y*dv.y + dv.z*dv.z);
  float rinv = 1.f / (dist + 1e-8f);
  F3 dh = {dv.x*rinv, dv.y*rinv, dv.z*rinv};
  float Rt[9], Rs[9];
#pragma unroll
  for (int i = 0; i < 9; i++) { Rt[i] = R[tprev*9+i]; Rs[i] = R[sidx*9+i]; }
  float dir[3];
#pragma unroll
  for (int i = 0; i < 3; i++) dir[i] = Rt[i]*dh.x + Rt[3+i]*dh.y + Rt[6+i]*dh.z;
  float Rr[9];
#pragma unroll
  for (int i = 0; i < 3; i++)
#pragma unroll
    for (int l = 0; l < 3; l++)
      Rr[i*3+l] = Rt[i]*Rs[l] + Rt[3+i]*Rs[3+l] + Rt[6+i]*Rs[6+l];
  float m00 = Rr[0], m11 = Rr[4], m22 = Rr[8];
  float qw = 0.5f * sqrtf(fmaxf(1e-8f, 1.f + m00 + m11 + m22));
  float qx = quat_comp(1.f + m00 - m11 - m22, Rr[7], Rr[5]);
  float qy = quat_comp(1.f - m00 + m11 - m22, Rr[2], Rr[6]);
  float qz = quat_comp(1.f - m00 - m11 + m22, Rr[3], Rr[1]);
  f16* e = edges + (size_t)id * EDIM;
#pragma unroll
  for (int j = 0; j < 16; j++) {
    float mu = (20.f / 15.f) * j;            // linspace(0,20,16)
    float zz = (dist - mu) * (1.f / 1.25f);  // sigma = 20/16
    e[j] = (f16)expf(-zz*zz);
  }
  e[16] = (f16)dir[0]; e[17] = (f16)dir[1]; e[18] = (f16)dir[2];
  e[19] = (f16)qw; e[20] = (f16)qx; e[21] = (f16)qy; e[22] = (f16)qz;
  e[23] = (f16)((float)(sidx - tprev) * 0.01f);
}

// ---------------- input embedding ----------------
__global__ __launch_bounds__(128) void init_kernel(const float* __restrict__ angles,
    const float* __restrict__ W_in, const float* __restrict__ b_in,
    const float* __restrict__ W_pre, const float* __restrict__ b_pre, float* __restrict__ x) {
  int n = blockIdx.x, c = threadIdx.x;
  __shared__ float fs[128];
  float af[6];
  if (n == 0) { af[0]=af[1]=af[2]=0.f; af[3]=af[4]=af[5]=1.f; }
  else {
#pragma unroll
    for (int j = 0; j < 3; j++) {
      float p = angles[(n-1)*3 + j];
      af[j] = sinf(p); af[3+j] = cosf(p);
    }
  }
  float f = b_in[c];
#pragma unroll
  for (int j = 0; j < 6; j++) f += af[j] * W_in[j*SDIM + c];
  fs[c] = f;
  __syncthreads();
  float xv = b_pre[c];
  for (int j = 0; j < 128; j++) xv += fs[j] * W_pre[j*SDIM + c];
  x[(size_t)n*SDIM + c] = xv;
}

// ---------------- all weight convert+swizzle jobs in ONE dispatch ----------------
struct SwzJob { const float* src; int srcStride, srcLd, K, N; size_t dstOff; int dstLayerHalves, dstN, colOff; };
struct SwzJobs { SwzJob j[7]; };
__global__ void convswz_all(SwzJobs jobs, char* __restrict__ wsb) {
  SwzJob jb = jobs.j[blockIdx.y];
  int d = blockIdx.z;
  const float* s = jb.src + (size_t)d * jb.srcStride;
  f16* o = (f16*)(wsb + jb.dstOff) + (size_t)d * jb.dstLayerHalves;
  int tot = jb.K * jb.N;
  for (int i = blockIdx.x*blockDim.x + threadIdx.x; i < tot; i += gridDim.x*blockDim.x) {
    int k = i / jb.N, n = i - k*jb.N;
    o[((size_t)(k>>3)*jb.dstN + jb.colOff + n)*8 + (k&7)] = (f16)s[(size_t)k*jb.srcLd + n];
  }
}

// Wcomb = Wq @ Wd (per-head-masked WkB|bk) -> cols 768..1024 of qkv swizzled B; also fills b1024.
__global__ __launch_bounds__(128) void wcomb_kernel(const float* __restrict__ Wq,
    const float* __restrict__ bq, const float* __restrict__ Wk, const float* __restrict__ bk,
    f16* __restrict__ qkvw, float* __restrict__ b1024) {
  int blk = blockIdx.x;          // d*256 + col
  int d = blk >> 8, col = blk & 255;
  int k = threadIdx.x;           // 0..127
  float acc = 0.f, bacc = 0.f;
  if (col < 200) {
    int h = col / 25, jj = col % 25;
    const float* WkB = Wk + (size_t)d*(SDIM+EDIM)*QDIM + (size_t)SDIM*QDIM;
    const float* wqrow = Wq + (size_t)d*SDIM*QDIM + (size_t)k*QDIM;
    int r0 = h*32;
    for (int rr = 0; rr < 32; rr++) {
      int r = r0 + rr;
      float wd = (jj < 24) ? WkB[(size_t)jj*QDIM + r] : bk[d*QDIM + r];
      acc += wqrow[r] * wd;
      if (k == 0) bacc += bq[d*QDIM + r] * wd;
    }
  }
  qkvw[(size_t)d*131072 + ((size_t)(k>>3)*1024 + 768 + col)*8 + (k&7)] = (f16)acc;
  if (k == 0) {
    b1024[d*1024 + col]       = bq[d*QDIM + col];
    b1024[d*1024 + 256 + col] = 0.f;
    b1024[d*1024 + 512 + col] = 0.f;
    b1024[d*1024 + 768 + col] = bacc;
  }
}

// ---------------- LN-fused MFMA GEMM: A = f32 x (8192x128), LN applied per row ----------------
// MODE 3: Nd=1024, cols 0..768 fp16 q|pk|pv split, cols 768..1024 f32 qW into C2 (stride 256).
template<int MODE>
__global__ __launch_bounds__(256) void gemm_ln_mfma(const float* __restrict__ A,
    const float* __restrict__ lng, const float* __restrict__ lnb,
    const f16* __restrict__ Bsw, const float* __restrict__ bias,
    void* __restrict__ Cv, float* __restrict__ C2, int Nd) {
  int w = blockIdx.x * 4 + (threadIdx.x >> 6);
  int lane = threadIdx.x & 63;
  int wm = w & 255, wn = w >> 8;
  int m0 = wm * 32, n0 = wn * 64;
  int r16 = lane & 15, qd = lane >> 4;
  const float* r0p = A + (size_t)(m0 + r16)*SDIM + qd*8;
  const float* r1p = r0p + (size_t)16*SDIM;
  float4 a0[8], a1[8];
#pragma unroll
  for (int kc = 0; kc < 4; kc++) {
    a0[kc*2+0] = *(const float4*)(r0p + kc*32);
    a0[kc*2+1] = *(const float4*)(r0p + kc*32 + 4);
    a1[kc*2+0] = *(const float4*)(r1p + kc*32);
    a1[kc*2+1] = *(const float4*)(r1p + kc*32 + 4);
  }
  float s0 = 0.f, s1 = 0.f;
#pragma unroll
  for (int c = 0; c < 8; c++) {
    s0 += a0[c].x + a0[c].y + a0[c].z + a0[c].w;
    s1 += a1[c].x + a1[c].y + a1[c].z + a1[c].w;
  }
  s0 += __shfl_xor(s0, 16, 64); s0 += __shfl_xor(s0, 32, 64);
  s1 += __shfl_xor(s1, 16, 64); s1 += __shfl_xor(s1, 32, 64);
  float mean0 = s0 * (1.f/128.f), mean1 = s1 * (1.f/128.f);
  float v0 = 0.f, v1 = 0.f;
#pragma unroll
  for (int c = 0; c < 8; c++) {
    float d0x = a0[c].x-mean0, d0y = a0[c].y-mean0, d0z = a0[c].z-mean0, d0w = a0[c].w-mean0;
    v0 += d0x*d0x + d0y*d0y + d0z*d0z + d0w*d0w;
    float d1x = a1[c].x-mean1, d1y = a1[c].y-mean1, d1z = a1[c].z-mean1, d1w = a1[c].w-mean1;
    v1 += d1x*d1x + d1y*d1y + d1z*d1z + d1w*d1w;
  }
  v0 += __shfl_xor(v0, 16, 64); v0 += __shfl_xor(v0, 32, 64);
  v1 += __shfl_xor(v1, 16, 64); v1 += __shfl_xor(v1, 32, 64);
  float rs0 = rsqrtf(v0 * (1.f/128.f) + 1e-5f);
  float rs1 = rsqrtf(v1 * (1.f/128.f) + 1e-5f);
  f16x8 af0[4], af1[4];
#pragma unroll
  for (int kc = 0; kc < 4; kc++) {
    float4 g0 = *(const float4*)(lng + qd*8 + kc*32);
    float4 g1 = *(const float4*)(lng + qd*8 + kc*32 + 4);
    float4 bl0 = *(const float4*)(lnb + qd*8 + kc*32);
    float4 bl1 = *(const float4*)(lnb + qd*8 + kc*32 + 4);
    f16x8 f0, f1;
    f0[0] = (f16)((a0[kc*2].x  -mean0)*rs0*g0.x + bl0.x);
    f0[1] = (f16)((a0[kc*2].y  -mean0)*rs0*g0.y + bl0.y);
    f0[2] = (f16)((a0[kc*2].z  -mean0)*rs0*g0.z + bl0.z);
    f0[3] = (f16)((a0[kc*2].w  -mean0)*rs0*g0.w + bl0.w);
    f0[4] = (f16)((a0[kc*2+1].x-mean0)*rs0*g1.x + bl1.x);
    f0[5] = (f16)((a0[kc*2+1].y-mean0)*rs0*g1.y + bl1.y);
    f0[6] = (f16)((a0[kc*2+1].z-mean0)*rs0*g1.z + bl1.z);
    f0[7] = (f16)((a0[kc*2+1].w-mean0)*rs0*g1.w + bl1.w);
    f1[0] = (f16)((a1[kc*2].x  -mean1)*rs1*g0.x + bl0.x);
    f1[1] = (f16)((a1[kc*2].y  -mean1)*rs1*g0.y + bl0.y);
    f1[2] = (f16)((a1[kc*2].z  -mean1)*rs1*g0.z + bl0.z);
    f1[3] = (f16)((a1[kc*2].w  -mean1)*rs1*g0.w + bl0.w);
    f1[4] = (f16)((a1[kc*2+1].x-mean1)*rs1*g1.x + bl1.x);
    f1[5] = (f16)((a1[kc*2+1].y-mean1)*rs1*g1.y + bl1.y);
    f1[6] = (f16)((a1[kc*2+1].z-mean1)*rs1*g1.z + bl1.z);
    f1[7] = (f16)((a1[kc*2+1].w-mean1)*rs1*g1.w + bl1.w);
    af0[kc] = f0; af1[kc] = f1;
  }
  f32x4 acc[2][4] = {};
#pragma unroll
  for (int kc = 0; kc < 4; kc++) {
    const f16* bBase = Bsw + ((size_t)(kc*4 + qd)*Nd + n0 + r16)*8;
    f16x8 bf[4];
#pragma unroll
    for (int nt = 0; nt < 4; nt++) bf[nt] = *(const f16x8*)(bBase + nt*16*8);
#pragma unroll
    for (int nt = 0; nt < 4; nt++) {
      acc[0][nt] = __builtin_amdgcn_mfma_f32_16x16x32_f16(af0[kc], bf[nt], acc[0][nt], 0, 0, 0);
      acc[1][nt] = __builtin_amdgcn_mfma_f32_16x16x32_f16(af1[kc], bf[nt], acc[1][nt], 0, 0, 0);
    }
  }
#pragma unroll
  for (int mt = 0; mt < 2; mt++) {
#pragma unroll
    for (int nt = 0; nt < 4; nt++) {
      int col = n0 + nt*16 + r16;
      float bj = bias[col];
#pragma unroll
      for (int r = 0; r < 4; r++) {
        int row = m0 + mt*16 + qd*4 + r;
        float v = acc[mt][nt][r] + bj;
        if (MODE == 1) {
          ((f16*)Cv)[(size_t)row*Nd + col] = (f16)fmaxf(v, 0.f);
        } else {  // MODE 3: q|pk|pv fp16 + qW f32
          int third = col >> 8, cl = col & 255;
          if (third < 3)
            ((f16*)Cv)[(size_t)third*NRES*QDIM + (size_t)row*QDIM + cl] = (f16)v;
          else
            C2[(size_t)row*256 + cl] = v;
        }
      }
    }
  }
}

// ---------------- fused Wo + LN2 + FFN + residual, one kernel ----------------
// 16-row tile per block, 4 waves. Stage 0: xs = x + att@Wo + bo (LDS f32, pad to 132).
// LN2 reads xs; W1/W2 hidden tiles in LDS fp16 (row stride 520); stage C writes x once.
// Numerics identical to the previous unfused chain (same kc orders, same rounding points).
__global__ __launch_bounds__(256) void ffn2_kernel(const f16* __restrict__ att,
    const f16* __restrict__ wosw, const float* __restrict__ bo,
    const float* __restrict__ xin,
    const float* __restrict__ lng, const float* __restrict__ lnb,
    const f16* __restrict__ w1sw, const float* __restrict__ b1,
    const f16* __restrict__ w2sw, const float* __restrict__ b2,
    const f16* __restrict__ w3sw, const float* __restrict__ b3,
    float* __restrict__ xout) {
  __shared__ float xs[16][132];
  __shared__ f16 h1s[16][520];
  __shared__ f16 h2s[16][520];
  int wv = threadIdx.x >> 6;
  int lane = threadIdx.x & 63;
  int m0 = blockIdx.x * 16;
  int r16 = lane & 15, qd = lane >> 4;

  // Stage 0: Wo projection, cols [wv*32, +32): xs = x + att@Wo + bo
  {
    f32x4 acc[2] = {};
    const f16* aBase = att + (size_t)(m0 + r16)*QDIM + qd*8;
    for (int kc = 0; kc < QDIM; kc += 32) {
      f16x8 af = *(const f16x8*)(aBase + kc);
      const f16* bBase = wosw + ((size_t)((kc>>3) + qd)*SDIM + wv*32 + r16)*8;
#pragma unroll
      for (int nt = 0; nt < 2; nt++) {
        f16x8 bf = *(const f16x8*)(bBase + nt*16*8);
        acc[nt] = __builtin_amdgcn_mfma_f32_16x16x32_f16(af, bf, acc[nt], 0, 0, 0);
      }
    }
#pragma unroll
    for (int nt = 0; nt < 2; nt++) {
      int col = wv*32 + nt*16 + r16;
      float bj = bo[col];
#pragma unroll
      for (int r = 0; r < 4; r++) {
        int rl = qd*4 + r;
        xs[rl][col] = xin[(size_t)(m0 + rl)*SDIM + col] + acc[nt][r] + bj;
      }
    }
  }
  __syncthreads();

  // LN on xs rows (each lane: row r16, 32 channels)
  float4 a0[8];
#pragma unroll
  for (int kc = 0; kc < 4; kc++) {
    a0[kc*2+0] = *(const float4*)&xs[r16][qd*8 + kc*32];
    a0[kc*2+1] = *(const float4*)&xs[r16][qd*8 + kc*32 + 4];
  }
  float s0 = 0.f;
#pragma unroll
  for (int c = 0; c < 8; c++) s0 += a0[c].x + a0[c].y + a0[c].z + a0[c].w;
  s0 += __shfl_xor(s0, 16, 64); s0 += __shfl_xor(s0, 32, 64);
  float mean0 = s0 * (1.f/128.f);
  float v0 = 0.f;
#pragma unroll
  for (int c = 0; c < 8; c++) {
    float dx = a0[c].x-mean0, dy = a0[c].y-mean0, dz = a0[c].z-mean0, dw = a0[c].w-mean0;
    v0 += dx*dx + dy*dy + dz*dz + dw*dw;
  }
  v0 += __shfl_xor(v0, 16, 64); v0 += __shfl_xor(v0, 32, 64);
  float rs0 = rsqrtf(v0 * (1.f/128.f) + 1e-5f);
  f16x8 af[4];
#pragma unroll
  for (int kc = 0; kc < 4; kc++) {
    float4 g0 = *(const float4*)(lng + qd*8 + kc*32);
    float4 g1 = *(const float4*)(lng + qd*8 + kc*32 + 4);
    float4 bl0 = *(const float4*)(lnb + qd*8 + kc*32);
    float4 bl1 = *(const float4*)(lnb + qd*8 + kc*32 + 4);
    f16x8 f0;
    f0[0] = (f16)((a0[kc*2].x  -mean0)*rs0*g0.x + bl0.x);
    f0[1] = (f16)((a0[kc*2].y  -mean0)*rs0*g0.y + bl0.y);
    f0[2] = (f16)((a0[kc*2].z  -mean0)*rs0*g0.z + bl0.z);
    f0[3] = (f16)((a0[kc*2].w  -mean0)*rs0*g0.w + bl0.w);
    f0[4] = (f16)((a0[kc*2+1].x-mean0)*rs0*g1.x + bl1.x);
    f0[5] = (f16)((a0[kc*2+1].y-mean0)*rs0*g1.y + bl1.y);
    f0[6] = (f16)((a0[kc*2+1].z-mean0)*rs0*g1.z + bl1.z);
    f0[7] = (f16)((a0[kc*2+1].w-mean0)*rs0*g1.w + bl1.w);
    af[kc] = f0;
  }
  // stage A: h1 cols [wv*128, +128)
  {
    f32x4 acc[8] = {};
#pragma unroll
    for (int kc = 0; kc < 4; kc++) {
      const f16* bBase = w1sw + ((size_t)(kc*4 + qd)*HIDD + wv*128 + r16)*8;
#pragma unroll
      for (int nt = 0; nt < 8; nt++) {
        f16x8 bf = *(const f16x8*)(bBase + nt*16*8);
        acc[nt] = __builtin_amdgcn_mfma_f32_16x16x32_f16(af[kc], bf, acc[nt], 0, 0, 0);
      }
    }
#pragma unroll
    for (int nt = 0; nt < 8; nt++) {
      int col = wv*128 + nt*16 + r16;
      float bj = b1[col];
#pragma unroll
      for (int r = 0; r < 4; r++)
        h1s[qd*4 + r][col] = (f16)fmaxf(acc[nt][r] + bj, 0.f);
    }
  }
  __syncthreads();
  // stage B: h2 cols [wv*128, +128), K=512 from LDS h1
  {
    f32x4 acc[8] = {};
    for (int kc = 0; kc < 16; kc++) {
      f16x8 a = *(const f16x8*)&h1s[r16][qd*8 + kc*32];
      const f16* bBase = w2sw + ((size_t)(kc*4 + qd)*HIDD + wv*128 + r16)*8;
#pragma unroll
      for (int nt = 0; nt < 8; nt++) {
        f16x8 bf = *(const f16x8*)(bBase + nt*16*8);
        acc[nt] = __builtin_amdgcn_mfma_f32_16x16x32_f16(a, bf, acc[nt], 0, 0, 0);
      }
    }
#pragma unroll
    for (int nt = 0; nt < 8; nt++) {
      int col = wv*128 + nt*16 + r16;
      float bj = b2[col];
#pragma unroll
      for (int r = 0; r < 4; r++)
        h2s[qd*4 + r][col] = (f16)fmaxf(acc[nt][r] + bj, 0.f);
    }
  }
  __syncthreads();
  // stage C: out cols [wv*32, +32), K=512 from LDS h2, write x = xs + W3 out + b3
  {
    f32x4 acc[2] = {};
    for (int kc = 0; kc < 16; kc++) {
      f16x8 a = *(const f16x8*)&h2s[r16][qd*8 + kc*32];
      const f16* bBase = w3sw + ((size_t)(kc*4 + qd)*SDIM + wv*32 + r16)*8;
#pragma unroll
      for (int nt = 0; nt < 2; nt++) {
        f16x8 bf = *(const f16x8*)(bBase + nt*16*8);
        acc[nt] = __builtin_amdgcn_mfma_f32_16x16x32_f16(a, bf, acc[nt], 0, 0, 0);
      }
    }
#pragma unroll
    for (int nt = 0; nt < 2; nt++) {
      int col = wv*32 + nt*16 + r16;
      float bj = b3[col];
#pragma unroll
      for (int r = 0; r < 4; r++) {
        int rl = qd*4 + r;
        xout[(size_t)(m0 + rl)*SDIM + col] = xs[rl][col] + acc[nt][r] + bj;
      }
    }
  }
}

// ---------------- fused attention: ONE WAVE PER NODE, barrier-free ----------------
__global__ __launch_bounds__(256) void attn_kernel(const f16* __restrict__ q,
    const f16* __restrict__ pk, const f16* __restrict__ pv,
    const f16* __restrict__ edges, const int* __restrict__ structure,
    const float* __restrict__ qW, const float* __restrict__ WvB,
    const float* __restrict__ bv, f16* __restrict__ att) {
  int t = threadIdx.x;
  int n = blockIdx.x*4 + (t >> 6);
  int lane = t & 63;
  int h = lane >> 3, i = lane & 7, base = h << 3;

  int s[KNB];
#pragma unroll
  for (int kk = 0; kk < KNB; kk++) s[kk] = structure[n*KNB + kk];
  const f16x4* pk4 = (const f16x4*)pk;
  const f16x4* pv4 = (const f16x4*)pv;
  f16x4 pks[KNB], pvs[KNB];
#pragma unroll
  for (int kk = 0; kk < KNB; kk++) pks[kk] = pk4[(size_t)s[kk]*64 + lane];
#pragma unroll
  for (int kk = 0; kk < KNB; kk++) pvs[kk] = pv4[(size_t)s[kk]*64 + lane];
  f16x4 q4 = ((const f16x4*)q)[(size_t)n*64 + lane];

  const float* qwr = qW + (size_t)n*256 + h*25;
  float qbias = qwr[24];
  float elA = qbias, elB = qbias;
  {
    const f16x2* eA = (const f16x2*)(edges + (size_t)n*KNB*EDIM + i*EDIM);
#pragma unroll
    for (int j2 = 0; j2 < 12; j2++) {
      f16x2 e2 = eA[j2];
      elA += qwr[2*j2]*(float)e2.x + qwr[2*j2+1]*(float)e2.y;
    }
  }
  if (i < 7) {
    const f16x2* eB = (const f16x2*)(edges + (size_t)n*KNB*EDIM + (i+8)*EDIM);
#pragma unroll
    for (int j2 = 0; j2 < 12; j2++) {
      f16x2 e2 = eB[j2];
      elB += qwr[2*j2]*(float)e2.x + qwr[2*j2+1]*(float)e2.y;
    }
  }

  float dot[KNB];
  f16x2 qlo; qlo.x = q4.x; qlo.y = q4.y;
  f16x2 qhi; qhi.x = q4.z; qhi.y = q4.w;
#pragma unroll
  for (int kk = 0; kk < KNB; kk++) {
    f16x2 plo; plo.x = pks[kk].x; plo.y = pks[kk].y;
    f16x2 phi; phi.x = pks[kk].z; phi.y = pks[kk].w;
    float p = FDOT2(qlo, plo, 0.f);
    p = FDOT2(qhi, phi, p);
    p += __shfl_xor(p, 4, 64);
    p += __shfl_xor(p, 2, 64);
    p += __shfl_xor(p, 1, 64);
    dot[kk] = p;
  }

  float logit[KNB];
#pragma unroll
  for (int kk = 0; kk < 8; kk++) {
    float el = __shfl(elA, base + kk, 64);
    logit[kk] = (dot[kk] + el) * 0.17677669529663687f;
  }
#pragma unroll
  for (int kk = 8; kk < KNB; kk++) {
    float el = __shfl(elB, base + (kk - 8), 64);
    logit[kk] = (dot[kk] + el) * 0.17677669529663687f;
  }

  float mx = -1e30f;
#pragma unroll
  for (int kk = 0; kk < KNB; kk++) mx = fmaxf(mx, logit[kk]);
  float attw[KNB]; float sum = 0.f;
#pragma unroll
  for (int kk = 0; kk < KNB; kk++) { attw[kk] = expf(logit[kk] - mx); sum += attw[kk]; }
  float inv = 1.f / sum;
#pragma unroll
  for (int kk = 0; kk < KNB; kk++) attw[kk] *= inv;

  float4 o = ((const float4*)bv)[lane];
#pragma unroll
  for (int kk = 0; kk < KNB; kk++) {
    float a = attw[kk];
    o.x += a * (float)pvs[kk].x;
    o.y += a * (float)pvs[kk].y;
    o.z += a * (float)pvs[kk].z;
    o.w += a * (float)pvs[kk].w;
  }

  const f16* ebase = edges + (size_t)n*KNB*EDIM;
  float ew0 = 0.f, ew1 = 0.f, ew2 = 0.f;
#pragma unroll
  for (int kk = 0; kk < KNB; kk++) {
    float a = attw[kk];
    ew0 += a * (float)ebase[kk*EDIM + 3*i + 0];
    ew1 += a * (float)ebase[kk*EDIM + 3*i + 1];
    ew2 += a * (float)ebase[kk*EDIM + 3*i + 2];
  }

#pragma unroll
  for (int src = 0; src < 8; src++) {
    float w0 = __shfl(ew0, base + src, 64);
    float w1 = __shfl(ew1, base + src, 64);
    float w2 = __shfl(ew2, base + src, 64);
    float4 wv0 = ((const float4*)(WvB + (size_t)(3*src + 0)*QDIM))[lane];
    float4 wv1 = ((const float4*)(WvB + (size_t)(3*src + 1)*QDIM))[lane];
    float4 wv2 = ((const float4*)(WvB + (size_t)(3*src + 2)*QDIM))[lane];
    o.x += w0*wv0.x + w1*wv1.x + w2*wv2.x;
    o.y += w0*wv0.y + w1*wv1.y + w2*wv2.y;
    o.z += w0*wv0.z + w1*wv1.z + w2*wv2.z;
    o.w += w0*wv0.w + w1*wv1.w + w2*wv2.w;
  }

  f16x4 ov; ov.x = (f16)o.x; ov.y = (f16)o.y; ov.z = (f16)o.z; ov.w = (f16)o.w;
  ((f16x4*)att)[(size_t)n*64 + lane] = ov;
}

// ---------------- output head (f32 output) ----------------
__global__ __launch_bounds__(128) void head_kernel(const float* __restrict__ enc,
    const float* Ws, const float* bs, const float* Wc, const float* bc,
    const float* Wconc, const float* bconc, const float* Wwt, const float* bwt,
    const float* Wfac, const float* bfac, const float* __restrict__ angles, float* __restrict__ out) {
  int n = blockIdx.x, t = threadIdx.x;
  __shared__ float es[128];
  __shared__ float outs[103];
  es[t] = enc[(size_t)n*SDIM + t];
  __syncthreads();
  const float* W = nullptr; const float* bb = nullptr; int col = 0, nc = 0;
  if (t < 30)       { W = Ws;    bb = bs;    col = t;       nc = 30; }
  else if (t < 60)  { W = Wc;    bb = bc;    col = t - 30;  nc = 30; }
  else if (t < 90)  { W = Wconc; bb = bconc; col = t - 60;  nc = 30; }
  else if (t < 100) { W = Wwt;   bb = bwt;   col = t - 90;  nc = 10; }
  else if (t < 103) { W = Wfac;  bb = bfac;  col = t - 100; nc = 3;  }
  if (W) {
    float acc = bb[col];
    for (int j = 0; j < 128; j++) acc += es[j] * W[j*nc + col];
    outs[t] = acc;
  }
  __syncthreads();
  if (t < MIXN) {
    float mx = -1e30f;
    for (int m = 0; m < MIXN; m++) mx = fmaxf(mx, outs[90 + m]);
    float sum = 0.f;
    for (int m = 0; m < MIXN; m++) sum += expf(outs[90 + m] - mx);
    out[(size_t)n*MIXN + t] = expf(outs[90 + t] - mx) / sum;
  }
  if (t < 30) {
    int j = t / 10;
    float v = atan2f(outs[t], outs[30 + t]);
    float a0 = angles[n*3 + 0], a1 = angles[n*3 + 1];
    if (j == 1) v += outs[100] * a0;
    if (j == 2) v += outs[101] * a0 + outs[102] * a1;
    out[(size_t)NRES*MIXN + (size_t)n*30 + t] = v;
    float z = outs[60 + t];
    float sg = 1.f / (1.f + expf(-z));
    out[(size_t)NRES*MIXN + (size_t)NRES*30 + (size_t)n*30 + t] = 0.1f + 1000.f * sg;
  }
}

// ---------------- launch ----------------
extern "C" void kernel_launch(void* const* d_in, const int* in_sizes, int n_in,
                              void* d_out, int out_size, void* d_ws, size_t ws_size,
                              hipStream_t stream) {
  const float* angles   = (const float*)d_in[0];
  const float* tertiary = (const float*)d_in[1];
  const int*   structure = (const int*)d_in[2];
  const float* W_in  = (const float*)d_in[4];  const float* b_in  = (const float*)d_in[5];
  const float* W_pre = (const float*)d_in[6];  const float* b_pre = (const float*)d_in[7];
  const float* ln1_g = (const float*)d_in[8];  const float* ln1_b = (const float*)d_in[9];
  const float* ln2_g = (const float*)d_in[10]; const float* ln2_b = (const float*)d_in[11];
  const float* Wq = (const float*)d_in[12]; const float* bq = (const float*)d_in[13];
  const float* Wk = (const float*)d_in[14]; const float* bk = (const float*)d_in[15];
  const float* Wv = (const float*)d_in[16]; const float* bv = (const float*)d_in[17];
  const float* Wo = (const float*)d_in[18]; const float* bo = (const float*)d_in[19];
  const float* W1 = (const float*)d_in[20]; const float* b1 = (const float*)d_in[21];
  const float* W2 = (const float*)d_in[22]; const float* b2 = (const float*)d_in[23];
  const float* W3 = (const float*)d_in[24]; const float* b3 = (const float*)d_in[25];
  const float* Ws = (const float*)d_in[26]; const float* bs = (const float*)d_in[27];
  const float* Wc = (const float*)d_in[28]; const float* bc = (const float*)d_in[29];
  const float* Wconc = (const float*)d_in[30]; const float* bconc = (const float*)d_in[31];
  const float* Wwt = (const float*)d_in[32]; const float* bwt = (const float*)d_in[33];
  const float* Wfac = (const float*)d_in[34]; const float* bfac = (const float*)d_in[35];

  // workspace layout (bytes); high-water ~38.9 MB
  char* wsb = (char*)d_ws;
  float* Rm    = (float*)(wsb + 0);           //   294,912 B
  f16*   edg_h = (f16*)  (wsb + 294912);      // 5,898,240 B
  float* x     = (float*)(wsb + 6193152);     // 4 MiB f32 residual
  f16*   att_h = (f16*)  (wsb + 10387456);    // 4 MiB
  f16*   qh    = (f16*)  (wsb + 14581760);    // 4 MiB (q | pk | pv contiguous fp16)
  f16*   pkh   = (f16*)  (wsb + 18776064);    // 4 MiB
  f16*   pvh   = (f16*)  (wsb + 22970368);    // 4 MiB
  size_t qkvwOff = 27164672;                  //   786,432 B (3 x 128x1024 swizzled)
  size_t w1wOff  = 27951104;                  //   393,216 B
  size_t w2wOff  = 28344320;                  // 1,572,864 B
  size_t w3wOff  = 29917184;                  //   393,216 B
  size_t wowOff  = 30310400;                  //   196,608 B
  f16*   qkvw  = (f16*)(wsb + qkvwOff);
  f16*   w1w   = (f16*)(wsb + w1wOff);
  f16*   w2w   = (f16*)(wsb + w2wOff);
  f16*   w3w   = (f16*)(wsb + w3wOff);
  f16*   wow   = (f16*)(wsb + wowOff);
  float* b1024 = (float*)(wsb + 30507008);    //    12,288 B
  float* qWb   = (float*)(wsb + 30519296);    // 8,388,608 B f32 [8192][256] -> 38,907,904

  frames_kernel<<<dim3((NRES+255)/256), dim3(256), 0, stream>>>(tertiary, Rm);
  edges_kernel<<<dim3((NRES*KNB+255)/256), dim3(256), 0, stream>>>(tertiary, Rm, structure, edg_h);
  init_kernel<<<dim3(NRES), dim3(128), 0, stream>>>(angles, W_in, b_in, W_pre, b_pre, x);

  SwzJobs jobs;
  jobs.j[0] = { Wq, SDIM*QDIM,        QDIM, 128, 256, qkvwOff, 131072, 1024, 0   };
  jobs.j[1] = { Wk, (SDIM+EDIM)*QDIM, QDIM, 128, 256, qkvwOff, 131072, 1024, 256 };
  jobs.j[2] = { Wv, (SDIM+EDIM)*QDIM, QDIM, 128, 256, qkvwOff, 131072, 1024, 512 };
  jobs.j[3] = { W1, SDIM*HIDD, HIDD, 128, 512, w1wOff, 65536,  512, 0 };
  jobs.j[4] = { W2, HIDD*HIDD, HIDD, 512, 512, w2wOff, 262144, 512, 0 };
  jobs.j[5] = { W3, HIDD*SDIM, SDIM, 512, 128, w3wOff, 65536,  128, 0 };
  jobs.j[6] = { Wo, QDIM*SDIM, SDIM, 256, 128, wowOff, 32768,  128, 0 };
  convswz_all<<<dim3(64, 7, 3), dim3(256), 0, stream>>>(jobs, wsb);
  wcomb_kernel<<<768, 128, 0, stream>>>(Wq, bq, Wk, bk, qkvw, b1024);

  for (int d = 0; d < 3; ++d) {
    const float* WvD = Wv + (size_t)d*(SDIM+EDIM)*QDIM;
    // LN1 + q|pk|pv + qW in one GEMM (Nd=1024)
    gemm_ln_mfma<3><<<1024, 256, 0, stream>>>(x, ln1_g + d*SDIM, ln1_b + d*SDIM,
        qkvw + (size_t)d*131072, b1024 + d*1024, qh, qWb, 1024);
    attn_kernel<<<dim3(NRES/4), dim3(256), 0, stream>>>(qh, pkh, pvh, edg_h, structure,
        qWb, WvD + (size_t)SDIM*QDIM, bv + d*QDIM, att_h);
    // Wo + residual + LN2 + W1 + W2 + W3 + residual, one kernel
    ffn2_kernel<<<dim3(NRES/16), dim3(256), 0, stream>>>(att_h,
        wow + (size_t)d*32768, bo + d*SDIM, x,
        ln2_g + d*SDIM, ln2_b + d*SDIM,
        w1w + (size_t)d*65536, b1 + d*HIDD,
        w2w + (size_t)d*262144, b2 + d*HIDD,
        w3w + (size_t)d*65536, b3 + d*SDIM, x);
  }

  head_kernel<<<dim3(NRES), dim3(128), 0, stream>>>(x, Ws, bs, Wc, bc, Wconc, bconc,
      Wwt, bwt, Wfac, bfac, angles, (float*)d_out);
}